// Round 5
// baseline (1957.667 us; speedup 1.0000x reference)
//
#include <hip/hip_runtime.h>
#include <hip/hip_bf16.h>

// GloAttnConv R5: k_kv CHUNK 250->50 (6->30 waves/CU), batch-uniform fast path
// (no batch[] loads in hot loop), unroll-4 for load pipelining.

typedef __attribute__((ext_vector_type(8))) short bf16x8;
typedef __attribute__((ext_vector_type(4))) float f32x4v;

#define CHUNK 50   // divides 1000 -> chunks never straddle graph boundaries here

__device__ __forceinline__ float asf(unsigned int u) { union { unsigned int i; float f; } v; v.i = u; return v.f; }
__device__ __forceinline__ float b2f_u(unsigned short u) { return asf((unsigned int)u << 16); }
__device__ __forceinline__ unsigned short f2b_u(float f) {
    __hip_bfloat16 h = __float2bfloat16(f);
    union { __hip_bfloat16 h; unsigned short u; } v; v.h = h; return v.u;
}
__device__ __forceinline__ unsigned int pack2(float a, float b) {
    return (unsigned int)f2b_u(a) | ((unsigned int)f2b_u(b) << 16);
}
__device__ __forceinline__ float wave_reduce_sum(float v) {
    #pragma unroll
    for (int off = 32; off > 0; off >>= 1) v += __shfl_xor(v, off, 64);
    return v;
}

// ---- graph bookkeeping -----------------------------------------------------
__global__ void k_ptr(const int* __restrict__ nn, int* __restrict__ ptr, int B) {
    if (threadIdx.x == 0 && blockIdx.x == 0) {
        int s = 0; ptr[0] = 0;
        for (int i = 0; i < B; ++i) { s += nn[i]; ptr[i + 1] = s; }
    }
}

__global__ void k_batch(const int* __restrict__ ptr, int* __restrict__ batch) {
    int b = blockIdx.x;
    int s = ptr[b], e = ptr[b + 1];
    for (int i = s + threadIdx.x; i < e; i += blockDim.x) batch[i] = b;
}

// ---- q/k projection + L2-normalize; init cur & acc. Thread = output col. ----
__global__ __launch_bounds__(256) void k_qk(
    const float* __restrict__ x,
    const float* __restrict__ Wq_w, const float* __restrict__ Wq_b,
    const float* __restrict__ Wk_w, const float* __restrict__ Wk_b,
    unsigned short* __restrict__ q, unsigned short* __restrict__ kq,
    unsigned short* __restrict__ curA, unsigned short* __restrict__ acc, int N)
{
    int t = threadIdx.x, w = t >> 6, l = t & 63;
    int col = ((w & 1) << 6) | l;           // 0..127 within q or k
    const float* W = (w >= 2) ? Wk_w : Wq_w;
    float4 wr[16];
    {
        const float4* Wrow = (const float4*)(W + col * 64);
        #pragma unroll
        for (int j = 0; j < 16; ++j) wr[j] = Wrow[j];
    }
    float bias = (w >= 2) ? Wk_b[col] : Wq_b[col];
    unsigned short* dst = (w >= 2) ? kq : q;

    __shared__ float xs[2][64];
    for (int n0 = blockIdx.x * 2; n0 < N; n0 += gridDim.x * 2) {
        __syncthreads();
        if (t < 128) {
            int nx = n0 + (t >> 6);
            xs[t >> 6][t & 63] = (nx < N) ? x[(size_t)nx * 64 + (t & 63)] : 0.f;
        }
        __syncthreads();
        #pragma unroll
        for (int s = 0; s < 2; ++s) {
            int n = n0 + s;
            if (n >= N) continue;
            const float4* xv = (const float4*)xs[s];
            float a0 = 0.f, a1 = 0.f, a2 = 0.f, a3 = 0.f;
            #pragma unroll
            for (int j = 0; j < 4; ++j) {
                float4 x0 = xv[j * 4 + 0], x1 = xv[j * 4 + 1];
                float4 x2 = xv[j * 4 + 2], x3 = xv[j * 4 + 3];
                float4 w0 = wr[j * 4 + 0], w1 = wr[j * 4 + 1];
                float4 w2 = wr[j * 4 + 2], w3 = wr[j * 4 + 3];
                a0 += x0.x * w0.x + x0.y * w0.y + x0.z * w0.z + x0.w * w0.w;
                a1 += x1.x * w1.x + x1.y * w1.y + x1.z * w1.z + x1.w * w1.w;
                a2 += x2.x * w2.x + x2.y * w2.y + x2.z * w2.z + x2.w * w2.w;
                a3 += x3.x * w3.x + x3.y * w3.y + x3.z * w3.z + x3.w * w3.w;
            }
            float v = a0 + a1 + a2 + a3 + bias;
            float ss = wave_reduce_sum(v * v);
            float o = v * rsqrtf(ss);
            dst[(size_t)n * 128 + col] = f2b_u(o);
        }
        {
            int nx = n0 + (w >> 1);
            if (nx < N) {
                unsigned short pb = f2b_u(xs[w >> 1][l]);
                size_t o = (size_t)nx * 128 + col;
                curA[o] = pb;
                acc[o] = pb;
            }
        }
    }
}

// ---- degree / dis ----------------------------------------------------------
__global__ void k_deg(const int* __restrict__ row, int* __restrict__ deg, int E) {
    int e = blockIdx.x * 256 + threadIdx.x;
    if (e < E) atomicAdd(&deg[row[e]], 1);
}

__global__ void k_dis(const int* __restrict__ deg, float* __restrict__ dis, int N) {
    int n = blockIdx.x * 256 + threadIdx.x;
    if (n < N) { int d = deg[n]; dis[n] = d > 0 ? rsqrtf((float)d) : 0.f; }
}

// ---- exclusive scan of deg -> rowstart -------------------------------------
__global__ void k_scan1(const int* __restrict__ deg, int* __restrict__ rowstart,
                        int* __restrict__ bsum, int N) {
    __shared__ int sh[256];
    int t = threadIdx.x, n = blockIdx.x * 256 + t;
    int v = (n < N) ? deg[n] : 0;
    sh[t] = v; __syncthreads();
    #pragma unroll
    for (int off = 1; off < 256; off <<= 1) {
        int add = (t >= off) ? sh[t - off] : 0;
        __syncthreads();
        sh[t] += add;
        __syncthreads();
    }
    if (n < N) rowstart[n] = sh[t] - v;
    if (t == 255) bsum[blockIdx.x] = sh[255];
}

__global__ void k_scan2(int* __restrict__ bsum, int nb) {
    __shared__ int sh[512];
    __shared__ int carry;
    int t = threadIdx.x;
    if (t == 0) carry = 0;
    __syncthreads();
    for (int base = 0; base < nb; base += 512) {
        int idx = base + t;
        int v = (idx < nb) ? bsum[idx] : 0;
        sh[t] = v; __syncthreads();
        for (int off = 1; off < 512; off <<= 1) {
            int add = (t >= off) ? sh[t - off] : 0;
            __syncthreads();
            sh[t] += add;
            __syncthreads();
        }
        if (idx < nb) bsum[idx] = sh[t] - v + carry;
        __syncthreads();
        if (t == 0) carry += sh[511];
        __syncthreads();
    }
}

__global__ void k_scan3(int* __restrict__ rowstart, const int* __restrict__ bsum, int N, int E) {
    int n = blockIdx.x * 256 + threadIdx.x;
    if (n < N) rowstart[n] += bsum[blockIdx.x];
    if (n == 0) rowstart[N] = E;
}

// ---- CSR fill (also packs edge attributes) ---------------------------------
__global__ void k_fill(const int* __restrict__ eidx, const float* __restrict__ dis,
                       const int* __restrict__ rowstart, int* __restrict__ cursor,
                       int* __restrict__ csr_col, float* __restrict__ csr_w,
                       int* __restrict__ csr_att, const int* __restrict__ eattr, int E) {
    int e = blockIdx.x * 256 + threadIdx.x;
    if (e >= E) return;
    int r = eidx[e], c = eidx[E + e];
    float wv = dis[r] * dis[c];
    int a0 = eattr[e * 3 + 0], a1 = eattr[e * 3 + 1], a2 = eattr[e * 3 + 2];
    int slot = atomicAdd(&cursor[r], 1);
    int idx = rowstart[r] + slot;
    csr_col[idx] = c; csr_w[idx] = wv; csr_att[idx] = a0 | (a1 << 8) | (a2 << 16);
}

// ---- msg_edge[n,64]; bond table in LDS, wave per node ----------------------
__global__ __launch_bounds__(256) void k_msg(
    const int* __restrict__ rowstart, const int* __restrict__ csr_att,
    const float* __restrict__ csr_w, const float* __restrict__ bond,
    float* __restrict__ msg, int N) {
    __shared__ float bl[1536];
    int t = threadIdx.x, w = t >> 6, l = t & 63;
    for (int i = t; i < 1536; i += 256) bl[i] = bond[i];
    __syncthreads();
    for (int n = blockIdx.x * 4 + w; n < N; n += gridDim.x * 4) {
        int s0 = rowstart[n], s1 = rowstart[n + 1];
        float m = 0.f;
        for (int i = s0; i < s1; ++i) {
            int att = csr_att[i];
            float wv = csr_w[i];
            m += wv * (bl[(att & 255) * 64 + l] + bl[(8 + ((att >> 8) & 255)) * 64 + l]
                     + bl[(16 + (att >> 16)) * 64 + l]);
        }
        msg[(size_t)n * 64 + l] = m;
    }
}

// ---- k_sum per graph (iteration-invariant) ---------------------------------
__global__ __launch_bounds__(128) void k_ksum(
    const unsigned short* __restrict__ kq, const int* __restrict__ batch,
    float* __restrict__ ksum, int N) {
    int t = threadIdx.x;
    int start = blockIdx.x * 256;
    if (start >= N) return;
    int curb = batch[start];
    float a = 0.f;
    for (int i = 0; i < 256; ++i) {
        int n = start + i;
        if (n >= N) break;
        int b = batch[n];
        if (b != curb) { atomicAdd(&ksum[curb * 128 + t], a); a = 0.f; curb = b; }
        a += b2f_u(kq[(size_t)n * 128 + t]);
    }
    atomicAdd(&ksum[curb * 128 + t], a);
}

// ---- denom[n][h] = q[n,h,:].ksum[b,h,:] + n_nodes[b] -----------------------
__global__ __launch_bounds__(256) void k_denom(
    const unsigned short* __restrict__ q, const float* __restrict__ ksum,
    const int* __restrict__ batch, const int* __restrict__ nn,
    float* __restrict__ denom, int N)
{
    int w = threadIdx.x >> 6, l = threadIdx.x & 63;
    int n = blockIdx.x * 4 + w;
    if (n >= N) return;
    int b = batch[n];
    float d0 = b2f_u(q[(size_t)n * 128 + l]) * ksum[b * 128 + l];
    float d1 = b2f_u(q[(size_t)n * 128 + 64 + l]) * ksum[b * 128 + 64 + l];
    d0 = wave_reduce_sum(d0);
    d1 = wave_reduce_sum(d1);
    if (l == 0) {
        float nf = (float)nn[b];
        denom[n * 2 + 0] = d0 + nf;
        denom[n * 2 + 1] = d1 + nf;
    }
}

// ---- kvT[b,h,e,d] += sum_n v[n,h,e]*k[n,h,d]; vsum[b,h,e] ------------------
// Wave = (chunk, h, dhalf); lane owns 4(d) x 8(e) tile; no LDS, no barriers.
__global__ __launch_bounds__(256) void k_kv(
    const unsigned short* __restrict__ kq, const unsigned short* __restrict__ cur,
    const int* __restrict__ batch, float* __restrict__ kvT,
    float* __restrict__ vsum, int N)
{
    int w = threadIdx.x >> 6, l = threadIdx.x & 63;
    int h = w >> 1, dhalf = w & 1;
    int start = blockIdx.x * CHUNK;
    if (start >= N) return;
    int end = min(start + CHUNK, N);
    int d0 = dhalf * 32 + (l & 7) * 4;
    int e0 = (l >> 3) * 8;
    float a[4][8], va[8];
    #pragma unroll
    for (int i = 0; i < 4; ++i)
        #pragma unroll
        for (int j = 0; j < 8; ++j) a[i][j] = 0.f;
    #pragma unroll
    for (int j = 0; j < 8; ++j) va[j] = 0.f;

    int bfirst = batch[start], blast = batch[end - 1];
    if (bfirst == blast) {
        // fast path: whole chunk in one graph; no batch loads, unroll for MLP
        const unsigned short* kp = kq + (size_t)start * 128 + h * 64 + d0;
        const unsigned short* vp = cur + (size_t)start * 128 + h * 64 + e0;
        #pragma unroll 4
        for (int n = start; n < end; ++n) {
            uint2 ku = *(const uint2*)kp;
            uint4 vu = *(const uint4*)vp;
            kp += 128; vp += 128;
            float k0 = asf(ku.x << 16), k1 = asf(ku.x & 0xffff0000u);
            float k2 = asf(ku.y << 16), k3 = asf(ku.y & 0xffff0000u);
            float v[8];
            v[0] = asf(vu.x << 16); v[1] = asf(vu.x & 0xffff0000u);
            v[2] = asf(vu.y << 16); v[3] = asf(vu.y & 0xffff0000u);
            v[4] = asf(vu.z << 16); v[5] = asf(vu.z & 0xffff0000u);
            v[6] = asf(vu.w << 16); v[7] = asf(vu.w & 0xffff0000u);
            #pragma unroll
            for (int j = 0; j < 8; ++j) {
                a[0][j] += k0 * v[j]; a[1][j] += k1 * v[j];
                a[2][j] += k2 * v[j]; a[3][j] += k3 * v[j];
                va[j] += v[j];
            }
        }
    } else {
        int curb = bfirst;
        for (int n = start; n < end; ++n) {
            int b = batch[n];
            if (b != curb) {
                float* dst = kvT + (size_t)(curb * 2 + h) * 4096;
                #pragma unroll
                for (int j = 0; j < 8; ++j)
                    #pragma unroll
                    for (int i = 0; i < 4; ++i) {
                        atomicAdd(&dst[(e0 + j) * 64 + d0 + i], a[i][j]);
                        a[i][j] = 0.f;
                    }
                if (dhalf == 0 && (l & 7) == 0)
                    #pragma unroll
                    for (int j = 0; j < 8; ++j) {
                        atomicAdd(&vsum[(curb * 2 + h) * 64 + e0 + j], va[j]);
                        va[j] = 0.f;
                    }
                curb = b;
            }
            const unsigned short* krow = kq + (size_t)n * 128 + h * 64;
            const unsigned short* vrow = cur + (size_t)n * 128 + h * 64;
            uint2 ku = *(const uint2*)(krow + d0);
            uint4 vu = *(const uint4*)(vrow + e0);
            float k0 = asf(ku.x << 16), k1 = asf(ku.x & 0xffff0000u);
            float k2 = asf(ku.y << 16), k3 = asf(ku.y & 0xffff0000u);
            float v[8];
            v[0] = asf(vu.x << 16); v[1] = asf(vu.x & 0xffff0000u);
            v[2] = asf(vu.y << 16); v[3] = asf(vu.y & 0xffff0000u);
            v[4] = asf(vu.z << 16); v[5] = asf(vu.z & 0xffff0000u);
            v[6] = asf(vu.w << 16); v[7] = asf(vu.w & 0xffff0000u);
            #pragma unroll
            for (int j = 0; j < 8; ++j) {
                a[0][j] += k0 * v[j]; a[1][j] += k1 * v[j];
                a[2][j] += k2 * v[j]; a[3][j] += k3 * v[j];
                va[j] += v[j];
            }
        }
        bfirst = curb;  // flush below targets the last graph
    }
    float* dst = kvT + (size_t)(bfirst * 2 + h) * 4096;
    #pragma unroll
    for (int j = 0; j < 8; ++j)
        #pragma unroll
        for (int i = 0; i < 4; ++i)
            atomicAdd(&dst[(e0 + j) * 64 + d0 + i], a[i][j]);
    if (dhalf == 0 && (l & 7) == 0)
        #pragma unroll
        for (int j = 0; j < 8; ++j)
            atomicAdd(&vsum[(bfirst * 2 + h) * 64 + e0 + j], va[j]);
}

// ---- kvT fp32 -> bf16 (linear) ---------------------------------------------
__global__ void k_cvt(const float* __restrict__ src, unsigned short* __restrict__ dst, int n4) {
    int i = blockIdx.x * 256 + threadIdx.x;
    if (i >= n4) return;
    float4 v = ((const float4*)src)[i];
    ushort4 o;
    o.x = f2b_u(v.x); o.y = f2b_u(v.y); o.z = f2b_u(v.z); o.w = f2b_u(v.w);
    ((ushort4*)dst)[i] = o;
}

// ---- attn via MFMA: num[n,h,e] = sum_d q[n,h,d]*kvT[b,h,e,d]; write 0.5*attn
__global__ __launch_bounds__(256) void k_attn(
    const unsigned short* __restrict__ q, const unsigned short* __restrict__ kvT,
    const float* __restrict__ vsum, const float* __restrict__ denom,
    const int* __restrict__ batch, unsigned short* __restrict__ curB, int N)
{
    int w = threadIdx.x >> 6, l = threadIdx.x & 63;
    int base = blockIdx.x * 64 + w * 16;
    if (base >= N) return;
    int quad = l >> 4, six = l & 15;
    int b0 = batch[base];
    int nlast = min(base + 15, N - 1);
    bool uni = (base + 15 < N) && (batch[nlast] == b0);
    if (uni) {
        int n = base + six;
        #pragma unroll
        for (int h = 0; h < 2; ++h) {
            const unsigned short* qrow = q + (size_t)n * 128 + h * 64;
            bf16x8 a0 = *(const bf16x8*)(qrow + quad * 8);
            bf16x8 a1 = *(const bf16x8*)(qrow + 32 + quad * 8);
            const unsigned short* Bb = kvT + (size_t)(b0 * 2 + h) * 4096;
            f32x4v acc[4];
            #pragma unroll
            for (int et = 0; et < 4; ++et) {
                const unsigned short* brow = Bb + (size_t)(et * 16 + six) * 64;
                bf16x8 bb0 = *(const bf16x8*)(brow + quad * 8);
                bf16x8 bb1 = *(const bf16x8*)(brow + 32 + quad * 8);
                f32x4v c = {0.f, 0.f, 0.f, 0.f};
                c = __builtin_amdgcn_mfma_f32_16x16x32_bf16(a0, bb0, c, 0, 0, 0);
                c = __builtin_amdgcn_mfma_f32_16x16x32_bf16(a1, bb1, c, 0, 0, 0);
                acc[et] = c;
            }
            #pragma unroll
            for (int et = 0; et < 4; ++et) {
                int e = et * 16 + six;
                float vs = vsum[(b0 * 2 + h) * 64 + e];
                #pragma unroll
                for (int r = 0; r < 4; ++r) {
                    int nr = base + quad * 4 + r;
                    float dn = denom[nr * 2 + h];
                    float val = 0.5f * (acc[et][r] + vs) / dn;
                    curB[(size_t)nr * 128 + h * 64 + e] = f2b_u(val);
                }
            }
        }
    } else {
        for (int i = 0; i < 16; ++i) {
            int n = base + i;
            if (n >= N) break;
            int b = batch[n];
            #pragma unroll
            for (int h = 0; h < 2; ++h) {
                float num = 0.f;
                const unsigned short* krow = kvT + (size_t)((b * 2 + h) * 64 + l) * 64;
                for (int d = 0; d < 64; ++d)
                    num += b2f_u(q[(size_t)n * 128 + h * 64 + d]) * b2f_u(krow[d]);
                float val = 0.5f * (num + vsum[(b * 2 + h) * 64 + l]) / denom[n * 2 + h];
                curB[(size_t)n * 128 + h * 64 + l] = f2b_u(val);
            }
        }
    }
}

// ---- GCN gather + combine (wave per node) ----------------------------------
__global__ __launch_bounds__(256) void k_gcn(
    const unsigned short* __restrict__ curA, const float* __restrict__ msg,
    const int* __restrict__ rowstart, const int* __restrict__ csr_col,
    const float* __restrict__ csr_w,
    unsigned short* __restrict__ curB, unsigned short* __restrict__ acc, int N)
{
    int w = threadIdx.x >> 6, l = threadIdx.x & 63;
    int n = blockIdx.x * 4 + w;
    if (n >= N) return;
    int s0 = rowstart[n], s1 = rowstart[n + 1];
    float g0 = 0.f, g1 = 0.f;
    #pragma unroll 2
    for (int i = s0; i < s1; ++i) {
        int c = csr_col[i];
        float wv = csr_w[i];
        unsigned int u = *(const unsigned int*)(curA + (size_t)c * 128 + 2 * l);
        g0 += wv * asf(u << 16);
        g1 += wv * asf(u & 0xffff0000u);
    }
    float2 m = *(const float2*)(msg + (size_t)n * 64 + ((2 * l) & 63));
    size_t o = (size_t)n * 128 + 2 * l;
    unsigned int ub = *(const unsigned int*)(curB + o);
    float v0 = 0.5f * (g0 + m.x) + asf(ub << 16);
    float v1 = 0.5f * (g1 + m.y) + asf(ub & 0xffff0000u);
    *(unsigned int*)(curB + o) = pack2(v0, v1);
    unsigned int ua = *(const unsigned int*)(acc + o);
    *(unsigned int*)(acc + o) = pack2(asf(ua << 16) + v0, asf(ua & 0xffff0000u) + v1);
}

// ---- out = (acc @ Wo^T + b) / 2 -------------------------------------------
__global__ __launch_bounds__(256) void k_out(
    const unsigned short* __restrict__ acc, const float* __restrict__ Wo_w,
    const float* __restrict__ Wo_b, float* __restrict__ out, int N)
{
    __shared__ float wol[64 * 129];
    __shared__ float accl[512];
    int t = threadIdx.x;
    for (int idx = t; idx < 64 * 128; idx += 256) {
        int o = idx >> 7, c = idx & 127;
        wol[o * 129 + c] = Wo_w[idx];
    }
    float bias = Wo_b[t & 63];
    __syncthreads();
    int base = blockIdx.x * 64;
    for (int s = 0; s < 16; ++s) {
        int nb = base + s * 4;
        __syncthreads();
        for (int idx = t; idx < 512; idx += 256) {
            int r = idx >> 7, c = idx & 127;
            int n = nb + r;
            accl[idx] = (n < N) ? b2f_u(acc[(size_t)n * 128 + c]) : 0.f;
        }
        __syncthreads();
        int i = t >> 6, o = t & 63;
        int n = nb + i;
        if (n < N) {
            float s2 = 0.f;
            const float4* a4 = (const float4*)(accl + i * 128);
            #pragma unroll
            for (int c4 = 0; c4 < 32; ++c4) {
                float4 av = a4[c4];
                s2 += av.x * wol[o * 129 + c4 * 4 + 0] + av.y * wol[o * 129 + c4 * 4 + 1]
                    + av.z * wol[o * 129 + c4 * 4 + 2] + av.w * wol[o * 129 + c4 * 4 + 3];
            }
            out[n * 64 + o] = (s2 + bias) * 0.5f;
        }
    }
}

extern "C" void kernel_launch(void* const* d_in, const int* in_sizes, int n_in,
                              void* d_out, int out_size, void* d_ws, size_t ws_size,
                              hipStream_t stream) {
    const float* x    = (const float*)d_in[0];
    const float* Wq_w = (const float*)d_in[1];
    const float* Wq_b = (const float*)d_in[2];
    const float* Wk_w = (const float*)d_in[3];
    const float* Wk_b = (const float*)d_in[4];
    const float* Wo_w = (const float*)d_in[5];
    const float* Wo_b = (const float*)d_in[6];
    const float* bond = (const float*)d_in[7];
    const int*   eidx = (const int*)d_in[8];
    const int*   eattr= (const int*)d_in[9];
    const int*   nn   = (const int*)d_in[10];
    float* out = (float*)d_out;
    int N = in_sizes[0] / 64;
    int E = in_sizes[9] / 3;
    int B = in_sizes[10];

    char* p = (char*)d_ws;
    auto alloc = [&](size_t bytes) { char* r = p; p += (bytes + 255) & ~(size_t)255; return r; };
    unsigned short* q    = (unsigned short*)alloc((size_t)N * 128 * 2);
    unsigned short* kq   = (unsigned short*)alloc((size_t)N * 128 * 2);
    unsigned short* curA = (unsigned short*)alloc((size_t)N * 128 * 2);
    unsigned short* curB = (unsigned short*)alloc((size_t)N * 128 * 2);
    unsigned short* acc  = (unsigned short*)alloc((size_t)N * 128 * 2);
    float* kvT_f = (float*)alloc((size_t)B * 2 * 64 * 64 * 4);
    float* vsum  = (float*)alloc((size_t)B * 128 * 4);
    unsigned short* kvT_b = (unsigned short*)alloc((size_t)B * 2 * 64 * 64 * 2);
    float* ksum  = (float*)alloc((size_t)B * 128 * 4);
    float* denom = (float*)alloc((size_t)N * 2 * 4);
    float* dis   = (float*)alloc((size_t)N * 4);
    int* deg     = (int*)alloc((size_t)N * 4);
    int* rowstart= (int*)alloc((size_t)(N + 1) * 4);
    int* cursor  = (int*)alloc((size_t)N * 4);
    int* csr_col = (int*)alloc((size_t)E * 4);
    float* csr_w = (float*)alloc((size_t)E * 4);
    int* csr_att = (int*)alloc((size_t)E * 4);
    int* batch   = (int*)alloc((size_t)N * 4);
    int* ptr     = (int*)alloc((size_t)(B + 1) * 4);
    int nb = (N + 255) / 256;
    int* bsum    = (int*)alloc((size_t)nb * 4);
    float* msg   = out;   // [N,64] fp32 aliased onto d_out; k_out rewrites it last

    size_t kvreg = (size_t)B * 2 * 64 * 64 * 4 + (size_t)B * 128 * 4;

    hipMemsetAsync(deg,    0, (size_t)N * 4, stream);
    hipMemsetAsync(cursor, 0, (size_t)N * 4, stream);
    hipMemsetAsync(ksum,   0, (size_t)B * 128 * 4, stream);

    k_ptr  <<<1, 64, 0, stream>>>(nn, ptr, B);
    k_batch<<<B, 256, 0, stream>>>(ptr, batch);
    k_qk   <<<2048, 256, 0, stream>>>(x, Wq_w, Wq_b, Wk_w, Wk_b, q, kq, curA, acc, N);
    k_deg  <<<(E + 255) / 256, 256, 0, stream>>>(eidx, deg, E);
    k_dis  <<<(N + 255) / 256, 256, 0, stream>>>(deg, dis, N);
    k_scan1<<<nb, 256, 0, stream>>>(deg, rowstart, bsum, N);
    k_scan2<<<1, 512, 0, stream>>>(bsum, nb);
    k_scan3<<<nb, 256, 0, stream>>>(rowstart, bsum, N, E);
    k_fill <<<(E + 255) / 256, 256, 0, stream>>>(eidx, dis, rowstart, cursor, csr_col, csr_w, csr_att, eattr, E);
    k_msg  <<<2048, 256, 0, stream>>>(rowstart, csr_att, csr_w, bond, msg, N);
    k_ksum <<<(N + 255) / 256, 128, 0, stream>>>(kq, batch, ksum, N);
    k_denom<<<(N + 3) / 4, 256, 0, stream>>>(q, ksum, batch, nn, denom, N);

    int kvblocks = (N + CHUNK - 1) / CHUNK;
    int n4 = B * 2 * 64 * 64 / 4;
    for (int it = 0; it < 4; ++it) {
        hipMemsetAsync(kvT_f, 0, kvreg, stream);
        k_kv  <<<kvblocks, 256, 0, stream>>>(kq, curA, batch, kvT_f, vsum, N);
        k_cvt <<<(n4 + 255) / 256, 256, 0, stream>>>(kvT_f, kvT_b, n4);
        k_attn<<<(N + 63) / 64, 256, 0, stream>>>(q, kvT_b, vsum, denom, batch, curB, N);
        k_gcn <<<(N + 3) / 4, 256, 0, stream>>>(curA, msg, rowstart, csr_col, csr_w, curB, acc, N);
        unsigned short* tmp = curA; curA = curB; curB = tmp;
    }
    k_out<<<(N + 63) / 64, 256, 0, stream>>>(acc, Wo_w, Wo_b, out, N);
}

// Round 6
// 1255.454 us; speedup vs baseline: 1.5593x; 1.5593x over previous
//
#include <hip/hip_runtime.h>
#include <hip/hip_bf16.h>

// GloAttnConv R6: kv via two-stage reduction (no atomics): k_kvp writes per-chunk
// partials with plain coalesced stores (chunks per-graph-aligned via cptr, never
// straddle), k_red sums partials -> bf16 kvT + vsum (absorbs k_cvt + memsets).

typedef __attribute__((ext_vector_type(8))) short bf16x8;
typedef __attribute__((ext_vector_type(4))) float f32x4v;

#define CHUNK 100

__device__ __forceinline__ float asf(unsigned int u) { union { unsigned int i; float f; } v; v.i = u; return v.f; }
__device__ __forceinline__ float b2f_u(unsigned short u) { return asf((unsigned int)u << 16); }
__device__ __forceinline__ unsigned short f2b_u(float f) {
    __hip_bfloat16 h = __float2bfloat16(f);
    union { __hip_bfloat16 h; unsigned short u; } v; v.h = h; return v.u;
}
__device__ __forceinline__ unsigned int pack2(float a, float b) {
    return (unsigned int)f2b_u(a) | ((unsigned int)f2b_u(b) << 16);
}
__device__ __forceinline__ float wave_reduce_sum(float v) {
    #pragma unroll
    for (int off = 32; off > 0; off >>= 1) v += __shfl_xor(v, off, 64);
    return v;
}

// ---- graph bookkeeping: node ptr + chunk ptr -------------------------------
__global__ void k_ptr(const int* __restrict__ nn, int* __restrict__ ptr,
                      int* __restrict__ cptr, int B) {
    if (threadIdx.x == 0 && blockIdx.x == 0) {
        int s = 0, c = 0; ptr[0] = 0; cptr[0] = 0;
        for (int i = 0; i < B; ++i) {
            s += nn[i]; ptr[i + 1] = s;
            c += (nn[i] + CHUNK - 1) / CHUNK; cptr[i + 1] = c;
        }
    }
}

__global__ void k_batch(const int* __restrict__ ptr, int* __restrict__ batch) {
    int b = blockIdx.x;
    int s = ptr[b], e = ptr[b + 1];
    for (int i = s + threadIdx.x; i < e; i += blockDim.x) batch[i] = b;
}

// ---- q/k projection + L2-normalize; init cur & acc. Thread = output col. ----
__global__ __launch_bounds__(256) void k_qk(
    const float* __restrict__ x,
    const float* __restrict__ Wq_w, const float* __restrict__ Wq_b,
    const float* __restrict__ Wk_w, const float* __restrict__ Wk_b,
    unsigned short* __restrict__ q, unsigned short* __restrict__ kq,
    unsigned short* __restrict__ curA, unsigned short* __restrict__ acc, int N)
{
    int t = threadIdx.x, w = t >> 6, l = t & 63;
    int col = ((w & 1) << 6) | l;           // 0..127 within q or k
    const float* W = (w >= 2) ? Wk_w : Wq_w;
    float4 wr[16];
    {
        const float4* Wrow = (const float4*)(W + col * 64);
        #pragma unroll
        for (int j = 0; j < 16; ++j) wr[j] = Wrow[j];
    }
    float bias = (w >= 2) ? Wk_b[col] : Wq_b[col];
    unsigned short* dst = (w >= 2) ? kq : q;

    __shared__ float xs[2][64];
    for (int n0 = blockIdx.x * 2; n0 < N; n0 += gridDim.x * 2) {
        __syncthreads();
        if (t < 128) {
            int nx = n0 + (t >> 6);
            xs[t >> 6][t & 63] = (nx < N) ? x[(size_t)nx * 64 + (t & 63)] : 0.f;
        }
        __syncthreads();
        #pragma unroll
        for (int s = 0; s < 2; ++s) {
            int n = n0 + s;
            if (n >= N) continue;
            const float4* xv = (const float4*)xs[s];
            float a0 = 0.f, a1 = 0.f, a2 = 0.f, a3 = 0.f;
            #pragma unroll
            for (int j = 0; j < 4; ++j) {
                float4 x0 = xv[j * 4 + 0], x1 = xv[j * 4 + 1];
                float4 x2 = xv[j * 4 + 2], x3 = xv[j * 4 + 3];
                float4 w0 = wr[j * 4 + 0], w1 = wr[j * 4 + 1];
                float4 w2 = wr[j * 4 + 2], w3 = wr[j * 4 + 3];
                a0 += x0.x * w0.x + x0.y * w0.y + x0.z * w0.z + x0.w * w0.w;
                a1 += x1.x * w1.x + x1.y * w1.y + x1.z * w1.z + x1.w * w1.w;
                a2 += x2.x * w2.x + x2.y * w2.y + x2.z * w2.z + x2.w * w2.w;
                a3 += x3.x * w3.x + x3.y * w3.y + x3.z * w3.z + x3.w * w3.w;
            }
            float v = a0 + a1 + a2 + a3 + bias;
            float ss = wave_reduce_sum(v * v);
            float o = v * rsqrtf(ss);
            dst[(size_t)n * 128 + col] = f2b_u(o);
        }
        {
            int nx = n0 + (w >> 1);
            if (nx < N) {
                unsigned short pb = f2b_u(xs[w >> 1][l]);
                size_t o = (size_t)nx * 128 + col;
                curA[o] = pb;
                acc[o] = pb;
            }
        }
    }
}

// ---- degree / dis ----------------------------------------------------------
__global__ void k_deg(const int* __restrict__ row, int* __restrict__ deg, int E) {
    int e = blockIdx.x * 256 + threadIdx.x;
    if (e < E) atomicAdd(&deg[row[e]], 1);
}

__global__ void k_dis(const int* __restrict__ deg, float* __restrict__ dis, int N) {
    int n = blockIdx.x * 256 + threadIdx.x;
    if (n < N) { int d = deg[n]; dis[n] = d > 0 ? rsqrtf((float)d) : 0.f; }
}

// ---- exclusive scan of deg -> rowstart -------------------------------------
__global__ void k_scan1(const int* __restrict__ deg, int* __restrict__ rowstart,
                        int* __restrict__ bsum, int N) {
    __shared__ int sh[256];
    int t = threadIdx.x, n = blockIdx.x * 256 + t;
    int v = (n < N) ? deg[n] : 0;
    sh[t] = v; __syncthreads();
    #pragma unroll
    for (int off = 1; off < 256; off <<= 1) {
        int add = (t >= off) ? sh[t - off] : 0;
        __syncthreads();
        sh[t] += add;
        __syncthreads();
    }
    if (n < N) rowstart[n] = sh[t] - v;
    if (t == 255) bsum[blockIdx.x] = sh[255];
}

__global__ void k_scan2(int* __restrict__ bsum, int nb) {
    __shared__ int sh[512];
    __shared__ int carry;
    int t = threadIdx.x;
    if (t == 0) carry = 0;
    __syncthreads();
    for (int base = 0; base < nb; base += 512) {
        int idx = base + t;
        int v = (idx < nb) ? bsum[idx] : 0;
        sh[t] = v; __syncthreads();
        for (int off = 1; off < 512; off <<= 1) {
            int add = (t >= off) ? sh[t - off] : 0;
            __syncthreads();
            sh[t] += add;
            __syncthreads();
        }
        if (idx < nb) bsum[idx] = sh[t] - v + carry;
        __syncthreads();
        if (t == 0) carry += sh[511];
        __syncthreads();
    }
}

__global__ void k_scan3(int* __restrict__ rowstart, const int* __restrict__ bsum, int N, int E) {
    int n = blockIdx.x * 256 + threadIdx.x;
    if (n < N) rowstart[n] += bsum[blockIdx.x];
    if (n == 0) rowstart[N] = E;
}

// ---- CSR fill (also packs edge attributes) ---------------------------------
__global__ void k_fill(const int* __restrict__ eidx, const float* __restrict__ dis,
                       const int* __restrict__ rowstart, int* __restrict__ cursor,
                       int* __restrict__ csr_col, float* __restrict__ csr_w,
                       int* __restrict__ csr_att, const int* __restrict__ eattr, int E) {
    int e = blockIdx.x * 256 + threadIdx.x;
    if (e >= E) return;
    int r = eidx[e], c = eidx[E + e];
    float wv = dis[r] * dis[c];
    int a0 = eattr[e * 3 + 0], a1 = eattr[e * 3 + 1], a2 = eattr[e * 3 + 2];
    int slot = atomicAdd(&cursor[r], 1);
    int idx = rowstart[r] + slot;
    csr_col[idx] = c; csr_w[idx] = wv; csr_att[idx] = a0 | (a1 << 8) | (a2 << 16);
}

// ---- msg_edge[n,64]; bond table in LDS, wave per node ----------------------
__global__ __launch_bounds__(256) void k_msg(
    const int* __restrict__ rowstart, const int* __restrict__ csr_att,
    const float* __restrict__ csr_w, const float* __restrict__ bond,
    float* __restrict__ msg, int N) {
    __shared__ float bl[1536];
    int t = threadIdx.x, w = t >> 6, l = t & 63;
    for (int i = t; i < 1536; i += 256) bl[i] = bond[i];
    __syncthreads();
    for (int n = blockIdx.x * 4 + w; n < N; n += gridDim.x * 4) {
        int s0 = rowstart[n], s1 = rowstart[n + 1];
        float m = 0.f;
        for (int i = s0; i < s1; ++i) {
            int att = csr_att[i];
            float wv = csr_w[i];
            m += wv * (bl[(att & 255) * 64 + l] + bl[(8 + ((att >> 8) & 255)) * 64 + l]
                     + bl[(16 + (att >> 16)) * 64 + l]);
        }
        msg[(size_t)n * 64 + l] = m;
    }
}

// ---- k_sum per graph (iteration-invariant) ---------------------------------
__global__ __launch_bounds__(128) void k_ksum(
    const unsigned short* __restrict__ kq, const int* __restrict__ batch,
    float* __restrict__ ksum, int N) {
    int t = threadIdx.x;
    int start = blockIdx.x * 256;
    if (start >= N) return;
    int curb = batch[start];
    float a = 0.f;
    for (int i = 0; i < 256; ++i) {
        int n = start + i;
        if (n >= N) break;
        int b = batch[n];
        if (b != curb) { atomicAdd(&ksum[curb * 128 + t], a); a = 0.f; curb = b; }
        a += b2f_u(kq[(size_t)n * 128 + t]);
    }
    atomicAdd(&ksum[curb * 128 + t], a);
}

// ---- denom[n][h] = q[n,h,:].ksum[b,h,:] + n_nodes[b] -----------------------
__global__ __launch_bounds__(256) void k_denom(
    const unsigned short* __restrict__ q, const float* __restrict__ ksum,
    const int* __restrict__ batch, const int* __restrict__ nn,
    float* __restrict__ denom, int N)
{
    int w = threadIdx.x >> 6, l = threadIdx.x & 63;
    int n = blockIdx.x * 4 + w;
    if (n >= N) return;
    int b = batch[n];
    float d0 = b2f_u(q[(size_t)n * 128 + l]) * ksum[b * 128 + l];
    float d1 = b2f_u(q[(size_t)n * 128 + 64 + l]) * ksum[b * 128 + 64 + l];
    d0 = wave_reduce_sum(d0);
    d1 = wave_reduce_sum(d1);
    if (l == 0) {
        float nf = (float)nn[b];
        denom[n * 2 + 0] = d0 + nf;
        denom[n * 2 + 1] = d1 + nf;
    }
}

// ---- stage 1: per-chunk partial kv (plain stores, no atomics) --------------
// Chunk cid belongs to exactly one graph (cptr-aligned). Wave = (h, dhalf).
__global__ __launch_bounds__(256) void k_kvp(
    const unsigned short* __restrict__ kq, const unsigned short* __restrict__ cur,
    const int* __restrict__ ptr, const int* __restrict__ cptr,
    float* __restrict__ partKV, float* __restrict__ partVS, int B)
{
    int cid = blockIdx.x;
    if (cid >= cptr[B]) return;
    // binary search: b with cptr[b] <= cid < cptr[b+1]
    int lo = 0, hi = B - 1;
    while (lo < hi) { int mid = (lo + hi + 1) >> 1; if (cptr[mid] <= cid) lo = mid; else hi = mid - 1; }
    int b = lo;
    int start = ptr[b] + (cid - cptr[b]) * CHUNK;
    int end = min(start + CHUNK, ptr[b + 1]);

    int w = threadIdx.x >> 6, l = threadIdx.x & 63;
    int h = w >> 1, dhalf = w & 1;
    int d0 = dhalf * 32 + (l & 7) * 4;
    int e0 = (l >> 3) * 8;
    float a[4][8], va[8];
    #pragma unroll
    for (int i = 0; i < 4; ++i)
        #pragma unroll
        for (int j = 0; j < 8; ++j) a[i][j] = 0.f;
    #pragma unroll
    for (int j = 0; j < 8; ++j) va[j] = 0.f;

    const unsigned short* kp = kq + (size_t)start * 128 + h * 64 + d0;
    const unsigned short* vp = cur + (size_t)start * 128 + h * 64 + e0;
    #pragma unroll 4
    for (int n = start; n < end; ++n) {
        uint2 ku = *(const uint2*)kp;
        uint4 vu = *(const uint4*)vp;
        kp += 128; vp += 128;
        float k0 = asf(ku.x << 16), k1 = asf(ku.x & 0xffff0000u);
        float k2 = asf(ku.y << 16), k3 = asf(ku.y & 0xffff0000u);
        float v[8];
        v[0] = asf(vu.x << 16); v[1] = asf(vu.x & 0xffff0000u);
        v[2] = asf(vu.y << 16); v[3] = asf(vu.y & 0xffff0000u);
        v[4] = asf(vu.z << 16); v[5] = asf(vu.z & 0xffff0000u);
        v[6] = asf(vu.w << 16); v[7] = asf(vu.w & 0xffff0000u);
        #pragma unroll
        for (int j = 0; j < 8; ++j) {
            a[0][j] += k0 * v[j]; a[1][j] += k1 * v[j];
            a[2][j] += k2 * v[j]; a[3][j] += k3 * v[j];
            va[j] += v[j];
        }
    }
    // coalesced partial store: kvT layout [e][d], lane's 4 d's contiguous
    float* dst = partKV + (size_t)cid * 8192 + h * 4096;
    #pragma unroll
    for (int j = 0; j < 8; ++j) {
        float4 s4 = { a[0][j], a[1][j], a[2][j], a[3][j] };
        *(float4*)(dst + (e0 + j) * 64 + d0) = s4;
    }
    if (dhalf == 0 && (l & 7) == 0) {
        float* vdst = partVS + (size_t)cid * 128 + h * 64 + e0;
        #pragma unroll
        for (int j = 0; j < 8; ++j) vdst[j] = va[j];
    }
}

// ---- stage 2: sum partials -> kvT bf16 + vsum ------------------------------
__global__ __launch_bounds__(256) void k_red(
    const float* __restrict__ partKV, const float* __restrict__ partVS,
    const int* __restrict__ cptr, unsigned short* __restrict__ kvT_b,
    float* __restrict__ vsum, int B)
{
    int gh = blockIdx.x, g = gh >> 1, h = gh & 1;
    int c0 = cptr[g], c1 = cptr[g + 1];
    int t = threadIdx.x;
    float s[16];
    #pragma unroll
    for (int i = 0; i < 16; ++i) s[i] = 0.f;
    for (int c = c0; c < c1; ++c) {
        const float4* src = (const float4*)(partKV + (size_t)c * 8192 + h * 4096 + t * 16);
        #pragma unroll
        for (int i = 0; i < 4; ++i) {
            float4 v = src[i];
            s[i * 4 + 0] += v.x; s[i * 4 + 1] += v.y; s[i * 4 + 2] += v.z; s[i * 4 + 3] += v.w;
        }
    }
    unsigned int u[8];
    #pragma unroll
    for (int i = 0; i < 8; ++i) u[i] = pack2(s[2 * i], s[2 * i + 1]);
    uint4* dst = (uint4*)(kvT_b + (size_t)gh * 4096 + t * 16);
    dst[0] = make_uint4(u[0], u[1], u[2], u[3]);
    dst[1] = make_uint4(u[4], u[5], u[6], u[7]);
    if (t < 64) {
        float vs = 0.f;
        for (int c = c0; c < c1; ++c) vs += partVS[(size_t)c * 128 + h * 64 + t];
        vsum[g * 128 + h * 64 + t] = vs;
    }
}

// ---- attn via MFMA: num[n,h,e] = sum_d q[n,h,d]*kvT[b,h,e,d]; write 0.5*attn
__global__ __launch_bounds__(256) void k_attn(
    const unsigned short* __restrict__ q, const unsigned short* __restrict__ kvT,
    const float* __restrict__ vsum, const float* __restrict__ denom,
    const int* __restrict__ batch, unsigned short* __restrict__ curB, int N)
{
    int w = threadIdx.x >> 6, l = threadIdx.x & 63;
    int base = blockIdx.x * 64 + w * 16;
    if (base >= N) return;
    int quad = l >> 4, six = l & 15;
    int b0 = batch[base];
    int nlast = min(base + 15, N - 1);
    bool uni = (base + 15 < N) && (batch[nlast] == b0);
    if (uni) {
        int n = base + six;
        #pragma unroll
        for (int h = 0; h < 2; ++h) {
            const unsigned short* qrow = q + (size_t)n * 128 + h * 64;
            bf16x8 a0 = *(const bf16x8*)(qrow + quad * 8);
            bf16x8 a1 = *(const bf16x8*)(qrow + 32 + quad * 8);
            const unsigned short* Bb = kvT + (size_t)(b0 * 2 + h) * 4096;
            f32x4v acc[4];
            #pragma unroll
            for (int et = 0; et < 4; ++et) {
                const unsigned short* brow = Bb + (size_t)(et * 16 + six) * 64;
                bf16x8 bb0 = *(const bf16x8*)(brow + quad * 8);
                bf16x8 bb1 = *(const bf16x8*)(brow + 32 + quad * 8);
                f32x4v c = {0.f, 0.f, 0.f, 0.f};
                c = __builtin_amdgcn_mfma_f32_16x16x32_bf16(a0, bb0, c, 0, 0, 0);
                c = __builtin_amdgcn_mfma_f32_16x16x32_bf16(a1, bb1, c, 0, 0, 0);
                acc[et] = c;
            }
            #pragma unroll
            for (int et = 0; et < 4; ++et) {
                int e = et * 16 + six;
                float vs = vsum[(b0 * 2 + h) * 64 + e];
                #pragma unroll
                for (int r = 0; r < 4; ++r) {
                    int nr = base + quad * 4 + r;
                    float dn = denom[nr * 2 + h];
                    float val = 0.5f * (acc[et][r] + vs) / dn;
                    curB[(size_t)nr * 128 + h * 64 + e] = f2b_u(val);
                }
            }
        }
    } else {
        for (int i = 0; i < 16; ++i) {
            int n = base + i;
            if (n >= N) break;
            int b = batch[n];
            #pragma unroll
            for (int h = 0; h < 2; ++h) {
                float num = 0.f;
                const unsigned short* krow = kvT + (size_t)((b * 2 + h) * 64 + l) * 64;
                for (int d = 0; d < 64; ++d)
                    num += b2f_u(q[(size_t)n * 128 + h * 64 + d]) * b2f_u(krow[d]);
                float val = 0.5f * (num + vsum[(b * 2 + h) * 64 + l]) / denom[n * 2 + h];
                curB[(size_t)n * 128 + h * 64 + l] = f2b_u(val);
            }
        }
    }
}

// ---- GCN gather + combine (wave per node) ----------------------------------
__global__ __launch_bounds__(256) void k_gcn(
    const unsigned short* __restrict__ curA, const float* __restrict__ msg,
    const int* __restrict__ rowstart, const int* __restrict__ csr_col,
    const float* __restrict__ csr_w,
    unsigned short* __restrict__ curB, unsigned short* __restrict__ acc, int N)
{
    int w = threadIdx.x >> 6, l = threadIdx.x & 63;
    int n = blockIdx.x * 4 + w;
    if (n >= N) return;
    int s0 = rowstart[n], s1 = rowstart[n + 1];
    float g0 = 0.f, g1 = 0.f;
    #pragma unroll 2
    for (int i = s0; i < s1; ++i) {
        int c = csr_col[i];
        float wv = csr_w[i];
        unsigned int u = *(const unsigned int*)(curA + (size_t)c * 128 + 2 * l);
        g0 += wv * asf(u << 16);
        g1 += wv * asf(u & 0xffff0000u);
    }
    float2 m = *(const float2*)(msg + (size_t)n * 64 + ((2 * l) & 63));
    size_t o = (size_t)n * 128 + 2 * l;
    unsigned int ub = *(const unsigned int*)(curB + o);
    float v0 = 0.5f * (g0 + m.x) + asf(ub << 16);
    float v1 = 0.5f * (g1 + m.y) + asf(ub & 0xffff0000u);
    *(unsigned int*)(curB + o) = pack2(v0, v1);
    unsigned int ua = *(const unsigned int*)(acc + o);
    *(unsigned int*)(acc + o) = pack2(asf(ua << 16) + v0, asf(ua & 0xffff0000u) + v1);
}

// ---- out = (acc @ Wo^T + b) / 2 -------------------------------------------
__global__ __launch_bounds__(256) void k_out(
    const unsigned short* __restrict__ acc, const float* __restrict__ Wo_w,
    const float* __restrict__ Wo_b, float* __restrict__ out, int N)
{
    __shared__ float wol[64 * 129];
    __shared__ float accl[512];
    int t = threadIdx.x;
    for (int idx = t; idx < 64 * 128; idx += 256) {
        int o = idx >> 7, c = idx & 127;
        wol[o * 129 + c] = Wo_w[idx];
    }
    float bias = Wo_b[t & 63];
    __syncthreads();
    int base = blockIdx.x * 64;
    for (int s = 0; s < 16; ++s) {
        int nb = base + s * 4;
        __syncthreads();
        for (int idx = t; idx < 512; idx += 256) {
            int r = idx >> 7, c = idx & 127;
            int n = nb + r;
            accl[idx] = (n < N) ? b2f_u(acc[(size_t)n * 128 + c]) : 0.f;
        }
        __syncthreads();
        int i = t >> 6, o = t & 63;
        int n = nb + i;
        if (n < N) {
            float s2 = 0.f;
            const float4* a4 = (const float4*)(accl + i * 128);
            #pragma unroll
            for (int c4 = 0; c4 < 32; ++c4) {
                float4 av = a4[c4];
                s2 += av.x * wol[o * 129 + c4 * 4 + 0] + av.y * wol[o * 129 + c4 * 4 + 1]
                    + av.z * wol[o * 129 + c4 * 4 + 2] + av.w * wol[o * 129 + c4 * 4 + 3];
            }
            out[n * 64 + o] = (s2 + bias) * 0.5f;
        }
    }
}

extern "C" void kernel_launch(void* const* d_in, const int* in_sizes, int n_in,
                              void* d_out, int out_size, void* d_ws, size_t ws_size,
                              hipStream_t stream) {
    const float* x    = (const float*)d_in[0];
    const float* Wq_w = (const float*)d_in[1];
    const float* Wq_b = (const float*)d_in[2];
    const float* Wk_w = (const float*)d_in[3];
    const float* Wk_b = (const float*)d_in[4];
    const float* Wo_w = (const float*)d_in[5];
    const float* Wo_b = (const float*)d_in[6];
    const float* bond = (const float*)d_in[7];
    const int*   eidx = (const int*)d_in[8];
    const int*   eattr= (const int*)d_in[9];
    const int*   nn   = (const int*)d_in[10];
    float* out = (float*)d_out;
    int N = in_sizes[0] / 64;
    int E = in_sizes[9] / 3;
    int B = in_sizes[10];

    char* p = (char*)d_ws;
    auto alloc = [&](size_t bytes) { char* r = p; p += (bytes + 255) & ~(size_t)255; return r; };
    unsigned short* q    = (unsigned short*)alloc((size_t)N * 128 * 2);
    unsigned short* kq   = (unsigned short*)alloc((size_t)N * 128 * 2);
    unsigned short* curA = (unsigned short*)alloc((size_t)N * 128 * 2);
    unsigned short* curB = (unsigned short*)alloc((size_t)N * 128 * 2);
    unsigned short* acc  = (unsigned short*)alloc((size_t)N * 128 * 2);
    int maxchunks = (N + CHUNK - 1) / CHUNK + B;     // upper bound on total chunks
    float* partKV = (float*)alloc((size_t)maxchunks * 8192 * 4);
    float* partVS = (float*)alloc((size_t)maxchunks * 128 * 4);
    unsigned short* kvT_b = (unsigned short*)alloc((size_t)B * 2 * 64 * 64 * 2);
    float* vsum  = (float*)alloc((size_t)B * 128 * 4);
    float* ksum  = (float*)alloc((size_t)B * 128 * 4);
    float* denom = (float*)alloc((size_t)N * 2 * 4);
    float* dis   = (float*)alloc((size_t)N * 4);
    int* deg     = (int*)alloc((size_t)N * 4);
    int* rowstart= (int*)alloc((size_t)(N + 1) * 4);
    int* cursor  = (int*)alloc((size_t)N * 4);
    int* csr_col = (int*)alloc((size_t)E * 4);
    float* csr_w = (float*)alloc((size_t)E * 4);
    int* csr_att = (int*)alloc((size_t)E * 4);
    int* batch   = (int*)alloc((size_t)N * 4);
    int* ptr     = (int*)alloc((size_t)(B + 1) * 4);
    int* cptr    = (int*)alloc((size_t)(B + 1) * 4);
    int nb = (N + 255) / 256;
    int* bsum    = (int*)alloc((size_t)nb * 4);
    float* msg   = out;   // [N,64] fp32 aliased onto d_out; k_out rewrites it last

    hipMemsetAsync(deg,    0, (size_t)N * 4, stream);
    hipMemsetAsync(cursor, 0, (size_t)N * 4, stream);
    hipMemsetAsync(ksum,   0, (size_t)B * 128 * 4, stream);

    k_ptr  <<<1, 64, 0, stream>>>(nn, ptr, cptr, B);
    k_batch<<<B, 256, 0, stream>>>(ptr, batch);
    k_qk   <<<2048, 256, 0, stream>>>(x, Wq_w, Wq_b, Wk_w, Wk_b, q, kq, curA, acc, N);
    k_deg  <<<(E + 255) / 256, 256, 0, stream>>>(eidx, deg, E);
    k_dis  <<<(N + 255) / 256, 256, 0, stream>>>(deg, dis, N);
    k_scan1<<<nb, 256, 0, stream>>>(deg, rowstart, bsum, N);
    k_scan2<<<1, 512, 0, stream>>>(bsum, nb);
    k_scan3<<<nb, 256, 0, stream>>>(rowstart, bsum, N, E);
    k_fill <<<(E + 255) / 256, 256, 0, stream>>>(eidx, dis, rowstart, cursor, csr_col, csr_w, csr_att, eattr, E);
    k_msg  <<<2048, 256, 0, stream>>>(rowstart, csr_att, csr_w, bond, msg, N);
    k_ksum <<<(N + 255) / 256, 128, 0, stream>>>(kq, batch, ksum, N);
    k_denom<<<(N + 3) / 4, 256, 0, stream>>>(q, ksum, batch, nn, denom, N);

    for (int it = 0; it < 4; ++it) {
        k_kvp <<<maxchunks, 256, 0, stream>>>(kq, curA, ptr, cptr, partKV, partVS, B);
        k_red <<<B * 2, 256, 0, stream>>>(partKV, partVS, cptr, kvT_b, vsum, B);
        k_attn<<<(N + 63) / 64, 256, 0, stream>>>(q, kvT_b, vsum, denom, batch, curB, N);
        k_gcn <<<(N + 3) / 4, 256, 0, stream>>>(curA, msg, rowstart, csr_col, csr_w, curB, acc, N);
        unsigned short* tmp = curA; curA = curB; curB = tmp;
    }
    k_out<<<(N + 63) / 64, 256, 0, stream>>>(acc, Wo_w, Wo_b, out, N);
}

// Round 7
// 1198.679 us; speedup vs baseline: 1.6332x; 1.0474x over previous
//
#include <hip/hip_runtime.h>
#include <hip/hip_bf16.h>

// GloAttnConv R7: q/k projection via MFMA (k_qkm; W bf16-stacked by k_wcvt),
// norm via quad-shfl reduce; acc init folded into k_gcn iter0 (first flag).

typedef __attribute__((ext_vector_type(8))) short bf16x8;
typedef __attribute__((ext_vector_type(4))) float f32x4v;

#define CHUNK 100

__device__ __forceinline__ float asf(unsigned int u) { union { unsigned int i; float f; } v; v.i = u; return v.f; }
__device__ __forceinline__ float b2f_u(unsigned short u) { return asf((unsigned int)u << 16); }
__device__ __forceinline__ unsigned short f2b_u(float f) {
    __hip_bfloat16 h = __float2bfloat16(f);
    union { __hip_bfloat16 h; unsigned short u; } v; v.h = h; return v.u;
}
__device__ __forceinline__ unsigned int pack2(float a, float b) {
    return (unsigned int)f2b_u(a) | ((unsigned int)f2b_u(b) << 16);
}
__device__ __forceinline__ float wave_reduce_sum(float v) {
    #pragma unroll
    for (int off = 32; off > 0; off >>= 1) v += __shfl_xor(v, off, 64);
    return v;
}

// ---- graph bookkeeping: node ptr + chunk ptr -------------------------------
__global__ void k_ptr(const int* __restrict__ nn, int* __restrict__ ptr,
                      int* __restrict__ cptr, int B) {
    if (threadIdx.x == 0 && blockIdx.x == 0) {
        int s = 0, c = 0; ptr[0] = 0; cptr[0] = 0;
        for (int i = 0; i < B; ++i) {
            s += nn[i]; ptr[i + 1] = s;
            c += (nn[i] + CHUNK - 1) / CHUNK; cptr[i + 1] = c;
        }
    }
}

__global__ void k_batch(const int* __restrict__ ptr, int* __restrict__ batch) {
    int b = blockIdx.x;
    int s = ptr[b], e = ptr[b + 1];
    for (int i = s + threadIdx.x; i < e; i += blockDim.x) batch[i] = b;
}

// ---- W -> bf16 stacked (rows 0..127 = Wq, 128..255 = Wk) -------------------
__global__ void k_wcvt(const float* __restrict__ Wq_w, const float* __restrict__ Wk_w,
                       unsigned short* __restrict__ Wb) {
    int i = blockIdx.x * 256 + threadIdx.x;
    if (i < 16384) Wb[i] = f2b_u(i < 8192 ? Wq_w[i] : Wk_w[i - 8192]);
}

// ---- q/k projection via MFMA + L2-normalize; writes q, kq, curA ------------
// Wave = one 16-node tile. A = Wb rows (outcols), B = x^T (nodes as cols).
__global__ __launch_bounds__(256) void k_qkm(
    const float* __restrict__ x, const unsigned short* __restrict__ Wb,
    const float* __restrict__ Wq_b, const float* __restrict__ Wk_b,
    unsigned short* __restrict__ q, unsigned short* __restrict__ kq,
    unsigned short* __restrict__ curA, int N)
{
    int w = threadIdx.x >> 6, l = threadIdx.x & 63;
    int six = l & 15, quad = l >> 4;
    int base = (blockIdx.x * 4 + w) * 16;
    if (base >= N) return;
    int n = base + six;
    int nc = min(n, N - 1);

    // B-fragments: lane holds x[node=six][k=quad*8+j] (k<32) and k>=32
    const float* xr = x + (size_t)nc * 64;
    float xv0[8], xv1[8];
    #pragma unroll
    for (int j = 0; j < 8; ++j) { xv0[j] = xr[quad * 8 + j]; xv1[j] = xr[32 + quad * 8 + j]; }
    union { bf16x8 v; unsigned int u[4]; } b0, b1;
    #pragma unroll
    for (int i = 0; i < 4; ++i) {
        b0.u[i] = pack2(xv0[2 * i], xv0[2 * i + 1]);
        b1.u[i] = pack2(xv1[2 * i], xv1[2 * i + 1]);
    }
    // curA init from registers (cols c and c+64 both = x[c])
    if (n < N) {
        unsigned short* cr = curA + (size_t)n * 128;
        *(uint4*)(cr + quad * 8)       = make_uint4(b0.u[0], b0.u[1], b0.u[2], b0.u[3]);
        *(uint4*)(cr + 32 + quad * 8)  = make_uint4(b1.u[0], b1.u[1], b1.u[2], b1.u[3]);
        *(uint4*)(cr + 64 + quad * 8)  = make_uint4(b0.u[0], b0.u[1], b0.u[2], b0.u[3]);
        *(uint4*)(cr + 96 + quad * 8)  = make_uint4(b1.u[0], b1.u[1], b1.u[2], b1.u[3]);
    }

    // groups g: 0 = q h0, 1 = q h1, 2 = k h0, 3 = k h1 (64 outcols each)
    #pragma unroll
    for (int g = 0; g < 4; ++g) {
        f32x4v c[4];
        #pragma unroll
        for (int tt = 0; tt < 4; ++tt) {
            int t = g * 4 + tt;
            const unsigned short* wr = Wb + (size_t)(t * 16 + six) * 64;
            bf16x8 a0 = *(const bf16x8*)(wr + quad * 8);
            bf16x8 a1 = *(const bf16x8*)(wr + 32 + quad * 8);
            f32x4v cc = {0.f, 0.f, 0.f, 0.f};
            cc = __builtin_amdgcn_mfma_f32_16x16x32_bf16(a0, b0.v, cc, 0, 0, 0);
            cc = __builtin_amdgcn_mfma_f32_16x16x32_bf16(a1, b1.v, cc, 0, 0, 0);
            c[tt] = cc;
        }
        const float* bias = (g < 2) ? Wq_b : Wk_b;
        int cb = (g & 1) * 64 + quad * 4;
        float ss = 0.f;
        #pragma unroll
        for (int tt = 0; tt < 4; ++tt)
            #pragma unroll
            for (int r = 0; r < 4; ++r) {
                float v = c[tt][r] + bias[cb + tt * 16 + r];
                c[tt][r] = v;
                ss += v * v;
            }
        ss += __shfl_xor(ss, 16, 64);
        ss += __shfl_xor(ss, 32, 64);
        float sc = rsqrtf(ss);
        if (n < N) {
            unsigned short* dst = ((g < 2) ? q : kq) + (size_t)n * 128;
            #pragma unroll
            for (int tt = 0; tt < 4; ++tt) {
                unsigned int u0 = pack2(c[tt][0] * sc, c[tt][1] * sc);
                unsigned int u1 = pack2(c[tt][2] * sc, c[tt][3] * sc);
                *(uint2*)(dst + cb + tt * 16) = make_uint2(u0, u1);
            }
        }
    }
}

// ---- degree / dis ----------------------------------------------------------
__global__ void k_deg(const int* __restrict__ row, int* __restrict__ deg, int E) {
    int e = blockIdx.x * 256 + threadIdx.x;
    if (e < E) atomicAdd(&deg[row[e]], 1);
}

__global__ void k_dis(const int* __restrict__ deg, float* __restrict__ dis, int N) {
    int n = blockIdx.x * 256 + threadIdx.x;
    if (n < N) { int d = deg[n]; dis[n] = d > 0 ? rsqrtf((float)d) : 0.f; }
}

// ---- exclusive scan of deg -> rowstart -------------------------------------
__global__ void k_scan1(const int* __restrict__ deg, int* __restrict__ rowstart,
                        int* __restrict__ bsum, int N) {
    __shared__ int sh[256];
    int t = threadIdx.x, n = blockIdx.x * 256 + t;
    int v = (n < N) ? deg[n] : 0;
    sh[t] = v; __syncthreads();
    #pragma unroll
    for (int off = 1; off < 256; off <<= 1) {
        int add = (t >= off) ? sh[t - off] : 0;
        __syncthreads();
        sh[t] += add;
        __syncthreads();
    }
    if (n < N) rowstart[n] = sh[t] - v;
    if (t == 255) bsum[blockIdx.x] = sh[255];
}

__global__ void k_scan2(int* __restrict__ bsum, int nb) {
    __shared__ int sh[512];
    __shared__ int carry;
    int t = threadIdx.x;
    if (t == 0) carry = 0;
    __syncthreads();
    for (int base = 0; base < nb; base += 512) {
        int idx = base + t;
        int v = (idx < nb) ? bsum[idx] : 0;
        sh[t] = v; __syncthreads();
        for (int off = 1; off < 512; off <<= 1) {
            int add = (t >= off) ? sh[t - off] : 0;
            __syncthreads();
            sh[t] += add;
            __syncthreads();
        }
        if (idx < nb) bsum[idx] = sh[t] - v + carry;
        __syncthreads();
        if (t == 0) carry += sh[511];
        __syncthreads();
    }
}

__global__ void k_scan3(int* __restrict__ rowstart, const int* __restrict__ bsum, int N, int E) {
    int n = blockIdx.x * 256 + threadIdx.x;
    if (n < N) rowstart[n] += bsum[blockIdx.x];
    if (n == 0) rowstart[N] = E;
}

// ---- CSR fill (also packs edge attributes) ---------------------------------
__global__ void k_fill(const int* __restrict__ eidx, const float* __restrict__ dis,
                       const int* __restrict__ rowstart, int* __restrict__ cursor,
                       int* __restrict__ csr_col, float* __restrict__ csr_w,
                       int* __restrict__ csr_att, const int* __restrict__ eattr, int E) {
    int e = blockIdx.x * 256 + threadIdx.x;
    if (e >= E) return;
    int r = eidx[e], c = eidx[E + e];
    float wv = dis[r] * dis[c];
    int a0 = eattr[e * 3 + 0], a1 = eattr[e * 3 + 1], a2 = eattr[e * 3 + 2];
    int slot = atomicAdd(&cursor[r], 1);
    int idx = rowstart[r] + slot;
    csr_col[idx] = c; csr_w[idx] = wv; csr_att[idx] = a0 | (a1 << 8) | (a2 << 16);
}

// ---- msg_edge[n,64]; bond table in LDS, wave per node ----------------------
__global__ __launch_bounds__(256) void k_msg(
    const int* __restrict__ rowstart, const int* __restrict__ csr_att,
    const float* __restrict__ csr_w, const float* __restrict__ bond,
    float* __restrict__ msg, int N) {
    __shared__ float bl[1536];
    int t = threadIdx.x, w = t >> 6, l = t & 63;
    for (int i = t; i < 1536; i += 256) bl[i] = bond[i];
    __syncthreads();
    for (int n = blockIdx.x * 4 + w; n < N; n += gridDim.x * 4) {
        int s0 = rowstart[n], s1 = rowstart[n + 1];
        float m = 0.f;
        for (int i = s0; i < s1; ++i) {
            int att = csr_att[i];
            float wv = csr_w[i];
            m += wv * (bl[(att & 255) * 64 + l] + bl[(8 + ((att >> 8) & 255)) * 64 + l]
                     + bl[(16 + (att >> 16)) * 64 + l]);
        }
        msg[(size_t)n * 64 + l] = m;
    }
}

// ---- k_sum per graph (iteration-invariant) ---------------------------------
__global__ __launch_bounds__(128) void k_ksum(
    const unsigned short* __restrict__ kq, const int* __restrict__ batch,
    float* __restrict__ ksum, int N) {
    int t = threadIdx.x;
    int start = blockIdx.x * 256;
    if (start >= N) return;
    int curb = batch[start];
    float a = 0.f;
    for (int i = 0; i < 256; ++i) {
        int n = start + i;
        if (n >= N) break;
        int b = batch[n];
        if (b != curb) { atomicAdd(&ksum[curb * 128 + t], a); a = 0.f; curb = b; }
        a += b2f_u(kq[(size_t)n * 128 + t]);
    }
    atomicAdd(&ksum[curb * 128 + t], a);
}

// ---- denom[n][h] = q[n,h,:].ksum[b,h,:] + n_nodes[b] -----------------------
__global__ __launch_bounds__(256) void k_denom(
    const unsigned short* __restrict__ q, const float* __restrict__ ksum,
    const int* __restrict__ batch, const int* __restrict__ nn,
    float* __restrict__ denom, int N)
{
    int w = threadIdx.x >> 6, l = threadIdx.x & 63;
    int n = blockIdx.x * 4 + w;
    if (n >= N) return;
    int b = batch[n];
    float d0 = b2f_u(q[(size_t)n * 128 + l]) * ksum[b * 128 + l];
    float d1 = b2f_u(q[(size_t)n * 128 + 64 + l]) * ksum[b * 128 + 64 + l];
    d0 = wave_reduce_sum(d0);
    d1 = wave_reduce_sum(d1);
    if (l == 0) {
        float nf = (float)nn[b];
        denom[n * 2 + 0] = d0 + nf;
        denom[n * 2 + 1] = d1 + nf;
    }
}

// ---- stage 1: per-chunk partial kv (plain stores, no atomics) --------------
__global__ __launch_bounds__(256) void k_kvp(
    const unsigned short* __restrict__ kq, const unsigned short* __restrict__ cur,
    const int* __restrict__ ptr, const int* __restrict__ cptr,
    float* __restrict__ partKV, float* __restrict__ partVS, int B)
{
    int cid = blockIdx.x;
    if (cid >= cptr[B]) return;
    int lo = 0, hi = B - 1;
    while (lo < hi) { int mid = (lo + hi + 1) >> 1; if (cptr[mid] <= cid) lo = mid; else hi = mid - 1; }
    int b = lo;
    int start = ptr[b] + (cid - cptr[b]) * CHUNK;
    int end = min(start + CHUNK, ptr[b + 1]);

    int w = threadIdx.x >> 6, l = threadIdx.x & 63;
    int h = w >> 1, dhalf = w & 1;
    int d0 = dhalf * 32 + (l & 7) * 4;
    int e0 = (l >> 3) * 8;
    float a[4][8], va[8];
    #pragma unroll
    for (int i = 0; i < 4; ++i)
        #pragma unroll
        for (int j = 0; j < 8; ++j) a[i][j] = 0.f;
    #pragma unroll
    for (int j = 0; j < 8; ++j) va[j] = 0.f;

    const unsigned short* kp = kq + (size_t)start * 128 + h * 64 + d0;
    const unsigned short* vp = cur + (size_t)start * 128 + h * 64 + e0;
    #pragma unroll 4
    for (int n = start; n < end; ++n) {
        uint2 ku = *(const uint2*)kp;
        uint4 vu = *(const uint4*)vp;
        kp += 128; vp += 128;
        float k0 = asf(ku.x << 16), k1 = asf(ku.x & 0xffff0000u);
        float k2 = asf(ku.y << 16), k3 = asf(ku.y & 0xffff0000u);
        float v[8];
        v[0] = asf(vu.x << 16); v[1] = asf(vu.x & 0xffff0000u);
        v[2] = asf(vu.y << 16); v[3] = asf(vu.y & 0xffff0000u);
        v[4] = asf(vu.z << 16); v[5] = asf(vu.z & 0xffff0000u);
        v[6] = asf(vu.w << 16); v[7] = asf(vu.w & 0xffff0000u);
        #pragma unroll
        for (int j = 0; j < 8; ++j) {
            a[0][j] += k0 * v[j]; a[1][j] += k1 * v[j];
            a[2][j] += k2 * v[j]; a[3][j] += k3 * v[j];
            va[j] += v[j];
        }
    }
    float* dst = partKV + (size_t)cid * 8192 + h * 4096;
    #pragma unroll
    for (int j = 0; j < 8; ++j) {
        float4 s4 = { a[0][j], a[1][j], a[2][j], a[3][j] };
        *(float4*)(dst + (e0 + j) * 64 + d0) = s4;
    }
    if (dhalf == 0 && (l & 7) == 0) {
        float* vdst = partVS + (size_t)cid * 128 + h * 64 + e0;
        #pragma unroll
        for (int j = 0; j < 8; ++j) vdst[j] = va[j];
    }
}

// ---- stage 2: sum partials -> kvT bf16 + vsum ------------------------------
__global__ __launch_bounds__(256) void k_red(
    const float* __restrict__ partKV, const float* __restrict__ partVS,
    const int* __restrict__ cptr, unsigned short* __restrict__ kvT_b,
    float* __restrict__ vsum, int B)
{
    int gh = blockIdx.x, g = gh >> 1, h = gh & 1;
    int c0 = cptr[g], c1 = cptr[g + 1];
    int t = threadIdx.x;
    float s[16];
    #pragma unroll
    for (int i = 0; i < 16; ++i) s[i] = 0.f;
    for (int c = c0; c < c1; ++c) {
        const float4* src = (const float4*)(partKV + (size_t)c * 8192 + h * 4096 + t * 16);
        #pragma unroll
        for (int i = 0; i < 4; ++i) {
            float4 v = src[i];
            s[i * 4 + 0] += v.x; s[i * 4 + 1] += v.y; s[i * 4 + 2] += v.z; s[i * 4 + 3] += v.w;
        }
    }
    unsigned int u[8];
    #pragma unroll
    for (int i = 0; i < 8; ++i) u[i] = pack2(s[2 * i], s[2 * i + 1]);
    uint4* dst = (uint4*)(kvT_b + (size_t)gh * 4096 + t * 16);
    dst[0] = make_uint4(u[0], u[1], u[2], u[3]);
    dst[1] = make_uint4(u[4], u[5], u[6], u[7]);
    if (t < 64) {
        float vs = 0.f;
        for (int c = c0; c < c1; ++c) vs += partVS[(size_t)c * 128 + h * 64 + t];
        vsum[g * 128 + h * 64 + t] = vs;
    }
}

// ---- attn via MFMA: num[n,h,e] = sum_d q[n,h,d]*kvT[b,h,e,d]; write 0.5*attn
__global__ __launch_bounds__(256) void k_attn(
    const unsigned short* __restrict__ q, const unsigned short* __restrict__ kvT,
    const float* __restrict__ vsum, const float* __restrict__ denom,
    const int* __restrict__ batch, unsigned short* __restrict__ curB, int N)
{
    int w = threadIdx.x >> 6, l = threadIdx.x & 63;
    int base = blockIdx.x * 64 + w * 16;
    if (base >= N) return;
    int quad = l >> 4, six = l & 15;
    int b0 = batch[base];
    int nlast = min(base + 15, N - 1);
    bool uni = (base + 15 < N) && (batch[nlast] == b0);
    if (uni) {
        int n = base + six;
        #pragma unroll
        for (int h = 0; h < 2; ++h) {
            const unsigned short* qrow = q + (size_t)n * 128 + h * 64;
            bf16x8 a0 = *(const bf16x8*)(qrow + quad * 8);
            bf16x8 a1 = *(const bf16x8*)(qrow + 32 + quad * 8);
            const unsigned short* Bb = kvT + (size_t)(b0 * 2 + h) * 4096;
            f32x4v acc[4];
            #pragma unroll
            for (int et = 0; et < 4; ++et) {
                const unsigned short* brow = Bb + (size_t)(et * 16 + six) * 64;
                bf16x8 bb0 = *(const bf16x8*)(brow + quad * 8);
                bf16x8 bb1 = *(const bf16x8*)(brow + 32 + quad * 8);
                f32x4v c = {0.f, 0.f, 0.f, 0.f};
                c = __builtin_amdgcn_mfma_f32_16x16x32_bf16(a0, bb0, c, 0, 0, 0);
                c = __builtin_amdgcn_mfma_f32_16x16x32_bf16(a1, bb1, c, 0, 0, 0);
                acc[et] = c;
            }
            #pragma unroll
            for (int et = 0; et < 4; ++et) {
                int e = et * 16 + six;
                float vs = vsum[(b0 * 2 + h) * 64 + e];
                #pragma unroll
                for (int r = 0; r < 4; ++r) {
                    int nr = base + quad * 4 + r;
                    float dn = denom[nr * 2 + h];
                    float val = 0.5f * (acc[et][r] + vs) / dn;
                    curB[(size_t)nr * 128 + h * 64 + e] = f2b_u(val);
                }
            }
        }
    } else {
        for (int i = 0; i < 16; ++i) {
            int n = base + i;
            if (n >= N) break;
            int b = batch[n];
            #pragma unroll
            for (int h = 0; h < 2; ++h) {
                float num = 0.f;
                const unsigned short* krow = kvT + (size_t)((b * 2 + h) * 64 + l) * 64;
                for (int d = 0; d < 64; ++d)
                    num += b2f_u(q[(size_t)n * 128 + h * 64 + d]) * b2f_u(krow[d]);
                float val = 0.5f * (num + vsum[(b * 2 + h) * 64 + l]) / denom[n * 2 + h];
                curB[(size_t)n * 128 + h * 64 + l] = f2b_u(val);
            }
        }
    }
}

// ---- GCN gather + combine (wave per node). first=1: acc base = curA row ----
__global__ __launch_bounds__(256) void k_gcn(
    const unsigned short* __restrict__ curA, const float* __restrict__ msg,
    const int* __restrict__ rowstart, const int* __restrict__ csr_col,
    const float* __restrict__ csr_w,
    unsigned short* __restrict__ curB, unsigned short* __restrict__ acc, int N, int first)
{
    int w = threadIdx.x >> 6, l = threadIdx.x & 63;
    int n = blockIdx.x * 4 + w;
    if (n >= N) return;
    int s0 = rowstart[n], s1 = rowstart[n + 1];
    float g0 = 0.f, g1 = 0.f;
    #pragma unroll 2
    for (int i = s0; i < s1; ++i) {
        int c = csr_col[i];
        float wv = csr_w[i];
        unsigned int u = *(const unsigned int*)(curA + (size_t)c * 128 + 2 * l);
        g0 += wv * asf(u << 16);
        g1 += wv * asf(u & 0xffff0000u);
    }
    float2 m = *(const float2*)(msg + (size_t)n * 64 + ((2 * l) & 63));
    size_t o = (size_t)n * 128 + 2 * l;
    unsigned int ub = *(const unsigned int*)(curB + o);
    float v0 = 0.5f * (g0 + m.x) + asf(ub << 16);
    float v1 = 0.5f * (g1 + m.y) + asf(ub & 0xffff0000u);
    *(unsigned int*)(curB + o) = pack2(v0, v1);
    unsigned int ua = *(const unsigned int*)(first ? (curA + o) : (acc + o));
    *(unsigned int*)(acc + o) = pack2(asf(ua << 16) + v0, asf(ua & 0xffff0000u) + v1);
}

// ---- out = (acc @ Wo^T + b) / 2 -------------------------------------------
__global__ __launch_bounds__(256) void k_out(
    const unsigned short* __restrict__ acc, const float* __restrict__ Wo_w,
    const float* __restrict__ Wo_b, float* __restrict__ out, int N)
{
    __shared__ float wol[64 * 129];
    __shared__ float accl[512];
    int t = threadIdx.x;
    for (int idx = t; idx < 64 * 128; idx += 256) {
        int o = idx >> 7, c = idx & 127;
        wol[o * 129 + c] = Wo_w[idx];
    }
    float bias = Wo_b[t & 63];
    __syncthreads();
    int base = blockIdx.x * 64;
    for (int s = 0; s < 16; ++s) {
        int nb = base + s * 4;
        __syncthreads();
        for (int idx = t; idx < 512; idx += 256) {
            int r = idx >> 7, c = idx & 127;
            int n = nb + r;
            accl[idx] = (n < N) ? b2f_u(acc[(size_t)n * 128 + c]) : 0.f;
        }
        __syncthreads();
        int i = t >> 6, o = t & 63;
        int n = nb + i;
        if (n < N) {
            float s2 = 0.f;
            const float4* a4 = (const float4*)(accl + i * 128);
            #pragma unroll
            for (int c4 = 0; c4 < 32; ++c4) {
                float4 av = a4[c4];
                s2 += av.x * wol[o * 129 + c4 * 4 + 0] + av.y * wol[o * 129 + c4 * 4 + 1]
                    + av.z * wol[o * 129 + c4 * 4 + 2] + av.w * wol[o * 129 + c4 * 4 + 3];
            }
            out[n * 64 + o] = (s2 + bias) * 0.5f;
        }
    }
}

extern "C" void kernel_launch(void* const* d_in, const int* in_sizes, int n_in,
                              void* d_out, int out_size, void* d_ws, size_t ws_size,
                              hipStream_t stream) {
    const float* x    = (const float*)d_in[0];
    const float* Wq_w = (const float*)d_in[1];
    const float* Wq_b = (const float*)d_in[2];
    const float* Wk_w = (const float*)d_in[3];
    const float* Wk_b = (const float*)d_in[4];
    const float* Wo_w = (const float*)d_in[5];
    const float* Wo_b = (const float*)d_in[6];
    const float* bond = (const float*)d_in[7];
    const int*   eidx = (const int*)d_in[8];
    const int*   eattr= (const int*)d_in[9];
    const int*   nn   = (const int*)d_in[10];
    float* out = (float*)d_out;
    int N = in_sizes[0] / 64;
    int E = in_sizes[9] / 3;
    int B = in_sizes[10];

    char* p = (char*)d_ws;
    auto alloc = [&](size_t bytes) { char* r = p; p += (bytes + 255) & ~(size_t)255; return r; };
    unsigned short* q    = (unsigned short*)alloc((size_t)N * 128 * 2);
    unsigned short* kq   = (unsigned short*)alloc((size_t)N * 128 * 2);
    unsigned short* curA = (unsigned short*)alloc((size_t)N * 128 * 2);
    unsigned short* curB = (unsigned short*)alloc((size_t)N * 128 * 2);
    unsigned short* acc  = (unsigned short*)alloc((size_t)N * 128 * 2);
    int maxchunks = (N + CHUNK - 1) / CHUNK + B;
    float* partKV = (float*)alloc((size_t)maxchunks * 8192 * 4);
    float* partVS = (float*)alloc((size_t)maxchunks * 128 * 4);
    unsigned short* kvT_b = (unsigned short*)alloc((size_t)B * 2 * 64 * 64 * 2);
    float* vsum  = (float*)alloc((size_t)B * 128 * 4);
    float* ksum  = (float*)alloc((size_t)B * 128 * 4);
    float* denom = (float*)alloc((size_t)N * 2 * 4);
    float* dis   = (float*)alloc((size_t)N * 4);
    int* deg     = (int*)alloc((size_t)N * 4);
    int* rowstart= (int*)alloc((size_t)(N + 1) * 4);
    int* cursor  = (int*)alloc((size_t)N * 4);
    int* csr_col = (int*)alloc((size_t)E * 4);
    float* csr_w = (float*)alloc((size_t)E * 4);
    int* csr_att = (int*)alloc((size_t)E * 4);
    int* batch   = (int*)alloc((size_t)N * 4);
    int* ptr     = (int*)alloc((size_t)(B + 1) * 4);
    int* cptr    = (int*)alloc((size_t)(B + 1) * 4);
    unsigned short* Wb = (unsigned short*)alloc(16384 * 2);
    int nb = (N + 255) / 256;
    int* bsum    = (int*)alloc((size_t)nb * 4);
    float* msg   = out;   // [N,64] fp32 aliased onto d_out; k_out rewrites it last

    hipMemsetAsync(deg,    0, (size_t)N * 4, stream);
    hipMemsetAsync(cursor, 0, (size_t)N * 4, stream);
    hipMemsetAsync(ksum,   0, (size_t)B * 128 * 4, stream);

    k_ptr  <<<1, 64, 0, stream>>>(nn, ptr, cptr, B);
    k_batch<<<B, 256, 0, stream>>>(ptr, batch);
    k_wcvt <<<64, 256, 0, stream>>>(Wq_w, Wk_w, Wb);
    k_qkm  <<<(N + 63) / 64, 256, 0, stream>>>(x, Wb, Wq_b, Wk_b, q, kq, curA, N);
    k_deg  <<<(E + 255) / 256, 256, 0, stream>>>(eidx, deg, E);
    k_dis  <<<(N + 255) / 256, 256, 0, stream>>>(deg, dis, N);
    k_scan1<<<nb, 256, 0, stream>>>(deg, rowstart, bsum, N);
    k_scan2<<<1, 512, 0, stream>>>(bsum, nb);
    k_scan3<<<nb, 256, 0, stream>>>(rowstart, bsum, N, E);
    k_fill <<<(E + 255) / 256, 256, 0, stream>>>(eidx, dis, rowstart, cursor, csr_col, csr_w, csr_att, eattr, E);
    k_msg  <<<2048, 256, 0, stream>>>(rowstart, csr_att, csr_w, bond, msg, N);
    k_ksum <<<(N + 255) / 256, 128, 0, stream>>>(kq, batch, ksum, N);
    k_denom<<<(N + 3) / 4, 256, 0, stream>>>(q, ksum, batch, nn, denom, N);

    for (int it = 0; it < 4; ++it) {
        k_kvp <<<maxchunks, 256, 0, stream>>>(kq, curA, ptr, cptr, partKV, partVS, B);
        k_red <<<B * 2, 256, 0, stream>>>(partKV, partVS, cptr, kvT_b, vsum, B);
        k_attn<<<(N + 63) / 64, 256, 0, stream>>>(q, kvT_b, vsum, denom, batch, curB, N);
        k_gcn <<<(N + 3) / 4, 256, 0, stream>>>(curA, msg, rowstart, csr_col, csr_w, curB, acc, N, it == 0 ? 1 : 0);
        unsigned short* tmp = curA; curA = curB; curB = tmp;
    }
    k_out<<<(N + 63) / 64, 256, 0, stream>>>(acc, Wo_w, Wo_b, out, N);
}

// Round 8
// 1135.332 us; speedup vs baseline: 1.7243x; 1.0558x over previous
//
#include <hip/hip_runtime.h>
#include <hip/hip_bf16.h>

// GloAttnConv R8: k_out -> MFMA epilogue (k_outm) using the validated fragment
// convention; Wo packed bf16 into the existing k_wcvt. No LDS, no barriers.

typedef __attribute__((ext_vector_type(8))) short bf16x8;
typedef __attribute__((ext_vector_type(4))) float f32x4v;

#define CHUNK 100

__device__ __forceinline__ float asf(unsigned int u) { union { unsigned int i; float f; } v; v.i = u; return v.f; }
__device__ __forceinline__ float b2f_u(unsigned short u) { return asf((unsigned int)u << 16); }
__device__ __forceinline__ unsigned short f2b_u(float f) {
    __hip_bfloat16 h = __float2bfloat16(f);
    union { __hip_bfloat16 h; unsigned short u; } v; v.h = h; return v.u;
}
__device__ __forceinline__ unsigned int pack2(float a, float b) {
    return (unsigned int)f2b_u(a) | ((unsigned int)f2b_u(b) << 16);
}
__device__ __forceinline__ float wave_reduce_sum(float v) {
    #pragma unroll
    for (int off = 32; off > 0; off >>= 1) v += __shfl_xor(v, off, 64);
    return v;
}

// ---- graph bookkeeping: node ptr + chunk ptr -------------------------------
__global__ void k_ptr(const int* __restrict__ nn, int* __restrict__ ptr,
                      int* __restrict__ cptr, int B) {
    if (threadIdx.x == 0 && blockIdx.x == 0) {
        int s = 0, c = 0; ptr[0] = 0; cptr[0] = 0;
        for (int i = 0; i < B; ++i) {
            s += nn[i]; ptr[i + 1] = s;
            c += (nn[i] + CHUNK - 1) / CHUNK; cptr[i + 1] = c;
        }
    }
}

__global__ void k_batch(const int* __restrict__ ptr, int* __restrict__ batch) {
    int b = blockIdx.x;
    int s = ptr[b], e = ptr[b + 1];
    for (int i = s + threadIdx.x; i < e; i += blockDim.x) batch[i] = b;
}

// ---- W -> bf16 stacked: [0,8192)=Wq, [8192,16384)=Wk, [16384,24576)=Wo ------
__global__ void k_wcvt(const float* __restrict__ Wq_w, const float* __restrict__ Wk_w,
                       const float* __restrict__ Wo_w, unsigned short* __restrict__ Wb) {
    int i = blockIdx.x * 256 + threadIdx.x;
    if (i < 24576) {
        float v = (i < 8192) ? Wq_w[i] : ((i < 16384) ? Wk_w[i - 8192] : Wo_w[i - 16384]);
        Wb[i] = f2b_u(v);
    }
}

// ---- q/k projection via MFMA + L2-normalize; writes q, kq, curA ------------
__global__ __launch_bounds__(256) void k_qkm(
    const float* __restrict__ x, const unsigned short* __restrict__ Wb,
    const float* __restrict__ Wq_b, const float* __restrict__ Wk_b,
    unsigned short* __restrict__ q, unsigned short* __restrict__ kq,
    unsigned short* __restrict__ curA, int N)
{
    int w = threadIdx.x >> 6, l = threadIdx.x & 63;
    int six = l & 15, quad = l >> 4;
    int base = (blockIdx.x * 4 + w) * 16;
    if (base >= N) return;
    int n = base + six;
    int nc = min(n, N - 1);

    const float* xr = x + (size_t)nc * 64;
    float xv0[8], xv1[8];
    #pragma unroll
    for (int j = 0; j < 8; ++j) { xv0[j] = xr[quad * 8 + j]; xv1[j] = xr[32 + quad * 8 + j]; }
    union { bf16x8 v; unsigned int u[4]; } b0, b1;
    #pragma unroll
    for (int i = 0; i < 4; ++i) {
        b0.u[i] = pack2(xv0[2 * i], xv0[2 * i + 1]);
        b1.u[i] = pack2(xv1[2 * i], xv1[2 * i + 1]);
    }
    if (n < N) {
        unsigned short* cr = curA + (size_t)n * 128;
        *(uint4*)(cr + quad * 8)       = make_uint4(b0.u[0], b0.u[1], b0.u[2], b0.u[3]);
        *(uint4*)(cr + 32 + quad * 8)  = make_uint4(b1.u[0], b1.u[1], b1.u[2], b1.u[3]);
        *(uint4*)(cr + 64 + quad * 8)  = make_uint4(b0.u[0], b0.u[1], b0.u[2], b0.u[3]);
        *(uint4*)(cr + 96 + quad * 8)  = make_uint4(b1.u[0], b1.u[1], b1.u[2], b1.u[3]);
    }

    #pragma unroll
    for (int g = 0; g < 4; ++g) {
        f32x4v c[4];
        #pragma unroll
        for (int tt = 0; tt < 4; ++tt) {
            int t = g * 4 + tt;
            const unsigned short* wr = Wb + (size_t)(t * 16 + six) * 64;
            bf16x8 a0 = *(const bf16x8*)(wr + quad * 8);
            bf16x8 a1 = *(const bf16x8*)(wr + 32 + quad * 8);
            f32x4v cc = {0.f, 0.f, 0.f, 0.f};
            cc = __builtin_amdgcn_mfma_f32_16x16x32_bf16(a0, b0.v, cc, 0, 0, 0);
            cc = __builtin_amdgcn_mfma_f32_16x16x32_bf16(a1, b1.v, cc, 0, 0, 0);
            c[tt] = cc;
        }
        const float* bias = (g < 2) ? Wq_b : Wk_b;
        int cb = (g & 1) * 64 + quad * 4;
        float ss = 0.f;
        #pragma unroll
        for (int tt = 0; tt < 4; ++tt)
            #pragma unroll
            for (int r = 0; r < 4; ++r) {
                float v = c[tt][r] + bias[cb + tt * 16 + r];
                c[tt][r] = v;
                ss += v * v;
            }
        ss += __shfl_xor(ss, 16, 64);
        ss += __shfl_xor(ss, 32, 64);
        float sc = rsqrtf(ss);
        if (n < N) {
            unsigned short* dst = ((g < 2) ? q : kq) + (size_t)n * 128;
            #pragma unroll
            for (int tt = 0; tt < 4; ++tt) {
                unsigned int u0 = pack2(c[tt][0] * sc, c[tt][1] * sc);
                unsigned int u1 = pack2(c[tt][2] * sc, c[tt][3] * sc);
                *(uint2*)(dst + cb + tt * 16) = make_uint2(u0, u1);
            }
        }
    }
}

// ---- degree / dis ----------------------------------------------------------
__global__ void k_deg(const int* __restrict__ row, int* __restrict__ deg, int E) {
    int e = blockIdx.x * 256 + threadIdx.x;
    if (e < E) atomicAdd(&deg[row[e]], 1);
}

__global__ void k_dis(const int* __restrict__ deg, float* __restrict__ dis, int N) {
    int n = blockIdx.x * 256 + threadIdx.x;
    if (n < N) { int d = deg[n]; dis[n] = d > 0 ? rsqrtf((float)d) : 0.f; }
}

// ---- exclusive scan of deg -> rowstart -------------------------------------
__global__ void k_scan1(const int* __restrict__ deg, int* __restrict__ rowstart,
                        int* __restrict__ bsum, int N) {
    __shared__ int sh[256];
    int t = threadIdx.x, n = blockIdx.x * 256 + t;
    int v = (n < N) ? deg[n] : 0;
    sh[t] = v; __syncthreads();
    #pragma unroll
    for (int off = 1; off < 256; off <<= 1) {
        int add = (t >= off) ? sh[t - off] : 0;
        __syncthreads();
        sh[t] += add;
        __syncthreads();
    }
    if (n < N) rowstart[n] = sh[t] - v;
    if (t == 255) bsum[blockIdx.x] = sh[255];
}

__global__ void k_scan2(int* __restrict__ bsum, int nb) {
    __shared__ int sh[512];
    __shared__ int carry;
    int t = threadIdx.x;
    if (t == 0) carry = 0;
    __syncthreads();
    for (int base = 0; base < nb; base += 512) {
        int idx = base + t;
        int v = (idx < nb) ? bsum[idx] : 0;
        sh[t] = v; __syncthreads();
        for (int off = 1; off < 512; off <<= 1) {
            int add = (t >= off) ? sh[t - off] : 0;
            __syncthreads();
            sh[t] += add;
            __syncthreads();
        }
        if (idx < nb) bsum[idx] = sh[t] - v + carry;
        __syncthreads();
        if (t == 0) carry += sh[511];
        __syncthreads();
    }
}

__global__ void k_scan3(int* __restrict__ rowstart, const int* __restrict__ bsum, int N, int E) {
    int n = blockIdx.x * 256 + threadIdx.x;
    if (n < N) rowstart[n] += bsum[blockIdx.x];
    if (n == 0) rowstart[N] = E;
}

// ---- CSR fill (also packs edge attributes) ---------------------------------
__global__ void k_fill(const int* __restrict__ eidx, const float* __restrict__ dis,
                       const int* __restrict__ rowstart, int* __restrict__ cursor,
                       int* __restrict__ csr_col, float* __restrict__ csr_w,
                       int* __restrict__ csr_att, const int* __restrict__ eattr, int E) {
    int e = blockIdx.x * 256 + threadIdx.x;
    if (e >= E) return;
    int r = eidx[e], c = eidx[E + e];
    float wv = dis[r] * dis[c];
    int a0 = eattr[e * 3 + 0], a1 = eattr[e * 3 + 1], a2 = eattr[e * 3 + 2];
    int slot = atomicAdd(&cursor[r], 1);
    int idx = rowstart[r] + slot;
    csr_col[idx] = c; csr_w[idx] = wv; csr_att[idx] = a0 | (a1 << 8) | (a2 << 16);
}

// ---- msg_edge[n,64]; bond table in LDS, wave per node ----------------------
__global__ __launch_bounds__(256) void k_msg(
    const int* __restrict__ rowstart, const int* __restrict__ csr_att,
    const float* __restrict__ csr_w, const float* __restrict__ bond,
    float* __restrict__ msg, int N) {
    __shared__ float bl[1536];
    int t = threadIdx.x, w = t >> 6, l = t & 63;
    for (int i = t; i < 1536; i += 256) bl[i] = bond[i];
    __syncthreads();
    for (int n = blockIdx.x * 4 + w; n < N; n += gridDim.x * 4) {
        int s0 = rowstart[n], s1 = rowstart[n + 1];
        float m = 0.f;
        for (int i = s0; i < s1; ++i) {
            int att = csr_att[i];
            float wv = csr_w[i];
            m += wv * (bl[(att & 255) * 64 + l] + bl[(8 + ((att >> 8) & 255)) * 64 + l]
                     + bl[(16 + (att >> 16)) * 64 + l]);
        }
        msg[(size_t)n * 64 + l] = m;
    }
}

// ---- k_sum per graph (iteration-invariant) ---------------------------------
__global__ __launch_bounds__(128) void k_ksum(
    const unsigned short* __restrict__ kq, const int* __restrict__ batch,
    float* __restrict__ ksum, int N) {
    int t = threadIdx.x;
    int start = blockIdx.x * 256;
    if (start >= N) return;
    int curb = batch[start];
    float a = 0.f;
    for (int i = 0; i < 256; ++i) {
        int n = start + i;
        if (n >= N) break;
        int b = batch[n];
        if (b != curb) { atomicAdd(&ksum[curb * 128 + t], a); a = 0.f; curb = b; }
        a += b2f_u(kq[(size_t)n * 128 + t]);
    }
    atomicAdd(&ksum[curb * 128 + t], a);
}

// ---- denom[n][h] = q[n,h,:].ksum[b,h,:] + n_nodes[b] -----------------------
__global__ __launch_bounds__(256) void k_denom(
    const unsigned short* __restrict__ q, const float* __restrict__ ksum,
    const int* __restrict__ batch, const int* __restrict__ nn,
    float* __restrict__ denom, int N)
{
    int w = threadIdx.x >> 6, l = threadIdx.x & 63;
    int n = blockIdx.x * 4 + w;
    if (n >= N) return;
    int b = batch[n];
    float d0 = b2f_u(q[(size_t)n * 128 + l]) * ksum[b * 128 + l];
    float d1 = b2f_u(q[(size_t)n * 128 + 64 + l]) * ksum[b * 128 + 64 + l];
    d0 = wave_reduce_sum(d0);
    d1 = wave_reduce_sum(d1);
    if (l == 0) {
        float nf = (float)nn[b];
        denom[n * 2 + 0] = d0 + nf;
        denom[n * 2 + 1] = d1 + nf;
    }
}

// ---- stage 1: per-chunk partial kv (plain stores, no atomics) --------------
__global__ __launch_bounds__(256) void k_kvp(
    const unsigned short* __restrict__ kq, const unsigned short* __restrict__ cur,
    const int* __restrict__ ptr, const int* __restrict__ cptr,
    float* __restrict__ partKV, float* __restrict__ partVS, int B)
{
    int cid = blockIdx.x;
    if (cid >= cptr[B]) return;
    int lo = 0, hi = B - 1;
    while (lo < hi) { int mid = (lo + hi + 1) >> 1; if (cptr[mid] <= cid) lo = mid; else hi = mid - 1; }
    int b = lo;
    int start = ptr[b] + (cid - cptr[b]) * CHUNK;
    int end = min(start + CHUNK, ptr[b + 1]);

    int w = threadIdx.x >> 6, l = threadIdx.x & 63;
    int h = w >> 1, dhalf = w & 1;
    int d0 = dhalf * 32 + (l & 7) * 4;
    int e0 = (l >> 3) * 8;
    float a[4][8], va[8];
    #pragma unroll
    for (int i = 0; i < 4; ++i)
        #pragma unroll
        for (int j = 0; j < 8; ++j) a[i][j] = 0.f;
    #pragma unroll
    for (int j = 0; j < 8; ++j) va[j] = 0.f;

    const unsigned short* kp = kq + (size_t)start * 128 + h * 64 + d0;
    const unsigned short* vp = cur + (size_t)start * 128 + h * 64 + e0;
    #pragma unroll 4
    for (int n = start; n < end; ++n) {
        uint2 ku = *(const uint2*)kp;
        uint4 vu = *(const uint4*)vp;
        kp += 128; vp += 128;
        float k0 = asf(ku.x << 16), k1 = asf(ku.x & 0xffff0000u);
        float k2 = asf(ku.y << 16), k3 = asf(ku.y & 0xffff0000u);
        float v[8];
        v[0] = asf(vu.x << 16); v[1] = asf(vu.x & 0xffff0000u);
        v[2] = asf(vu.y << 16); v[3] = asf(vu.y & 0xffff0000u);
        v[4] = asf(vu.z << 16); v[5] = asf(vu.z & 0xffff0000u);
        v[6] = asf(vu.w << 16); v[7] = asf(vu.w & 0xffff0000u);
        #pragma unroll
        for (int j = 0; j < 8; ++j) {
            a[0][j] += k0 * v[j]; a[1][j] += k1 * v[j];
            a[2][j] += k2 * v[j]; a[3][j] += k3 * v[j];
            va[j] += v[j];
        }
    }
    float* dst = partKV + (size_t)cid * 8192 + h * 4096;
    #pragma unroll
    for (int j = 0; j < 8; ++j) {
        float4 s4 = { a[0][j], a[1][j], a[2][j], a[3][j] };
        *(float4*)(dst + (e0 + j) * 64 + d0) = s4;
    }
    if (dhalf == 0 && (l & 7) == 0) {
        float* vdst = partVS + (size_t)cid * 128 + h * 64 + e0;
        #pragma unroll
        for (int j = 0; j < 8; ++j) vdst[j] = va[j];
    }
}

// ---- stage 2: sum partials -> kvT bf16 + vsum ------------------------------
__global__ __launch_bounds__(256) void k_red(
    const float* __restrict__ partKV, const float* __restrict__ partVS,
    const int* __restrict__ cptr, unsigned short* __restrict__ kvT_b,
    float* __restrict__ vsum, int B)
{
    int gh = blockIdx.x, g = gh >> 1, h = gh & 1;
    int c0 = cptr[g], c1 = cptr[g + 1];
    int t = threadIdx.x;
    float s[16];
    #pragma unroll
    for (int i = 0; i < 16; ++i) s[i] = 0.f;
    for (int c = c0; c < c1; ++c) {
        const float4* src = (const float4*)(partKV + (size_t)c * 8192 + h * 4096 + t * 16);
        #pragma unroll
        for (int i = 0; i < 4; ++i) {
            float4 v = src[i];
            s[i * 4 + 0] += v.x; s[i * 4 + 1] += v.y; s[i * 4 + 2] += v.z; s[i * 4 + 3] += v.w;
        }
    }
    unsigned int u[8];
    #pragma unroll
    for (int i = 0; i < 8; ++i) u[i] = pack2(s[2 * i], s[2 * i + 1]);
    uint4* dst = (uint4*)(kvT_b + (size_t)gh * 4096 + t * 16);
    dst[0] = make_uint4(u[0], u[1], u[2], u[3]);
    dst[1] = make_uint4(u[4], u[5], u[6], u[7]);
    if (t < 64) {
        float vs = 0.f;
        for (int c = c0; c < c1; ++c) vs += partVS[(size_t)c * 128 + h * 64 + t];
        vsum[g * 128 + h * 64 + t] = vs;
    }
}

// ---- attn via MFMA ---------------------------------------------------------
__global__ __launch_bounds__(256) void k_attn(
    const unsigned short* __restrict__ q, const unsigned short* __restrict__ kvT,
    const float* __restrict__ vsum, const float* __restrict__ denom,
    const int* __restrict__ batch, unsigned short* __restrict__ curB, int N)
{
    int w = threadIdx.x >> 6, l = threadIdx.x & 63;
    int base = blockIdx.x * 64 + w * 16;
    if (base >= N) return;
    int quad = l >> 4, six = l & 15;
    int b0 = batch[base];
    int nlast = min(base + 15, N - 1);
    bool uni = (base + 15 < N) && (batch[nlast] == b0);
    if (uni) {
        int n = base + six;
        #pragma unroll
        for (int h = 0; h < 2; ++h) {
            const unsigned short* qrow = q + (size_t)n * 128 + h * 64;
            bf16x8 a0 = *(const bf16x8*)(qrow + quad * 8);
            bf16x8 a1 = *(const bf16x8*)(qrow + 32 + quad * 8);
            const unsigned short* Bb = kvT + (size_t)(b0 * 2 + h) * 4096;
            f32x4v acc[4];
            #pragma unroll
            for (int et = 0; et < 4; ++et) {
                const unsigned short* brow = Bb + (size_t)(et * 16 + six) * 64;
                bf16x8 bb0 = *(const bf16x8*)(brow + quad * 8);
                bf16x8 bb1 = *(const bf16x8*)(brow + 32 + quad * 8);
                f32x4v c = {0.f, 0.f, 0.f, 0.f};
                c = __builtin_amdgcn_mfma_f32_16x16x32_bf16(a0, bb0, c, 0, 0, 0);
                c = __builtin_amdgcn_mfma_f32_16x16x32_bf16(a1, bb1, c, 0, 0, 0);
                acc[et] = c;
            }
            #pragma unroll
            for (int et = 0; et < 4; ++et) {
                int e = et * 16 + six;
                float vs = vsum[(b0 * 2 + h) * 64 + e];
                #pragma unroll
                for (int r = 0; r < 4; ++r) {
                    int nr = base + quad * 4 + r;
                    float dn = denom[nr * 2 + h];
                    float val = 0.5f * (acc[et][r] + vs) / dn;
                    curB[(size_t)nr * 128 + h * 64 + e] = f2b_u(val);
                }
            }
        }
    } else {
        for (int i = 0; i < 16; ++i) {
            int n = base + i;
            if (n >= N) break;
            int b = batch[n];
            #pragma unroll
            for (int h = 0; h < 2; ++h) {
                float num = 0.f;
                const unsigned short* krow = kvT + (size_t)((b * 2 + h) * 64 + l) * 64;
                for (int d = 0; d < 64; ++d)
                    num += b2f_u(q[(size_t)n * 128 + h * 64 + d]) * b2f_u(krow[d]);
                float val = 0.5f * (num + vsum[(b * 2 + h) * 64 + l]) / denom[n * 2 + h];
                curB[(size_t)n * 128 + h * 64 + l] = f2b_u(val);
            }
        }
    }
}

// ---- GCN gather + combine (wave per node). first=1: acc base = curA row ----
__global__ __launch_bounds__(256) void k_gcn(
    const unsigned short* __restrict__ curA, const float* __restrict__ msg,
    const int* __restrict__ rowstart, const int* __restrict__ csr_col,
    const float* __restrict__ csr_w,
    unsigned short* __restrict__ curB, unsigned short* __restrict__ acc, int N, int first)
{
    int w = threadIdx.x >> 6, l = threadIdx.x & 63;
    int n = blockIdx.x * 4 + w;
    if (n >= N) return;
    int s0 = rowstart[n], s1 = rowstart[n + 1];
    float g0 = 0.f, g1 = 0.f;
    #pragma unroll 2
    for (int i = s0; i < s1; ++i) {
        int c = csr_col[i];
        float wv = csr_w[i];
        unsigned int u = *(const unsigned int*)(curA + (size_t)c * 128 + 2 * l);
        g0 += wv * asf(u << 16);
        g1 += wv * asf(u & 0xffff0000u);
    }
    float2 m = *(const float2*)(msg + (size_t)n * 64 + ((2 * l) & 63));
    size_t o = (size_t)n * 128 + 2 * l;
    unsigned int ub = *(const unsigned int*)(curB + o);
    float v0 = 0.5f * (g0 + m.x) + asf(ub << 16);
    float v1 = 0.5f * (g1 + m.y) + asf(ub & 0xffff0000u);
    *(unsigned int*)(curB + o) = pack2(v0, v1);
    unsigned int ua = *(const unsigned int*)(first ? (curA + o) : (acc + o));
    *(unsigned int*)(acc + o) = pack2(asf(ua << 16) + v0, asf(ua & 0xffff0000u) + v1);
}

// ---- out = (acc @ Wo^T + b) / 2 via MFMA -----------------------------------
// A = Wo rows (m=o), B = acc rows (col=node), K=128 -> 4 MFMAs per o-tile.
__global__ __launch_bounds__(256) void k_outm(
    const unsigned short* __restrict__ acc, const unsigned short* __restrict__ Wob,
    const float* __restrict__ Wo_b, float* __restrict__ out, int N)
{
    int w = threadIdx.x >> 6, l = threadIdx.x & 63;
    int six = l & 15, quad = l >> 4;
    int base = (blockIdx.x * 4 + w) * 16;
    if (base >= N) return;
    int n = base + six;
    int nc = min(n, N - 1);
    const unsigned short* ar = acc + (size_t)nc * 128;
    bf16x8 b0 = *(const bf16x8*)(ar + quad * 8);
    bf16x8 b1 = *(const bf16x8*)(ar + 32 + quad * 8);
    bf16x8 b2 = *(const bf16x8*)(ar + 64 + quad * 8);
    bf16x8 b3 = *(const bf16x8*)(ar + 96 + quad * 8);
    #pragma unroll
    for (int t = 0; t < 4; ++t) {
        const unsigned short* wr = Wob + (size_t)(t * 16 + six) * 128;
        bf16x8 a0 = *(const bf16x8*)(wr + quad * 8);
        bf16x8 a1 = *(const bf16x8*)(wr + 32 + quad * 8);
        bf16x8 a2 = *(const bf16x8*)(wr + 64 + quad * 8);
        bf16x8 a3 = *(const bf16x8*)(wr + 96 + quad * 8);
        f32x4v c = {0.f, 0.f, 0.f, 0.f};
        c = __builtin_amdgcn_mfma_f32_16x16x32_bf16(a0, b0, c, 0, 0, 0);
        c = __builtin_amdgcn_mfma_f32_16x16x32_bf16(a1, b1, c, 0, 0, 0);
        c = __builtin_amdgcn_mfma_f32_16x16x32_bf16(a2, b2, c, 0, 0, 0);
        c = __builtin_amdgcn_mfma_f32_16x16x32_bf16(a3, b3, c, 0, 0, 0);
        if (n < N) {
            float4 bias = *(const float4*)(Wo_b + t * 16 + quad * 4);
            float4 o4;
            o4.x = (c[0] + bias.x) * 0.5f;
            o4.y = (c[1] + bias.y) * 0.5f;
            o4.z = (c[2] + bias.z) * 0.5f;
            o4.w = (c[3] + bias.w) * 0.5f;
            *(float4*)(out + (size_t)n * 64 + t * 16 + quad * 4) = o4;
        }
    }
}

extern "C" void kernel_launch(void* const* d_in, const int* in_sizes, int n_in,
                              void* d_out, int out_size, void* d_ws, size_t ws_size,
                              hipStream_t stream) {
    const float* x    = (const float*)d_in[0];
    const float* Wq_w = (const float*)d_in[1];
    const float* Wq_b = (const float*)d_in[2];
    const float* Wk_w = (const float*)d_in[3];
    const float* Wk_b = (const float*)d_in[4];
    const float* Wo_w = (const float*)d_in[5];
    const float* Wo_b = (const float*)d_in[6];
    const float* bond = (const float*)d_in[7];
    const int*   eidx = (const int*)d_in[8];
    const int*   eattr= (const int*)d_in[9];
    const int*   nn   = (const int*)d_in[10];
    float* out = (float*)d_out;
    int N = in_sizes[0] / 64;
    int E = in_sizes[9] / 3;
    int B = in_sizes[10];

    char* p = (char*)d_ws;
    auto alloc = [&](size_t bytes) { char* r = p; p += (bytes + 255) & ~(size_t)255; return r; };
    unsigned short* q    = (unsigned short*)alloc((size_t)N * 128 * 2);
    unsigned short* kq   = (unsigned short*)alloc((size_t)N * 128 * 2);
    unsigned short* curA = (unsigned short*)alloc((size_t)N * 128 * 2);
    unsigned short* curB = (unsigned short*)alloc((size_t)N * 128 * 2);
    unsigned short* acc  = (unsigned short*)alloc((size_t)N * 128 * 2);
    int maxchunks = (N + CHUNK - 1) / CHUNK + B;
    float* partKV = (float*)alloc((size_t)maxchunks * 8192 * 4);
    float* partVS = (float*)alloc((size_t)maxchunks * 128 * 4);
    unsigned short* kvT_b = (unsigned short*)alloc((size_t)B * 2 * 64 * 64 * 2);
    float* vsum  = (float*)alloc((size_t)B * 128 * 4);
    float* ksum  = (float*)alloc((size_t)B * 128 * 4);
    float* denom = (float*)alloc((size_t)N * 2 * 4);
    float* dis   = (float*)alloc((size_t)N * 4);
    int* deg     = (int*)alloc((size_t)N * 4);
    int* rowstart= (int*)alloc((size_t)(N + 1) * 4);
    int* cursor  = (int*)alloc((size_t)N * 4);
    int* csr_col = (int*)alloc((size_t)E * 4);
    float* csr_w = (float*)alloc((size_t)E * 4);
    int* csr_att = (int*)alloc((size_t)E * 4);
    int* batch   = (int*)alloc((size_t)N * 4);
    int* ptr     = (int*)alloc((size_t)(B + 1) * 4);
    int* cptr    = (int*)alloc((size_t)(B + 1) * 4);
    unsigned short* Wb = (unsigned short*)alloc(24576 * 2);
    int nb = (N + 255) / 256;
    int* bsum    = (int*)alloc((size_t)nb * 4);
    float* msg   = out;   // [N,64] fp32 aliased onto d_out; k_outm rewrites it last

    hipMemsetAsync(deg,    0, (size_t)N * 4, stream);
    hipMemsetAsync(cursor, 0, (size_t)N * 4, stream);
    hipMemsetAsync(ksum,   0, (size_t)B * 128 * 4, stream);

    k_ptr  <<<1, 64, 0, stream>>>(nn, ptr, cptr, B);
    k_batch<<<B, 256, 0, stream>>>(ptr, batch);
    k_wcvt <<<96, 256, 0, stream>>>(Wq_w, Wk_w, Wo_w, Wb);
    k_qkm  <<<(N + 63) / 64, 256, 0, stream>>>(x, Wb, Wq_b, Wk_b, q, kq, curA, N);
    k_deg  <<<(E + 255) / 256, 256, 0, stream>>>(eidx, deg, E);
    k_dis  <<<(N + 255) / 256, 256, 0, stream>>>(deg, dis, N);
    k_scan1<<<nb, 256, 0, stream>>>(deg, rowstart, bsum, N);
    k_scan2<<<1, 512, 0, stream>>>(bsum, nb);
    k_scan3<<<nb, 256, 0, stream>>>(rowstart, bsum, N, E);
    k_fill <<<(E + 255) / 256, 256, 0, stream>>>(eidx, dis, rowstart, cursor, csr_col, csr_w, csr_att, eattr, E);
    k_msg  <<<2048, 256, 0, stream>>>(rowstart, csr_att, csr_w, bond, msg, N);
    k_ksum <<<(N + 255) / 256, 128, 0, stream>>>(kq, batch, ksum, N);
    k_denom<<<(N + 3) / 4, 256, 0, stream>>>(q, ksum, batch, nn, denom, N);

    for (int it = 0; it < 4; ++it) {
        k_kvp <<<maxchunks, 256, 0, stream>>>(kq, curA, ptr, cptr, partKV, partVS, B);
        k_red <<<B * 2, 256, 0, stream>>>(partKV, partVS, cptr, kvT_b, vsum, B);
        k_attn<<<(N + 63) / 64, 256, 0, stream>>>(q, kvT_b, vsum, denom, batch, curB, N);
        k_gcn <<<(N + 3) / 4, 256, 0, stream>>>(curA, msg, rowstart, csr_col, csr_w, curB, acc, N, it == 0 ? 1 : 0);
        unsigned short* tmp = curA; curA = curB; curB = tmp;
    }
    k_outm<<<(N + 63) / 64, 256, 0, stream>>>(acc, Wb + 16384, Wo_b, out, N);
}

// Round 9
// 1073.733 us; speedup vs baseline: 1.8232x; 1.0574x over previous
//
#include <hip/hip_runtime.h>
#include <hip/hip_bf16.h>

// GloAttnConv R9: k_ksum (82us latency-bound serial walk) -> two-stage chunked
// reduction (k_ksump partials + k_ksr), reusing the cptr chunk machinery.

typedef __attribute__((ext_vector_type(8))) short bf16x8;
typedef __attribute__((ext_vector_type(4))) float f32x4v;

#define CHUNK 100

__device__ __forceinline__ float asf(unsigned int u) { union { unsigned int i; float f; } v; v.i = u; return v.f; }
__device__ __forceinline__ float b2f_u(unsigned short u) { return asf((unsigned int)u << 16); }
__device__ __forceinline__ unsigned short f2b_u(float f) {
    __hip_bfloat16 h = __float2bfloat16(f);
    union { __hip_bfloat16 h; unsigned short u; } v; v.h = h; return v.u;
}
__device__ __forceinline__ unsigned int pack2(float a, float b) {
    return (unsigned int)f2b_u(a) | ((unsigned int)f2b_u(b) << 16);
}
__device__ __forceinline__ float wave_reduce_sum(float v) {
    #pragma unroll
    for (int off = 32; off > 0; off >>= 1) v += __shfl_xor(v, off, 64);
    return v;
}

// ---- graph bookkeeping: node ptr + chunk ptr -------------------------------
__global__ void k_ptr(const int* __restrict__ nn, int* __restrict__ ptr,
                      int* __restrict__ cptr, int B) {
    if (threadIdx.x == 0 && blockIdx.x == 0) {
        int s = 0, c = 0; ptr[0] = 0; cptr[0] = 0;
        for (int i = 0; i < B; ++i) {
            s += nn[i]; ptr[i + 1] = s;
            c += (nn[i] + CHUNK - 1) / CHUNK; cptr[i + 1] = c;
        }
    }
}

__global__ void k_batch(const int* __restrict__ ptr, int* __restrict__ batch) {
    int b = blockIdx.x;
    int s = ptr[b], e = ptr[b + 1];
    for (int i = s + threadIdx.x; i < e; i += blockDim.x) batch[i] = b;
}

// ---- W -> bf16 stacked: [0,8192)=Wq, [8192,16384)=Wk, [16384,24576)=Wo ------
__global__ void k_wcvt(const float* __restrict__ Wq_w, const float* __restrict__ Wk_w,
                       const float* __restrict__ Wo_w, unsigned short* __restrict__ Wb) {
    int i = blockIdx.x * 256 + threadIdx.x;
    if (i < 24576) {
        float v = (i < 8192) ? Wq_w[i] : ((i < 16384) ? Wk_w[i - 8192] : Wo_w[i - 16384]);
        Wb[i] = f2b_u(v);
    }
}

// ---- q/k projection via MFMA + L2-normalize; writes q, kq, curA ------------
__global__ __launch_bounds__(256) void k_qkm(
    const float* __restrict__ x, const unsigned short* __restrict__ Wb,
    const float* __restrict__ Wq_b, const float* __restrict__ Wk_b,
    unsigned short* __restrict__ q, unsigned short* __restrict__ kq,
    unsigned short* __restrict__ curA, int N)
{
    int w = threadIdx.x >> 6, l = threadIdx.x & 63;
    int six = l & 15, quad = l >> 4;
    int base = (blockIdx.x * 4 + w) * 16;
    if (base >= N) return;
    int n = base + six;
    int nc = min(n, N - 1);

    const float* xr = x + (size_t)nc * 64;
    float xv0[8], xv1[8];
    #pragma unroll
    for (int j = 0; j < 8; ++j) { xv0[j] = xr[quad * 8 + j]; xv1[j] = xr[32 + quad * 8 + j]; }
    union { bf16x8 v; unsigned int u[4]; } b0, b1;
    #pragma unroll
    for (int i = 0; i < 4; ++i) {
        b0.u[i] = pack2(xv0[2 * i], xv0[2 * i + 1]);
        b1.u[i] = pack2(xv1[2 * i], xv1[2 * i + 1]);
    }
    if (n < N) {
        unsigned short* cr = curA + (size_t)n * 128;
        *(uint4*)(cr + quad * 8)       = make_uint4(b0.u[0], b0.u[1], b0.u[2], b0.u[3]);
        *(uint4*)(cr + 32 + quad * 8)  = make_uint4(b1.u[0], b1.u[1], b1.u[2], b1.u[3]);
        *(uint4*)(cr + 64 + quad * 8)  = make_uint4(b0.u[0], b0.u[1], b0.u[2], b0.u[3]);
        *(uint4*)(cr + 96 + quad * 8)  = make_uint4(b1.u[0], b1.u[1], b1.u[2], b1.u[3]);
    }

    #pragma unroll
    for (int g = 0; g < 4; ++g) {
        f32x4v c[4];
        #pragma unroll
        for (int tt = 0; tt < 4; ++tt) {
            int t = g * 4 + tt;
            const unsigned short* wr = Wb + (size_t)(t * 16 + six) * 64;
            bf16x8 a0 = *(const bf16x8*)(wr + quad * 8);
            bf16x8 a1 = *(const bf16x8*)(wr + 32 + quad * 8);
            f32x4v cc = {0.f, 0.f, 0.f, 0.f};
            cc = __builtin_amdgcn_mfma_f32_16x16x32_bf16(a0, b0.v, cc, 0, 0, 0);
            cc = __builtin_amdgcn_mfma_f32_16x16x32_bf16(a1, b1.v, cc, 0, 0, 0);
            c[tt] = cc;
        }
        const float* bias = (g < 2) ? Wq_b : Wk_b;
        int cb = (g & 1) * 64 + quad * 4;
        float ss = 0.f;
        #pragma unroll
        for (int tt = 0; tt < 4; ++tt)
            #pragma unroll
            for (int r = 0; r < 4; ++r) {
                float v = c[tt][r] + bias[cb + tt * 16 + r];
                c[tt][r] = v;
                ss += v * v;
            }
        ss += __shfl_xor(ss, 16, 64);
        ss += __shfl_xor(ss, 32, 64);
        float sc = rsqrtf(ss);
        if (n < N) {
            unsigned short* dst = ((g < 2) ? q : kq) + (size_t)n * 128;
            #pragma unroll
            for (int tt = 0; tt < 4; ++tt) {
                unsigned int u0 = pack2(c[tt][0] * sc, c[tt][1] * sc);
                unsigned int u1 = pack2(c[tt][2] * sc, c[tt][3] * sc);
                *(uint2*)(dst + cb + tt * 16) = make_uint2(u0, u1);
            }
        }
    }
}

// ---- degree / dis ----------------------------------------------------------
__global__ void k_deg(const int* __restrict__ row, int* __restrict__ deg, int E) {
    int e = blockIdx.x * 256 + threadIdx.x;
    if (e < E) atomicAdd(&deg[row[e]], 1);
}

__global__ void k_dis(const int* __restrict__ deg, float* __restrict__ dis, int N) {
    int n = blockIdx.x * 256 + threadIdx.x;
    if (n < N) { int d = deg[n]; dis[n] = d > 0 ? rsqrtf((float)d) : 0.f; }
}

// ---- exclusive scan of deg -> rowstart -------------------------------------
__global__ void k_scan1(const int* __restrict__ deg, int* __restrict__ rowstart,
                        int* __restrict__ bsum, int N) {
    __shared__ int sh[256];
    int t = threadIdx.x, n = blockIdx.x * 256 + t;
    int v = (n < N) ? deg[n] : 0;
    sh[t] = v; __syncthreads();
    #pragma unroll
    for (int off = 1; off < 256; off <<= 1) {
        int add = (t >= off) ? sh[t - off] : 0;
        __syncthreads();
        sh[t] += add;
        __syncthreads();
    }
    if (n < N) rowstart[n] = sh[t] - v;
    if (t == 255) bsum[blockIdx.x] = sh[255];
}

__global__ void k_scan2(int* __restrict__ bsum, int nb) {
    __shared__ int sh[512];
    __shared__ int carry;
    int t = threadIdx.x;
    if (t == 0) carry = 0;
    __syncthreads();
    for (int base = 0; base < nb; base += 512) {
        int idx = base + t;
        int v = (idx < nb) ? bsum[idx] : 0;
        sh[t] = v; __syncthreads();
        for (int off = 1; off < 512; off <<= 1) {
            int add = (t >= off) ? sh[t - off] : 0;
            __syncthreads();
            sh[t] += add;
            __syncthreads();
        }
        if (idx < nb) bsum[idx] = sh[t] - v + carry;
        __syncthreads();
        if (t == 0) carry += sh[511];
        __syncthreads();
    }
}

__global__ void k_scan3(int* __restrict__ rowstart, const int* __restrict__ bsum, int N, int E) {
    int n = blockIdx.x * 256 + threadIdx.x;
    if (n < N) rowstart[n] += bsum[blockIdx.x];
    if (n == 0) rowstart[N] = E;
}

// ---- CSR fill (also packs edge attributes) ---------------------------------
__global__ void k_fill(const int* __restrict__ eidx, const float* __restrict__ dis,
                       const int* __restrict__ rowstart, int* __restrict__ cursor,
                       int* __restrict__ csr_col, float* __restrict__ csr_w,
                       int* __restrict__ csr_att, const int* __restrict__ eattr, int E) {
    int e = blockIdx.x * 256 + threadIdx.x;
    if (e >= E) return;
    int r = eidx[e], c = eidx[E + e];
    float wv = dis[r] * dis[c];
    int a0 = eattr[e * 3 + 0], a1 = eattr[e * 3 + 1], a2 = eattr[e * 3 + 2];
    int slot = atomicAdd(&cursor[r], 1);
    int idx = rowstart[r] + slot;
    csr_col[idx] = c; csr_w[idx] = wv; csr_att[idx] = a0 | (a1 << 8) | (a2 << 16);
}

// ---- msg_edge[n,64]; bond table in LDS, wave per node ----------------------
__global__ __launch_bounds__(256) void k_msg(
    const int* __restrict__ rowstart, const int* __restrict__ csr_att,
    const float* __restrict__ csr_w, const float* __restrict__ bond,
    float* __restrict__ msg, int N) {
    __shared__ float bl[1536];
    int t = threadIdx.x, w = t >> 6, l = t & 63;
    for (int i = t; i < 1536; i += 256) bl[i] = bond[i];
    __syncthreads();
    for (int n = blockIdx.x * 4 + w; n < N; n += gridDim.x * 4) {
        int s0 = rowstart[n], s1 = rowstart[n + 1];
        float m = 0.f;
        for (int i = s0; i < s1; ++i) {
            int att = csr_att[i];
            float wv = csr_w[i];
            m += wv * (bl[(att & 255) * 64 + l] + bl[(8 + ((att >> 8) & 255)) * 64 + l]
                     + bl[(16 + (att >> 16)) * 64 + l]);
        }
        msg[(size_t)n * 64 + l] = m;
    }
}

// ---- ksum stage 1: per-chunk partial (plain stores) ------------------------
__global__ __launch_bounds__(256) void k_ksump(
    const unsigned short* __restrict__ kq, const int* __restrict__ ptr,
    const int* __restrict__ cptr, float* __restrict__ partKS, int B)
{
    int cid = blockIdx.x;
    if (cid >= cptr[B]) return;
    int lo = 0, hi = B - 1;
    while (lo < hi) { int mid = (lo + hi + 1) >> 1; if (cptr[mid] <= cid) lo = mid; else hi = mid - 1; }
    int b = lo;
    int start = ptr[b] + (cid - cptr[b]) * CHUNK;
    int end = min(start + CHUNK, ptr[b + 1]);
    int t = threadIdx.x, r = t >> 7, col = t & 127;
    float a = 0.f;
    for (int n = start + r; n < end; n += 2)
        a += b2f_u(kq[(size_t)n * 128 + col]);
    __shared__ float sh[256];
    sh[t] = a;
    __syncthreads();
    if (t < 128) partKS[(size_t)cid * 128 + t] = sh[t] + sh[t + 128];
}

// ---- ksum stage 2: sum chunk partials per graph ----------------------------
__global__ __launch_bounds__(128) void k_ksr(
    const float* __restrict__ partKS, const int* __restrict__ cptr,
    float* __restrict__ ksum, int B)
{
    int b = blockIdx.x, t = threadIdx.x;
    float s = 0.f;
    int c0 = cptr[b], c1 = cptr[b + 1];
    for (int c = c0; c < c1; ++c) s += partKS[(size_t)c * 128 + t];
    ksum[b * 128 + t] = s;
}

// ---- denom[n][h] = q[n,h,:].ksum[b,h,:] + n_nodes[b] -----------------------
__global__ __launch_bounds__(256) void k_denom(
    const unsigned short* __restrict__ q, const float* __restrict__ ksum,
    const int* __restrict__ batch, const int* __restrict__ nn,
    float* __restrict__ denom, int N)
{
    int w = threadIdx.x >> 6, l = threadIdx.x & 63;
    int n = blockIdx.x * 4 + w;
    if (n >= N) return;
    int b = batch[n];
    float d0 = b2f_u(q[(size_t)n * 128 + l]) * ksum[b * 128 + l];
    float d1 = b2f_u(q[(size_t)n * 128 + 64 + l]) * ksum[b * 128 + 64 + l];
    d0 = wave_reduce_sum(d0);
    d1 = wave_reduce_sum(d1);
    if (l == 0) {
        float nf = (float)nn[b];
        denom[n * 2 + 0] = d0 + nf;
        denom[n * 2 + 1] = d1 + nf;
    }
}

// ---- stage 1: per-chunk partial kv (plain stores, no atomics) --------------
__global__ __launch_bounds__(256) void k_kvp(
    const unsigned short* __restrict__ kq, const unsigned short* __restrict__ cur,
    const int* __restrict__ ptr, const int* __restrict__ cptr,
    float* __restrict__ partKV, float* __restrict__ partVS, int B)
{
    int cid = blockIdx.x;
    if (cid >= cptr[B]) return;
    int lo = 0, hi = B - 1;
    while (lo < hi) { int mid = (lo + hi + 1) >> 1; if (cptr[mid] <= cid) lo = mid; else hi = mid - 1; }
    int b = lo;
    int start = ptr[b] + (cid - cptr[b]) * CHUNK;
    int end = min(start + CHUNK, ptr[b + 1]);

    int w = threadIdx.x >> 6, l = threadIdx.x & 63;
    int h = w >> 1, dhalf = w & 1;
    int d0 = dhalf * 32 + (l & 7) * 4;
    int e0 = (l >> 3) * 8;
    float a[4][8], va[8];
    #pragma unroll
    for (int i = 0; i < 4; ++i)
        #pragma unroll
        for (int j = 0; j < 8; ++j) a[i][j] = 0.f;
    #pragma unroll
    for (int j = 0; j < 8; ++j) va[j] = 0.f;

    const unsigned short* kp = kq + (size_t)start * 128 + h * 64 + d0;
    const unsigned short* vp = cur + (size_t)start * 128 + h * 64 + e0;
    #pragma unroll 4
    for (int n = start; n < end; ++n) {
        uint2 ku = *(const uint2*)kp;
        uint4 vu = *(const uint4*)vp;
        kp += 128; vp += 128;
        float k0 = asf(ku.x << 16), k1 = asf(ku.x & 0xffff0000u);
        float k2 = asf(ku.y << 16), k3 = asf(ku.y & 0xffff0000u);
        float v[8];
        v[0] = asf(vu.x << 16); v[1] = asf(vu.x & 0xffff0000u);
        v[2] = asf(vu.y << 16); v[3] = asf(vu.y & 0xffff0000u);
        v[4] = asf(vu.z << 16); v[5] = asf(vu.z & 0xffff0000u);
        v[6] = asf(vu.w << 16); v[7] = asf(vu.w & 0xffff0000u);
        #pragma unroll
        for (int j = 0; j < 8; ++j) {
            a[0][j] += k0 * v[j]; a[1][j] += k1 * v[j];
            a[2][j] += k2 * v[j]; a[3][j] += k3 * v[j];
            va[j] += v[j];
        }
    }
    float* dst = partKV + (size_t)cid * 8192 + h * 4096;
    #pragma unroll
    for (int j = 0; j < 8; ++j) {
        float4 s4 = { a[0][j], a[1][j], a[2][j], a[3][j] };
        *(float4*)(dst + (e0 + j) * 64 + d0) = s4;
    }
    if (dhalf == 0 && (l & 7) == 0) {
        float* vdst = partVS + (size_t)cid * 128 + h * 64 + e0;
        #pragma unroll
        for (int j = 0; j < 8; ++j) vdst[j] = va[j];
    }
}

// ---- stage 2: sum partials -> kvT bf16 + vsum ------------------------------
__global__ __launch_bounds__(256) void k_red(
    const float* __restrict__ partKV, const float* __restrict__ partVS,
    const int* __restrict__ cptr, unsigned short* __restrict__ kvT_b,
    float* __restrict__ vsum, int B)
{
    int gh = blockIdx.x, g = gh >> 1, h = gh & 1;
    int c0 = cptr[g], c1 = cptr[g + 1];
    int t = threadIdx.x;
    float s[16];
    #pragma unroll
    for (int i = 0; i < 16; ++i) s[i] = 0.f;
    for (int c = c0; c < c1; ++c) {
        const float4* src = (const float4*)(partKV + (size_t)c * 8192 + h * 4096 + t * 16);
        #pragma unroll
        for (int i = 0; i < 4; ++i) {
            float4 v = src[i];
            s[i * 4 + 0] += v.x; s[i * 4 + 1] += v.y; s[i * 4 + 2] += v.z; s[i * 4 + 3] += v.w;
        }
    }
    unsigned int u[8];
    #pragma unroll
    for (int i = 0; i < 8; ++i) u[i] = pack2(s[2 * i], s[2 * i + 1]);
    uint4* dst = (uint4*)(kvT_b + (size_t)gh * 4096 + t * 16);
    dst[0] = make_uint4(u[0], u[1], u[2], u[3]);
    dst[1] = make_uint4(u[4], u[5], u[6], u[7]);
    if (t < 64) {
        float vs = 0.f;
        for (int c = c0; c < c1; ++c) vs += partVS[(size_t)c * 128 + h * 64 + t];
        vsum[g * 128 + h * 64 + t] = vs;
    }
}

// ---- attn via MFMA ---------------------------------------------------------
__global__ __launch_bounds__(256) void k_attn(
    const unsigned short* __restrict__ q, const unsigned short* __restrict__ kvT,
    const float* __restrict__ vsum, const float* __restrict__ denom,
    const int* __restrict__ batch, unsigned short* __restrict__ curB, int N)
{
    int w = threadIdx.x >> 6, l = threadIdx.x & 63;
    int base = blockIdx.x * 64 + w * 16;
    if (base >= N) return;
    int quad = l >> 4, six = l & 15;
    int b0 = batch[base];
    int nlast = min(base + 15, N - 1);
    bool uni = (base + 15 < N) && (batch[nlast] == b0);
    if (uni) {
        int n = base + six;
        #pragma unroll
        for (int h = 0; h < 2; ++h) {
            const unsigned short* qrow = q + (size_t)n * 128 + h * 64;
            bf16x8 a0 = *(const bf16x8*)(qrow + quad * 8);
            bf16x8 a1 = *(const bf16x8*)(qrow + 32 + quad * 8);
            const unsigned short* Bb = kvT + (size_t)(b0 * 2 + h) * 4096;
            f32x4v acc[4];
            #pragma unroll
            for (int et = 0; et < 4; ++et) {
                const unsigned short* brow = Bb + (size_t)(et * 16 + six) * 64;
                bf16x8 bb0 = *(const bf16x8*)(brow + quad * 8);
                bf16x8 bb1 = *(const bf16x8*)(brow + 32 + quad * 8);
                f32x4v c = {0.f, 0.f, 0.f, 0.f};
                c = __builtin_amdgcn_mfma_f32_16x16x32_bf16(a0, bb0, c, 0, 0, 0);
                c = __builtin_amdgcn_mfma_f32_16x16x32_bf16(a1, bb1, c, 0, 0, 0);
                acc[et] = c;
            }
            #pragma unroll
            for (int et = 0; et < 4; ++et) {
                int e = et * 16 + six;
                float vs = vsum[(b0 * 2 + h) * 64 + e];
                #pragma unroll
                for (int r = 0; r < 4; ++r) {
                    int nr = base + quad * 4 + r;
                    float dn = denom[nr * 2 + h];
                    float val = 0.5f * (acc[et][r] + vs) / dn;
                    curB[(size_t)nr * 128 + h * 64 + e] = f2b_u(val);
                }
            }
        }
    } else {
        for (int i = 0; i < 16; ++i) {
            int n = base + i;
            if (n >= N) break;
            int b = batch[n];
            #pragma unroll
            for (int h = 0; h < 2; ++h) {
                float num = 0.f;
                const unsigned short* krow = kvT + (size_t)((b * 2 + h) * 64 + l) * 64;
                for (int d = 0; d < 64; ++d)
                    num += b2f_u(q[(size_t)n * 128 + h * 64 + d]) * b2f_u(krow[d]);
                float val = 0.5f * (num + vsum[(b * 2 + h) * 64 + l]) / denom[n * 2 + h];
                curB[(size_t)n * 128 + h * 64 + l] = f2b_u(val);
            }
        }
    }
}

// ---- GCN gather + combine (wave per node). first=1: acc base = curA row ----
__global__ __launch_bounds__(256) void k_gcn(
    const unsigned short* __restrict__ curA, const float* __restrict__ msg,
    const int* __restrict__ rowstart, const int* __restrict__ csr_col,
    const float* __restrict__ csr_w,
    unsigned short* __restrict__ curB, unsigned short* __restrict__ acc, int N, int first)
{
    int w = threadIdx.x >> 6, l = threadIdx.x & 63;
    int n = blockIdx.x * 4 + w;
    if (n >= N) return;
    int s0 = rowstart[n], s1 = rowstart[n + 1];
    float g0 = 0.f, g1 = 0.f;
    #pragma unroll 2
    for (int i = s0; i < s1; ++i) {
        int c = csr_col[i];
        float wv = csr_w[i];
        unsigned int u = *(const unsigned int*)(curA + (size_t)c * 128 + 2 * l);
        g0 += wv * asf(u << 16);
        g1 += wv * asf(u & 0xffff0000u);
    }
    float2 m = *(const float2*)(msg + (size_t)n * 64 + ((2 * l) & 63));
    size_t o = (size_t)n * 128 + 2 * l;
    unsigned int ub = *(const unsigned int*)(curB + o);
    float v0 = 0.5f * (g0 + m.x) + asf(ub << 16);
    float v1 = 0.5f * (g1 + m.y) + asf(ub & 0xffff0000u);
    *(unsigned int*)(curB + o) = pack2(v0, v1);
    unsigned int ua = *(const unsigned int*)(first ? (curA + o) : (acc + o));
    *(unsigned int*)(acc + o) = pack2(asf(ua << 16) + v0, asf(ua & 0xffff0000u) + v1);
}

// ---- out = (acc @ Wo^T + b) / 2 via MFMA -----------------------------------
__global__ __launch_bounds__(256) void k_outm(
    const unsigned short* __restrict__ acc, const unsigned short* __restrict__ Wob,
    const float* __restrict__ Wo_b, float* __restrict__ out, int N)
{
    int w = threadIdx.x >> 6, l = threadIdx.x & 63;
    int six = l & 15, quad = l >> 4;
    int base = (blockIdx.x * 4 + w) * 16;
    if (base >= N) return;
    int n = base + six;
    int nc = min(n, N - 1);
    const unsigned short* ar = acc + (size_t)nc * 128;
    bf16x8 b0 = *(const bf16x8*)(ar + quad * 8);
    bf16x8 b1 = *(const bf16x8*)(ar + 32 + quad * 8);
    bf16x8 b2 = *(const bf16x8*)(ar + 64 + quad * 8);
    bf16x8 b3 = *(const bf16x8*)(ar + 96 + quad * 8);
    #pragma unroll
    for (int t = 0; t < 4; ++t) {
        const unsigned short* wr = Wob + (size_t)(t * 16 + six) * 128;
        bf16x8 a0 = *(const bf16x8*)(wr + quad * 8);
        bf16x8 a1 = *(const bf16x8*)(wr + 32 + quad * 8);
        bf16x8 a2 = *(const bf16x8*)(wr + 64 + quad * 8);
        bf16x8 a3 = *(const bf16x8*)(wr + 96 + quad * 8);
        f32x4v c = {0.f, 0.f, 0.f, 0.f};
        c = __builtin_amdgcn_mfma_f32_16x16x32_bf16(a0, b0, c, 0, 0, 0);
        c = __builtin_amdgcn_mfma_f32_16x16x32_bf16(a1, b1, c, 0, 0, 0);
        c = __builtin_amdgcn_mfma_f32_16x16x32_bf16(a2, b2, c, 0, 0, 0);
        c = __builtin_amdgcn_mfma_f32_16x16x32_bf16(a3, b3, c, 0, 0, 0);
        if (n < N) {
            float4 bias = *(const float4*)(Wo_b + t * 16 + quad * 4);
            float4 o4;
            o4.x = (c[0] + bias.x) * 0.5f;
            o4.y = (c[1] + bias.y) * 0.5f;
            o4.z = (c[2] + bias.z) * 0.5f;
            o4.w = (c[3] + bias.w) * 0.5f;
            *(float4*)(out + (size_t)n * 64 + t * 16 + quad * 4) = o4;
        }
    }
}

extern "C" void kernel_launch(void* const* d_in, const int* in_sizes, int n_in,
                              void* d_out, int out_size, void* d_ws, size_t ws_size,
                              hipStream_t stream) {
    const float* x    = (const float*)d_in[0];
    const float* Wq_w = (const float*)d_in[1];
    const float* Wq_b = (const float*)d_in[2];
    const float* Wk_w = (const float*)d_in[3];
    const float* Wk_b = (const float*)d_in[4];
    const float* Wo_w = (const float*)d_in[5];
    const float* Wo_b = (const float*)d_in[6];
    const float* bond = (const float*)d_in[7];
    const int*   eidx = (const int*)d_in[8];
    const int*   eattr= (const int*)d_in[9];
    const int*   nn   = (const int*)d_in[10];
    float* out = (float*)d_out;
    int N = in_sizes[0] / 64;
    int E = in_sizes[9] / 3;
    int B = in_sizes[10];

    char* p = (char*)d_ws;
    auto alloc = [&](size_t bytes) { char* r = p; p += (bytes + 255) & ~(size_t)255; return r; };
    unsigned short* q    = (unsigned short*)alloc((size_t)N * 128 * 2);
    unsigned short* kq   = (unsigned short*)alloc((size_t)N * 128 * 2);
    unsigned short* curA = (unsigned short*)alloc((size_t)N * 128 * 2);
    unsigned short* curB = (unsigned short*)alloc((size_t)N * 128 * 2);
    unsigned short* acc  = (unsigned short*)alloc((size_t)N * 128 * 2);
    int maxchunks = (N + CHUNK - 1) / CHUNK + B;
    float* partKV = (float*)alloc((size_t)maxchunks * 8192 * 4);
    float* partVS = (float*)alloc((size_t)maxchunks * 128 * 4);
    float* partKS = (float*)alloc((size_t)maxchunks * 128 * 4);
    unsigned short* kvT_b = (unsigned short*)alloc((size_t)B * 2 * 64 * 64 * 2);
    float* vsum  = (float*)alloc((size_t)B * 128 * 4);
    float* ksum  = (float*)alloc((size_t)B * 128 * 4);
    float* denom = (float*)alloc((size_t)N * 2 * 4);
    float* dis   = (float*)alloc((size_t)N * 4);
    int* deg     = (int*)alloc((size_t)N * 4);
    int* rowstart= (int*)alloc((size_t)(N + 1) * 4);
    int* cursor  = (int*)alloc((size_t)N * 4);
    int* csr_col = (int*)alloc((size_t)E * 4);
    float* csr_w = (float*)alloc((size_t)E * 4);
    int* csr_att = (int*)alloc((size_t)E * 4);
    int* batch   = (int*)alloc((size_t)N * 4);
    int* ptr     = (int*)alloc((size_t)(B + 1) * 4);
    int* cptr    = (int*)alloc((size_t)(B + 1) * 4);
    unsigned short* Wb = (unsigned short*)alloc(24576 * 2);
    int nb = (N + 255) / 256;
    int* bsum    = (int*)alloc((size_t)nb * 4);
    float* msg   = out;   // [N,64] fp32 aliased onto d_out; k_outm rewrites it last

    hipMemsetAsync(deg,    0, (size_t)N * 4, stream);
    hipMemsetAsync(cursor, 0, (size_t)N * 4, stream);

    k_ptr  <<<1, 64, 0, stream>>>(nn, ptr, cptr, B);
    k_batch<<<B, 256, 0, stream>>>(ptr, batch);
    k_wcvt <<<96, 256, 0, stream>>>(Wq_w, Wk_w, Wo_w, Wb);
    k_qkm  <<<(N + 63) / 64, 256, 0, stream>>>(x, Wb, Wq_b, Wk_b, q, kq, curA, N);
    k_deg  <<<(E + 255) / 256, 256, 0, stream>>>(eidx, deg, E);
    k_dis  <<<(N + 255) / 256, 256, 0, stream>>>(deg, dis, N);
    k_scan1<<<nb, 256, 0, stream>>>(deg, rowstart, bsum, N);
    k_scan2<<<1, 512, 0, stream>>>(bsum, nb);
    k_scan3<<<nb, 256, 0, stream>>>(rowstart, bsum, N, E);
    k_fill <<<(E + 255) / 256, 256, 0, stream>>>(eidx, dis, rowstart, cursor, csr_col, csr_w, csr_att, eattr, E);
    k_msg  <<<2048, 256, 0, stream>>>(rowstart, csr_att, csr_w, bond, msg, N);
    k_ksump<<<maxchunks, 256, 0, stream>>>(kq, ptr, cptr, partKS, B);
    k_ksr  <<<B, 128, 0, stream>>>(partKS, cptr, ksum, B);
    k_denom<<<(N + 3) / 4, 256, 0, stream>>>(q, ksum, batch, nn, denom, N);

    for (int it = 0; it < 4; ++it) {
        k_kvp <<<maxchunks, 256, 0, stream>>>(kq, curA, ptr, cptr, partKV, partVS, B);
        k_red <<<B * 2, 256, 0, stream>>>(partKV, partVS, cptr, kvT_b, vsum, B);
        k_attn<<<(N + 63) / 64, 256, 0, stream>>>(q, kvT_b, vsum, denom, batch, curB, N);
        k_gcn <<<(N + 3) / 4, 256, 0, stream>>>(curA, msg, rowstart, csr_col, csr_w, curB, acc, N, it == 0 ? 1 : 0);
        unsigned short* tmp = curA; curA = curB; curB = tmp;
    }
    k_outm<<<(N + 63) / 64, 256, 0, stream>>>(acc, Wb + 16384, Wo_b, out, N);
}

// Round 10
// 1067.859 us; speedup vs baseline: 1.8333x; 1.0055x over previous
//
#include <hip/hip_runtime.h>
#include <hip/hip_bf16.h>

// GloAttnConv R10: k_attn MFMA operand swap (C col=node -> 8B packed stores,
// float4 vsum); k_fill packs CSR into one int4 store per edge (1 dirty
// line/edge instead of ~3); k_gcn/k_msg read packed CSR.

typedef __attribute__((ext_vector_type(8))) short bf16x8;
typedef __attribute__((ext_vector_type(4))) float f32x4v;

#define CHUNK 100

__device__ __forceinline__ float asf(unsigned int u) { union { unsigned int i; float f; } v; v.i = u; return v.f; }
__device__ __forceinline__ float b2f_u(unsigned short u) { return asf((unsigned int)u << 16); }
__device__ __forceinline__ unsigned short f2b_u(float f) {
    __hip_bfloat16 h = __float2bfloat16(f);
    union { __hip_bfloat16 h; unsigned short u; } v; v.h = h; return v.u;
}
__device__ __forceinline__ unsigned int pack2(float a, float b) {
    return (unsigned int)f2b_u(a) | ((unsigned int)f2b_u(b) << 16);
}
__device__ __forceinline__ float wave_reduce_sum(float v) {
    #pragma unroll
    for (int off = 32; off > 0; off >>= 1) v += __shfl_xor(v, off, 64);
    return v;
}

// ---- graph bookkeeping: node ptr + chunk ptr -------------------------------
__global__ void k_ptr(const int* __restrict__ nn, int* __restrict__ ptr,
                      int* __restrict__ cptr, int B) {
    if (threadIdx.x == 0 && blockIdx.x == 0) {
        int s = 0, c = 0; ptr[0] = 0; cptr[0] = 0;
        for (int i = 0; i < B; ++i) {
            s += nn[i]; ptr[i + 1] = s;
            c += (nn[i] + CHUNK - 1) / CHUNK; cptr[i + 1] = c;
        }
    }
}

__global__ void k_batch(const int* __restrict__ ptr, int* __restrict__ batch) {
    int b = blockIdx.x;
    int s = ptr[b], e = ptr[b + 1];
    for (int i = s + threadIdx.x; i < e; i += blockDim.x) batch[i] = b;
}

// ---- W -> bf16 stacked: [0,8192)=Wq, [8192,16384)=Wk, [16384,24576)=Wo ------
__global__ void k_wcvt(const float* __restrict__ Wq_w, const float* __restrict__ Wk_w,
                       const float* __restrict__ Wo_w, unsigned short* __restrict__ Wb) {
    int i = blockIdx.x * 256 + threadIdx.x;
    if (i < 24576) {
        float v = (i < 8192) ? Wq_w[i] : ((i < 16384) ? Wk_w[i - 8192] : Wo_w[i - 16384]);
        Wb[i] = f2b_u(v);
    }
}

// ---- q/k projection via MFMA + L2-normalize; writes q, kq, curA ------------
__global__ __launch_bounds__(256) void k_qkm(
    const float* __restrict__ x, const unsigned short* __restrict__ Wb,
    const float* __restrict__ Wq_b, const float* __restrict__ Wk_b,
    unsigned short* __restrict__ q, unsigned short* __restrict__ kq,
    unsigned short* __restrict__ curA, int N)
{
    int w = threadIdx.x >> 6, l = threadIdx.x & 63;
    int six = l & 15, quad = l >> 4;
    int base = (blockIdx.x * 4 + w) * 16;
    if (base >= N) return;
    int n = base + six;
    int nc = min(n, N - 1);

    const float* xr = x + (size_t)nc * 64;
    float xv0[8], xv1[8];
    #pragma unroll
    for (int j = 0; j < 8; ++j) { xv0[j] = xr[quad * 8 + j]; xv1[j] = xr[32 + quad * 8 + j]; }
    union { bf16x8 v; unsigned int u[4]; } b0, b1;
    #pragma unroll
    for (int i = 0; i < 4; ++i) {
        b0.u[i] = pack2(xv0[2 * i], xv0[2 * i + 1]);
        b1.u[i] = pack2(xv1[2 * i], xv1[2 * i + 1]);
    }
    if (n < N) {
        unsigned short* cr = curA + (size_t)n * 128;
        *(uint4*)(cr + quad * 8)       = make_uint4(b0.u[0], b0.u[1], b0.u[2], b0.u[3]);
        *(uint4*)(cr + 32 + quad * 8)  = make_uint4(b1.u[0], b1.u[1], b1.u[2], b1.u[3]);
        *(uint4*)(cr + 64 + quad * 8)  = make_uint4(b0.u[0], b0.u[1], b0.u[2], b0.u[3]);
        *(uint4*)(cr + 96 + quad * 8)  = make_uint4(b1.u[0], b1.u[1], b1.u[2], b1.u[3]);
    }

    #pragma unroll
    for (int g = 0; g < 4; ++g) {
        f32x4v c[4];
        #pragma unroll
        for (int tt = 0; tt < 4; ++tt) {
            int t = g * 4 + tt;
            const unsigned short* wr = Wb + (size_t)(t * 16 + six) * 64;
            bf16x8 a0 = *(const bf16x8*)(wr + quad * 8);
            bf16x8 a1 = *(const bf16x8*)(wr + 32 + quad * 8);
            f32x4v cc = {0.f, 0.f, 0.f, 0.f};
            cc = __builtin_amdgcn_mfma_f32_16x16x32_bf16(a0, b0.v, cc, 0, 0, 0);
            cc = __builtin_amdgcn_mfma_f32_16x16x32_bf16(a1, b1.v, cc, 0, 0, 0);
            c[tt] = cc;
        }
        const float* bias = (g < 2) ? Wq_b : Wk_b;
        int cb = (g & 1) * 64 + quad * 4;
        float ss = 0.f;
        #pragma unroll
        for (int tt = 0; tt < 4; ++tt)
            #pragma unroll
            for (int r = 0; r < 4; ++r) {
                float v = c[tt][r] + bias[cb + tt * 16 + r];
                c[tt][r] = v;
                ss += v * v;
            }
        ss += __shfl_xor(ss, 16, 64);
        ss += __shfl_xor(ss, 32, 64);
        float sc = rsqrtf(ss);
        if (n < N) {
            unsigned short* dst = ((g < 2) ? q : kq) + (size_t)n * 128;
            #pragma unroll
            for (int tt = 0; tt < 4; ++tt) {
                unsigned int u0 = pack2(c[tt][0] * sc, c[tt][1] * sc);
                unsigned int u1 = pack2(c[tt][2] * sc, c[tt][3] * sc);
                *(uint2*)(dst + cb + tt * 16) = make_uint2(u0, u1);
            }
        }
    }
}

// ---- degree / dis ----------------------------------------------------------
__global__ void k_deg(const int* __restrict__ row, int* __restrict__ deg, int E) {
    int e = blockIdx.x * 256 + threadIdx.x;
    if (e < E) atomicAdd(&deg[row[e]], 1);
}

__global__ void k_dis(const int* __restrict__ deg, float* __restrict__ dis, int N) {
    int n = blockIdx.x * 256 + threadIdx.x;
    if (n < N) { int d = deg[n]; dis[n] = d > 0 ? rsqrtf((float)d) : 0.f; }
}

// ---- exclusive scan of deg -> rowstart -------------------------------------
__global__ void k_scan1(const int* __restrict__ deg, int* __restrict__ rowstart,
                        int* __restrict__ bsum, int N) {
    __shared__ int sh[256];
    int t = threadIdx.x, n = blockIdx.x * 256 + t;
    int v = (n < N) ? deg[n] : 0;
    sh[t] = v; __syncthreads();
    #pragma unroll
    for (int off = 1; off < 256; off <<= 1) {
        int add = (t >= off) ? sh[t - off] : 0;
        __syncthreads();
        sh[t] += add;
        __syncthreads();
    }
    if (n < N) rowstart[n] = sh[t] - v;
    if (t == 255) bsum[blockIdx.x] = sh[255];
}

__global__ void k_scan2(int* __restrict__ bsum, int nb) {
    __shared__ int sh[512];
    __shared__ int carry;
    int t = threadIdx.x;
    if (t == 0) carry = 0;
    __syncthreads();
    for (int base = 0; base < nb; base += 512) {
        int idx = base + t;
        int v = (idx < nb) ? bsum[idx] : 0;
        sh[t] = v; __syncthreads();
        for (int off = 1; off < 512; off <<= 1) {
            int add = (t >= off) ? sh[t - off] : 0;
            __syncthreads();
            sh[t] += add;
            __syncthreads();
        }
        if (idx < nb) bsum[idx] = sh[t] - v + carry;
        __syncthreads();
        if (t == 0) carry += sh[511];
        __syncthreads();
    }
}

__global__ void k_scan3(int* __restrict__ rowstart, const int* __restrict__ bsum, int N, int E) {
    int n = blockIdx.x * 256 + threadIdx.x;
    if (n < N) rowstart[n] += bsum[blockIdx.x];
    if (n == 0) rowstart[N] = E;
}

// ---- CSR fill: ONE int4 {col, w_bits, att, 0} store per edge ---------------
__global__ void k_fill(const int* __restrict__ eidx, const float* __restrict__ dis,
                       const int* __restrict__ rowstart, int* __restrict__ cursor,
                       int4* __restrict__ csr_pack, const int* __restrict__ eattr, int E) {
    int e = blockIdx.x * 256 + threadIdx.x;
    if (e >= E) return;
    int r = eidx[e], c = eidx[E + e];
    float wv = dis[r] * dis[c];
    int a0 = eattr[e * 3 + 0], a1 = eattr[e * 3 + 1], a2 = eattr[e * 3 + 2];
    int slot = atomicAdd(&cursor[r], 1);
    int idx = rowstart[r] + slot;
    int4 v;
    v.x = c;
    v.y = __float_as_int(wv);
    v.z = a0 | (a1 << 8) | (a2 << 16);
    v.w = 0;
    csr_pack[idx] = v;
}

// ---- msg_edge[n,64]; bond table in LDS, wave per node ----------------------
__global__ __launch_bounds__(256) void k_msg(
    const int* __restrict__ rowstart, const int4* __restrict__ csr_pack,
    const float* __restrict__ bond, float* __restrict__ msg, int N) {
    __shared__ float bl[1536];
    int t = threadIdx.x, w = t >> 6, l = t & 63;
    for (int i = t; i < 1536; i += 256) bl[i] = bond[i];
    __syncthreads();
    for (int n = blockIdx.x * 4 + w; n < N; n += gridDim.x * 4) {
        int s0 = rowstart[n], s1 = rowstart[n + 1];
        float m = 0.f;
        for (int i = s0; i < s1; ++i) {
            int4 pk = csr_pack[i];
            float wv = __int_as_float(pk.y);
            int att = pk.z;
            m += wv * (bl[(att & 255) * 64 + l] + bl[(8 + ((att >> 8) & 255)) * 64 + l]
                     + bl[(16 + (att >> 16)) * 64 + l]);
        }
        msg[(size_t)n * 64 + l] = m;
    }
}

// ---- ksum stage 1: per-chunk partial (plain stores) ------------------------
__global__ __launch_bounds__(256) void k_ksump(
    const unsigned short* __restrict__ kq, const int* __restrict__ ptr,
    const int* __restrict__ cptr, float* __restrict__ partKS, int B)
{
    int cid = blockIdx.x;
    if (cid >= cptr[B]) return;
    int lo = 0, hi = B - 1;
    while (lo < hi) { int mid = (lo + hi + 1) >> 1; if (cptr[mid] <= cid) lo = mid; else hi = mid - 1; }
    int b = lo;
    int start = ptr[b] + (cid - cptr[b]) * CHUNK;
    int end = min(start + CHUNK, ptr[b + 1]);
    int t = threadIdx.x, r = t >> 7, col = t & 127;
    float a = 0.f;
    for (int n = start + r; n < end; n += 2)
        a += b2f_u(kq[(size_t)n * 128 + col]);
    __shared__ float sh[256];
    sh[t] = a;
    __syncthreads();
    if (t < 128) partKS[(size_t)cid * 128 + t] = sh[t] + sh[t + 128];
}

// ---- ksum stage 2: sum chunk partials per graph ----------------------------
__global__ __launch_bounds__(128) void k_ksr(
    const float* __restrict__ partKS, const int* __restrict__ cptr,
    float* __restrict__ ksum, int B)
{
    int b = blockIdx.x, t = threadIdx.x;
    float s = 0.f;
    int c0 = cptr[b], c1 = cptr[b + 1];
    for (int c = c0; c < c1; ++c) s += partKS[(size_t)c * 128 + t];
    ksum[b * 128 + t] = s;
}

// ---- denom[n][h] = q[n,h,:].ksum[b,h,:] + n_nodes[b] -----------------------
__global__ __launch_bounds__(256) void k_denom(
    const unsigned short* __restrict__ q, const float* __restrict__ ksum,
    const int* __restrict__ batch, const int* __restrict__ nn,
    float* __restrict__ denom, int N)
{
    int w = threadIdx.x >> 6, l = threadIdx.x & 63;
    int n = blockIdx.x * 4 + w;
    if (n >= N) return;
    int b = batch[n];
    float d0 = b2f_u(q[(size_t)n * 128 + l]) * ksum[b * 128 + l];
    float d1 = b2f_u(q[(size_t)n * 128 + 64 + l]) * ksum[b * 128 + 64 + l];
    d0 = wave_reduce_sum(d0);
    d1 = wave_reduce_sum(d1);
    if (l == 0) {
        float nf = (float)nn[b];
        denom[n * 2 + 0] = d0 + nf;
        denom[n * 2 + 1] = d1 + nf;
    }
}

// ---- stage 1: per-chunk partial kv (plain stores, no atomics) --------------
__global__ __launch_bounds__(256) void k_kvp(
    const unsigned short* __restrict__ kq, const unsigned short* __restrict__ cur,
    const int* __restrict__ ptr, const int* __restrict__ cptr,
    float* __restrict__ partKV, float* __restrict__ partVS, int B)
{
    int cid = blockIdx.x;
    if (cid >= cptr[B]) return;
    int lo = 0, hi = B - 1;
    while (lo < hi) { int mid = (lo + hi + 1) >> 1; if (cptr[mid] <= cid) lo = mid; else hi = mid - 1; }
    int b = lo;
    int start = ptr[b] + (cid - cptr[b]) * CHUNK;
    int end = min(start + CHUNK, ptr[b + 1]);

    int w = threadIdx.x >> 6, l = threadIdx.x & 63;
    int h = w >> 1, dhalf = w & 1;
    int d0 = dhalf * 32 + (l & 7) * 4;
    int e0 = (l >> 3) * 8;
    float a[4][8], va[8];
    #pragma unroll
    for (int i = 0; i < 4; ++i)
        #pragma unroll
        for (int j = 0; j < 8; ++j) a[i][j] = 0.f;
    #pragma unroll
    for (int j = 0; j < 8; ++j) va[j] = 0.f;

    const unsigned short* kp = kq + (size_t)start * 128 + h * 64 + d0;
    const unsigned short* vp = cur + (size_t)start * 128 + h * 64 + e0;
    #pragma unroll 4
    for (int n = start; n < end; ++n) {
        uint2 ku = *(const uint2*)kp;
        uint4 vu = *(const uint4*)vp;
        kp += 128; vp += 128;
        float k0 = asf(ku.x << 16), k1 = asf(ku.x & 0xffff0000u);
        float k2 = asf(ku.y << 16), k3 = asf(ku.y & 0xffff0000u);
        float v[8];
        v[0] = asf(vu.x << 16); v[1] = asf(vu.x & 0xffff0000u);
        v[2] = asf(vu.y << 16); v[3] = asf(vu.y & 0xffff0000u);
        v[4] = asf(vu.z << 16); v[5] = asf(vu.z & 0xffff0000u);
        v[6] = asf(vu.w << 16); v[7] = asf(vu.w & 0xffff0000u);
        #pragma unroll
        for (int j = 0; j < 8; ++j) {
            a[0][j] += k0 * v[j]; a[1][j] += k1 * v[j];
            a[2][j] += k2 * v[j]; a[3][j] += k3 * v[j];
            va[j] += v[j];
        }
    }
    float* dst = partKV + (size_t)cid * 8192 + h * 4096;
    #pragma unroll
    for (int j = 0; j < 8; ++j) {
        float4 s4 = { a[0][j], a[1][j], a[2][j], a[3][j] };
        *(float4*)(dst + (e0 + j) * 64 + d0) = s4;
    }
    if (dhalf == 0 && (l & 7) == 0) {
        float* vdst = partVS + (size_t)cid * 128 + h * 64 + e0;
        #pragma unroll
        for (int j = 0; j < 8; ++j) vdst[j] = va[j];
    }
}

// ---- stage 2: sum partials -> kvT bf16 + vsum ------------------------------
__global__ __launch_bounds__(256) void k_red(
    const float* __restrict__ partKV, const float* __restrict__ partVS,
    const int* __restrict__ cptr, unsigned short* __restrict__ kvT_b,
    float* __restrict__ vsum, int B)
{
    int gh = blockIdx.x, g = gh >> 1, h = gh & 1;
    int c0 = cptr[g], c1 = cptr[g + 1];
    int t = threadIdx.x;
    float s[16];
    #pragma unroll
    for (int i = 0; i < 16; ++i) s[i] = 0.f;
    for (int c = c0; c < c1; ++c) {
        const float4* src = (const float4*)(partKV + (size_t)c * 8192 + h * 4096 + t * 16);
        #pragma unroll
        for (int i = 0; i < 4; ++i) {
            float4 v = src[i];
            s[i * 4 + 0] += v.x; s[i * 4 + 1] += v.y; s[i * 4 + 2] += v.z; s[i * 4 + 3] += v.w;
        }
    }
    unsigned int u[8];
    #pragma unroll
    for (int i = 0; i < 8; ++i) u[i] = pack2(s[2 * i], s[2 * i + 1]);
    uint4* dst = (uint4*)(kvT_b + (size_t)gh * 4096 + t * 16);
    dst[0] = make_uint4(u[0], u[1], u[2], u[3]);
    dst[1] = make_uint4(u[4], u[5], u[6], u[7]);
    if (t < 64) {
        float vs = 0.f;
        for (int c = c0; c < c1; ++c) vs += partVS[(size_t)c * 128 + h * 64 + t];
        vsum[g * 128 + h * 64 + t] = vs;
    }
}

// ---- attn via MFMA (swapped operands: A=kvT tile, B=q tile) ----------------
// C[row=e-sub, col=node] -> lane holds 4 consecutive e for ONE node -> 8B stores.
__global__ __launch_bounds__(256) void k_attn(
    const unsigned short* __restrict__ q, const unsigned short* __restrict__ kvT,
    const float* __restrict__ vsum, const float* __restrict__ denom,
    const int* __restrict__ batch, unsigned short* __restrict__ curB, int N)
{
    int w = threadIdx.x >> 6, l = threadIdx.x & 63;
    int base = blockIdx.x * 64 + w * 16;
    if (base >= N) return;
    int quad = l >> 4, six = l & 15;
    int b0 = batch[base];
    int nlast = min(base + 15, N - 1);
    bool uni = (base + 15 < N) && (batch[nlast] == b0);
    if (uni) {
        int n = base + six;   // this lane's node (C column)
        #pragma unroll
        for (int h = 0; h < 2; ++h) {
            const unsigned short* qrow = q + (size_t)n * 128 + h * 64;
            bf16x8 qb0 = *(const bf16x8*)(qrow + quad * 8);        // B-frag k=quad*8+j
            bf16x8 qb1 = *(const bf16x8*)(qrow + 32 + quad * 8);
            const unsigned short* Bb = kvT + (size_t)(b0 * 2 + h) * 4096;
            float dn = denom[n * 2 + h];
            const float* vsb = vsum + (b0 * 2 + h) * 64;
            #pragma unroll
            for (int et = 0; et < 4; ++et) {
                const unsigned short* arow = Bb + (size_t)(et * 16 + six) * 64;  // A m=e row
                bf16x8 a0 = *(const bf16x8*)(arow + quad * 8);
                bf16x8 a1 = *(const bf16x8*)(arow + 32 + quad * 8);
                f32x4v c = {0.f, 0.f, 0.f, 0.f};
                c = __builtin_amdgcn_mfma_f32_16x16x32_bf16(a0, qb0, c, 0, 0, 0);
                c = __builtin_amdgcn_mfma_f32_16x16x32_bf16(a1, qb1, c, 0, 0, 0);
                // lane holds num[node=n][e = et*16 + quad*4 + r], r=0..3
                float4 vs = *(const float4*)(vsb + et * 16 + quad * 4);
                float v0 = 0.5f * (c[0] + vs.x) / dn;
                float v1 = 0.5f * (c[1] + vs.y) / dn;
                float v2 = 0.5f * (c[2] + vs.z) / dn;
                float v3 = 0.5f * (c[3] + vs.w) / dn;
                uint2 st = make_uint2(pack2(v0, v1), pack2(v2, v3));
                *(uint2*)(curB + (size_t)n * 128 + h * 64 + et * 16 + quad * 4) = st;
            }
        }
    } else {
        for (int i = 0; i < 16; ++i) {
            int n = base + i;
            if (n >= N) break;
            int b = batch[n];
            #pragma unroll
            for (int h = 0; h < 2; ++h) {
                float num = 0.f;
                const unsigned short* krow = kvT + (size_t)((b * 2 + h) * 64 + l) * 64;
                for (int d = 0; d < 64; ++d)
                    num += b2f_u(q[(size_t)n * 128 + h * 64 + d]) * b2f_u(krow[d]);
                float val = 0.5f * (num + vsum[(b * 2 + h) * 64 + l]) / denom[n * 2 + h];
                curB[(size_t)n * 128 + h * 64 + l] = f2b_u(val);
            }
        }
    }
}

// ---- GCN gather + combine (wave per node). first=1: acc base = curA row ----
__global__ __launch_bounds__(256) void k_gcn(
    const unsigned short* __restrict__ curA, const float* __restrict__ msg,
    const int* __restrict__ rowstart, const int4* __restrict__ csr_pack,
    unsigned short* __restrict__ curB, unsigned short* __restrict__ acc, int N, int first)
{
    int w = threadIdx.x >> 6, l = threadIdx.x & 63;
    int n = blockIdx.x * 4 + w;
    if (n >= N) return;
    int s0 = rowstart[n], s1 = rowstart[n + 1];
    float g0 = 0.f, g1 = 0.f;
    #pragma unroll 2
    for (int i = s0; i < s1; ++i) {
        int4 pk = csr_pack[i];
        int c = pk.x;
        float wv = __int_as_float(pk.y);
        unsigned int u = *(const unsigned int*)(curA + (size_t)c * 128 + 2 * l);
        g0 += wv * asf(u << 16);
        g1 += wv * asf(u & 0xffff0000u);
    }
    float2 m = *(const float2*)(msg + (size_t)n * 64 + ((2 * l) & 63));
    size_t o = (size_t)n * 128 + 2 * l;
    unsigned int ub = *(const unsigned int*)(curB + o);
    float v0 = 0.5f * (g0 + m.x) + asf(ub << 16);
    float v1 = 0.5f * (g1 + m.y) + asf(ub & 0xffff0000u);
    *(unsigned int*)(curB + o) = pack2(v0, v1);
    unsigned int ua = *(const unsigned int*)(first ? (curA + o) : (acc + o));
    *(unsigned int*)(acc + o) = pack2(asf(ua << 16) + v0, asf(ua & 0xffff0000u) + v1);
}

// ---- out = (acc @ Wo^T + b) / 2 via MFMA -----------------------------------
__global__ __launch_bounds__(256) void k_outm(
    const unsigned short* __restrict__ acc, const unsigned short* __restrict__ Wob,
    const float* __restrict__ Wo_b, float* __restrict__ out, int N)
{
    int w = threadIdx.x >> 6, l = threadIdx.x & 63;
    int six = l & 15, quad = l >> 4;
    int base = (blockIdx.x * 4 + w) * 16;
    if (base >= N) return;
    int n = base + six;
    int nc = min(n, N - 1);
    const unsigned short* ar = acc + (size_t)nc * 128;
    bf16x8 b0 = *(const bf16x8*)(ar + quad * 8);
    bf16x8 b1 = *(const bf16x8*)(ar + 32 + quad * 8);
    bf16x8 b2 = *(const bf16x8*)(ar + 64 + quad * 8);
    bf16x8 b3 = *(const bf16x8*)(ar + 96 + quad * 8);
    #pragma unroll
    for (int t = 0; t < 4; ++t) {
        const unsigned short* wr = Wob + (size_t)(t * 16 + six) * 128;
        bf16x8 a0 = *(const bf16x8*)(wr + quad * 8);
        bf16x8 a1 = *(const bf16x8*)(wr + 32 + quad * 8);
        bf16x8 a2 = *(const bf16x8*)(wr + 64 + quad * 8);
        bf16x8 a3 = *(const bf16x8*)(wr + 96 + quad * 8);
        f32x4v c = {0.f, 0.f, 0.f, 0.f};
        c = __builtin_amdgcn_mfma_f32_16x16x32_bf16(a0, b0, c, 0, 0, 0);
        c = __builtin_amdgcn_mfma_f32_16x16x32_bf16(a1, b1, c, 0, 0, 0);
        c = __builtin_amdgcn_mfma_f32_16x16x32_bf16(a2, b2, c, 0, 0, 0);
        c = __builtin_amdgcn_mfma_f32_16x16x32_bf16(a3, b3, c, 0, 0, 0);
        if (n < N) {
            float4 bias = *(const float4*)(Wo_b + t * 16 + quad * 4);
            float4 o4;
            o4.x = (c[0] + bias.x) * 0.5f;
            o4.y = (c[1] + bias.y) * 0.5f;
            o4.z = (c[2] + bias.z) * 0.5f;
            o4.w = (c[3] + bias.w) * 0.5f;
            *(float4*)(out + (size_t)n * 64 + t * 16 + quad * 4) = o4;
        }
    }
}

extern "C" void kernel_launch(void* const* d_in, const int* in_sizes, int n_in,
                              void* d_out, int out_size, void* d_ws, size_t ws_size,
                              hipStream_t stream) {
    const float* x    = (const float*)d_in[0];
    const float* Wq_w = (const float*)d_in[1];
    const float* Wq_b = (const float*)d_in[2];
    const float* Wk_w = (const float*)d_in[3];
    const float* Wk_b = (const float*)d_in[4];
    const float* Wo_w = (const float*)d_in[5];
    const float* Wo_b = (const float*)d_in[6];
    const float* bond = (const float*)d_in[7];
    const int*   eidx = (const int*)d_in[8];
    const int*   eattr= (const int*)d_in[9];
    const int*   nn   = (const int*)d_in[10];
    float* out = (float*)d_out;
    int N = in_sizes[0] / 64;
    int E = in_sizes[9] / 3;
    int B = in_sizes[10];

    char* p = (char*)d_ws;
    auto alloc = [&](size_t bytes) { char* r = p; p += (bytes + 255) & ~(size_t)255; return r; };
    unsigned short* q    = (unsigned short*)alloc((size_t)N * 128 * 2);
    unsigned short* kq   = (unsigned short*)alloc((size_t)N * 128 * 2);
    unsigned short* curA = (unsigned short*)alloc((size_t)N * 128 * 2);
    unsigned short* curB = (unsigned short*)alloc((size_t)N * 128 * 2);
    unsigned short* acc  = (unsigned short*)alloc((size_t)N * 128 * 2);
    int maxchunks = (N + CHUNK - 1) / CHUNK + B;
    float* partKV = (float*)alloc((size_t)maxchunks * 8192 * 4);
    float* partVS = (float*)alloc((size_t)maxchunks * 128 * 4);
    float* partKS = (float*)alloc((size_t)maxchunks * 128 * 4);
    unsigned short* kvT_b = (unsigned short*)alloc((size_t)B * 2 * 64 * 64 * 2);
    float* vsum  = (float*)alloc((size_t)B * 128 * 4);
    float* ksum  = (float*)alloc((size_t)B * 128 * 4);
    float* denom = (float*)alloc((size_t)N * 2 * 4);
    float* dis   = (float*)alloc((size_t)N * 4);
    int* deg     = (int*)alloc((size_t)N * 4);
    int* rowstart= (int*)alloc((size_t)(N + 1) * 4);
    int* cursor  = (int*)alloc((size_t)N * 4);
    int4* csr_pack = (int4*)alloc((size_t)E * 16);
    int* batch   = (int*)alloc((size_t)N * 4);
    int* ptr     = (int*)alloc((size_t)(B + 1) * 4);
    int* cptr    = (int*)alloc((size_t)(B + 1) * 4);
    unsigned short* Wb = (unsigned short*)alloc(24576 * 2);
    int nb = (N + 255) / 256;
    int* bsum    = (int*)alloc((size_t)nb * 4);
    float* msg   = out;   // [N,64] fp32 aliased onto d_out; k_outm rewrites it last

    hipMemsetAsync(deg,    0, (size_t)N * 4, stream);
    hipMemsetAsync(cursor, 0, (size_t)N * 4, stream);

    k_ptr  <<<1, 64, 0, stream>>>(nn, ptr, cptr, B);
    k_batch<<<B, 256, 0, stream>>>(ptr, batch);
    k_wcvt <<<96, 256, 0, stream>>>(Wq_w, Wk_w, Wo_w, Wb);
    k_qkm  <<<(N + 63) / 64, 256, 0, stream>>>(x, Wb, Wq_b, Wk_b, q, kq, curA, N);
    k_deg  <<<(E + 255) / 256, 256, 0, stream>>>(eidx, deg, E);
    k_dis  <<<(N + 255) / 256, 256, 0, stream>>>(deg, dis, N);
    k_scan1<<<nb, 256, 0, stream>>>(deg, rowstart, bsum, N);
    k_scan2<<<1, 512, 0, stream>>>(bsum, nb);
    k_scan3<<<nb, 256, 0, stream>>>(rowstart, bsum, N, E);
    k_fill <<<(E + 255) / 256, 256, 0, stream>>>(eidx, dis, rowstart, cursor, csr_pack, eattr, E);
    k_msg  <<<2048, 256, 0, stream>>>(rowstart, csr_pack, bond, msg, N);
    k_ksump<<<maxchunks, 256, 0, stream>>>(kq, ptr, cptr, partKS, B);
    k_ksr  <<<B, 128, 0, stream>>>(partKS, cptr, ksum, B);
    k_denom<<<(N + 3) / 4, 256, 0, stream>>>(q, ksum, batch, nn, denom, N);

    for (int it = 0; it < 4; ++it) {
        k_kvp <<<maxchunks, 256, 0, stream>>>(kq, curA, ptr, cptr, partKV, partVS, B);
        k_red <<<B * 2, 256, 0, stream>>>(partKV, partVS, cptr, kvT_b, vsum, B);
        k_attn<<<(N + 63) / 64, 256, 0, stream>>>(q, kvT_b, vsum, denom, batch, curB, N);
        k_gcn <<<(N + 3) / 4, 256, 0, stream>>>(curA, msg, rowstart, csr_pack, curB, acc, N, it == 0 ? 1 : 0);
        unsigned short* tmp = curA; curA = curB; curB = tmp;
    }
    k_outm<<<(N + 63) / 64, 256, 0, stream>>>(acc, Wb + 16384, Wo_b, out, N);
}

// Round 11
// 899.119 us; speedup vs baseline: 2.1773x; 1.1877x over previous
//
#include <hip/hip_runtime.h>
#include <hip/hip_bf16.h>

// GloAttnConv R11: k_attn graph-aligned 16-node tiles via tptr (slow path for
// boundary-straddling tiles ELIMINATED - it was a serial-scalar tail that
// bounded the whole dispatch). Loads clamped, stores masked for short tiles.

typedef __attribute__((ext_vector_type(8))) short bf16x8;
typedef __attribute__((ext_vector_type(4))) float f32x4v;

#define CHUNK 100

__device__ __forceinline__ float asf(unsigned int u) { union { unsigned int i; float f; } v; v.i = u; return v.f; }
__device__ __forceinline__ float b2f_u(unsigned short u) { return asf((unsigned int)u << 16); }
__device__ __forceinline__ unsigned short f2b_u(float f) {
    __hip_bfloat16 h = __float2bfloat16(f);
    union { __hip_bfloat16 h; unsigned short u; } v; v.h = h; return v.u;
}
__device__ __forceinline__ unsigned int pack2(float a, float b) {
    return (unsigned int)f2b_u(a) | ((unsigned int)f2b_u(b) << 16);
}
__device__ __forceinline__ float wave_reduce_sum(float v) {
    #pragma unroll
    for (int off = 32; off > 0; off >>= 1) v += __shfl_xor(v, off, 64);
    return v;
}

// ---- graph bookkeeping: node ptr + chunk ptr + 16-tile ptr ------------------
__global__ void k_ptr(const int* __restrict__ nn, int* __restrict__ ptr,
                      int* __restrict__ cptr, int* __restrict__ tptr, int B) {
    if (threadIdx.x == 0 && blockIdx.x == 0) {
        int s = 0, c = 0, t = 0; ptr[0] = 0; cptr[0] = 0; tptr[0] = 0;
        for (int i = 0; i < B; ++i) {
            s += nn[i]; ptr[i + 1] = s;
            c += (nn[i] + CHUNK - 1) / CHUNK; cptr[i + 1] = c;
            t += (nn[i] + 15) / 16; tptr[i + 1] = t;
        }
    }
}

__global__ void k_batch(const int* __restrict__ ptr, int* __restrict__ batch) {
    int b = blockIdx.x;
    int s = ptr[b], e = ptr[b + 1];
    for (int i = s + threadIdx.x; i < e; i += blockDim.x) batch[i] = b;
}

// ---- W -> bf16 stacked: [0,8192)=Wq, [8192,16384)=Wk, [16384,24576)=Wo ------
__global__ void k_wcvt(const float* __restrict__ Wq_w, const float* __restrict__ Wk_w,
                       const float* __restrict__ Wo_w, unsigned short* __restrict__ Wb) {
    int i = blockIdx.x * 256 + threadIdx.x;
    if (i < 24576) {
        float v = (i < 8192) ? Wq_w[i] : ((i < 16384) ? Wk_w[i - 8192] : Wo_w[i - 16384]);
        Wb[i] = f2b_u(v);
    }
}

// ---- q/k projection via MFMA + L2-normalize; writes q, kq, curA ------------
__global__ __launch_bounds__(256) void k_qkm(
    const float* __restrict__ x, const unsigned short* __restrict__ Wb,
    const float* __restrict__ Wq_b, const float* __restrict__ Wk_b,
    unsigned short* __restrict__ q, unsigned short* __restrict__ kq,
    unsigned short* __restrict__ curA, int N)
{
    int w = threadIdx.x >> 6, l = threadIdx.x & 63;
    int six = l & 15, quad = l >> 4;
    int base = (blockIdx.x * 4 + w) * 16;
    if (base >= N) return;
    int n = base + six;
    int nc = min(n, N - 1);

    const float* xr = x + (size_t)nc * 64;
    float xv0[8], xv1[8];
    #pragma unroll
    for (int j = 0; j < 8; ++j) { xv0[j] = xr[quad * 8 + j]; xv1[j] = xr[32 + quad * 8 + j]; }
    union { bf16x8 v; unsigned int u[4]; } b0, b1;
    #pragma unroll
    for (int i = 0; i < 4; ++i) {
        b0.u[i] = pack2(xv0[2 * i], xv0[2 * i + 1]);
        b1.u[i] = pack2(xv1[2 * i], xv1[2 * i + 1]);
    }
    if (n < N) {
        unsigned short* cr = curA + (size_t)n * 128;
        *(uint4*)(cr + quad * 8)       = make_uint4(b0.u[0], b0.u[1], b0.u[2], b0.u[3]);
        *(uint4*)(cr + 32 + quad * 8)  = make_uint4(b1.u[0], b1.u[1], b1.u[2], b1.u[3]);
        *(uint4*)(cr + 64 + quad * 8)  = make_uint4(b0.u[0], b0.u[1], b0.u[2], b0.u[3]);
        *(uint4*)(cr + 96 + quad * 8)  = make_uint4(b1.u[0], b1.u[1], b1.u[2], b1.u[3]);
    }

    #pragma unroll
    for (int g = 0; g < 4; ++g) {
        f32x4v c[4];
        #pragma unroll
        for (int tt = 0; tt < 4; ++tt) {
            int t = g * 4 + tt;
            const unsigned short* wr = Wb + (size_t)(t * 16 + six) * 64;
            bf16x8 a0 = *(const bf16x8*)(wr + quad * 8);
            bf16x8 a1 = *(const bf16x8*)(wr + 32 + quad * 8);
            f32x4v cc = {0.f, 0.f, 0.f, 0.f};
            cc = __builtin_amdgcn_mfma_f32_16x16x32_bf16(a0, b0.v, cc, 0, 0, 0);
            cc = __builtin_amdgcn_mfma_f32_16x16x32_bf16(a1, b1.v, cc, 0, 0, 0);
            c[tt] = cc;
        }
        const float* bias = (g < 2) ? Wq_b : Wk_b;
        int cb = (g & 1) * 64 + quad * 4;
        float ss = 0.f;
        #pragma unroll
        for (int tt = 0; tt < 4; ++tt)
            #pragma unroll
            for (int r = 0; r < 4; ++r) {
                float v = c[tt][r] + bias[cb + tt * 16 + r];
                c[tt][r] = v;
                ss += v * v;
            }
        ss += __shfl_xor(ss, 16, 64);
        ss += __shfl_xor(ss, 32, 64);
        float sc = rsqrtf(ss);
        if (n < N) {
            unsigned short* dst = ((g < 2) ? q : kq) + (size_t)n * 128;
            #pragma unroll
            for (int tt = 0; tt < 4; ++tt) {
                unsigned int u0 = pack2(c[tt][0] * sc, c[tt][1] * sc);
                unsigned int u1 = pack2(c[tt][2] * sc, c[tt][3] * sc);
                *(uint2*)(dst + cb + tt * 16) = make_uint2(u0, u1);
            }
        }
    }
}

// ---- degree / dis ----------------------------------------------------------
__global__ void k_deg(const int* __restrict__ row, int* __restrict__ deg, int E) {
    int e = blockIdx.x * 256 + threadIdx.x;
    if (e < E) atomicAdd(&deg[row[e]], 1);
}

__global__ void k_dis(const int* __restrict__ deg, float* __restrict__ dis, int N) {
    int n = blockIdx.x * 256 + threadIdx.x;
    if (n < N) { int d = deg[n]; dis[n] = d > 0 ? rsqrtf((float)d) : 0.f; }
}

// ---- exclusive scan of deg -> rowstart -------------------------------------
__global__ void k_scan1(const int* __restrict__ deg, int* __restrict__ rowstart,
                        int* __restrict__ bsum, int N) {
    __shared__ int sh[256];
    int t = threadIdx.x, n = blockIdx.x * 256 + t;
    int v = (n < N) ? deg[n] : 0;
    sh[t] = v; __syncthreads();
    #pragma unroll
    for (int off = 1; off < 256; off <<= 1) {
        int add = (t >= off) ? sh[t - off] : 0;
        __syncthreads();
        sh[t] += add;
        __syncthreads();
    }
    if (n < N) rowstart[n] = sh[t] - v;
    if (t == 255) bsum[blockIdx.x] = sh[255];
}

__global__ void k_scan2(int* __restrict__ bsum, int nb) {
    __shared__ int sh[512];
    __shared__ int carry;
    int t = threadIdx.x;
    if (t == 0) carry = 0;
    __syncthreads();
    for (int base = 0; base < nb; base += 512) {
        int idx = base + t;
        int v = (idx < nb) ? bsum[idx] : 0;
        sh[t] = v; __syncthreads();
        for (int off = 1; off < 512; off <<= 1) {
            int add = (t >= off) ? sh[t - off] : 0;
            __syncthreads();
            sh[t] += add;
            __syncthreads();
        }
        if (idx < nb) bsum[idx] = sh[t] - v + carry;
        __syncthreads();
        if (t == 0) carry += sh[511];
        __syncthreads();
    }
}

__global__ void k_scan3(int* __restrict__ rowstart, const int* __restrict__ bsum, int N, int E) {
    int n = blockIdx.x * 256 + threadIdx.x;
    if (n < N) rowstart[n] += bsum[blockIdx.x];
    if (n == 0) rowstart[N] = E;
}

// ---- CSR fill: ONE int4 {col, w_bits, att, 0} store per edge ---------------
__global__ void k_fill(const int* __restrict__ eidx, const float* __restrict__ dis,
                       const int* __restrict__ rowstart, int* __restrict__ cursor,
                       int4* __restrict__ csr_pack, const int* __restrict__ eattr, int E) {
    int e = blockIdx.x * 256 + threadIdx.x;
    if (e >= E) return;
    int r = eidx[e], c = eidx[E + e];
    float wv = dis[r] * dis[c];
    int a0 = eattr[e * 3 + 0], a1 = eattr[e * 3 + 1], a2 = eattr[e * 3 + 2];
    int slot = atomicAdd(&cursor[r], 1);
    int idx = rowstart[r] + slot;
    int4 v;
    v.x = c;
    v.y = __float_as_int(wv);
    v.z = a0 | (a1 << 8) | (a2 << 16);
    v.w = 0;
    csr_pack[idx] = v;
}

// ---- msg_edge[n,64]; bond table in LDS, wave per node ----------------------
__global__ __launch_bounds__(256) void k_msg(
    const int* __restrict__ rowstart, const int4* __restrict__ csr_pack,
    const float* __restrict__ bond, float* __restrict__ msg, int N) {
    __shared__ float bl[1536];
    int t = threadIdx.x, w = t >> 6, l = t & 63;
    for (int i = t; i < 1536; i += 256) bl[i] = bond[i];
    __syncthreads();
    for (int n = blockIdx.x * 4 + w; n < N; n += gridDim.x * 4) {
        int s0 = rowstart[n], s1 = rowstart[n + 1];
        float m = 0.f;
        for (int i = s0; i < s1; ++i) {
            int4 pk = csr_pack[i];
            float wv = __int_as_float(pk.y);
            int att = pk.z;
            m += wv * (bl[(att & 255) * 64 + l] + bl[(8 + ((att >> 8) & 255)) * 64 + l]
                     + bl[(16 + (att >> 16)) * 64 + l]);
        }
        msg[(size_t)n * 64 + l] = m;
    }
}

// ---- ksum stage 1: per-chunk partial (plain stores) ------------------------
__global__ __launch_bounds__(256) void k_ksump(
    const unsigned short* __restrict__ kq, const int* __restrict__ ptr,
    const int* __restrict__ cptr, float* __restrict__ partKS, int B)
{
    int cid = blockIdx.x;
    if (cid >= cptr[B]) return;
    int lo = 0, hi = B - 1;
    while (lo < hi) { int mid = (lo + hi + 1) >> 1; if (cptr[mid] <= cid) lo = mid; else hi = mid - 1; }
    int b = lo;
    int start = ptr[b] + (cid - cptr[b]) * CHUNK;
    int end = min(start + CHUNK, ptr[b + 1]);
    int t = threadIdx.x, r = t >> 7, col = t & 127;
    float a = 0.f;
    for (int n = start + r; n < end; n += 2)
        a += b2f_u(kq[(size_t)n * 128 + col]);
    __shared__ float sh[256];
    sh[t] = a;
    __syncthreads();
    if (t < 128) partKS[(size_t)cid * 128 + t] = sh[t] + sh[t + 128];
}

// ---- ksum stage 2: sum chunk partials per graph ----------------------------
__global__ __launch_bounds__(128) void k_ksr(
    const float* __restrict__ partKS, const int* __restrict__ cptr,
    float* __restrict__ ksum, int B)
{
    int b = blockIdx.x, t = threadIdx.x;
    float s = 0.f;
    int c0 = cptr[b], c1 = cptr[b + 1];
    for (int c = c0; c < c1; ++c) s += partKS[(size_t)c * 128 + t];
    ksum[b * 128 + t] = s;
}

// ---- denom[n][h] = q[n,h,:].ksum[b,h,:] + n_nodes[b] -----------------------
__global__ __launch_bounds__(256) void k_denom(
    const unsigned short* __restrict__ q, const float* __restrict__ ksum,
    const int* __restrict__ batch, const int* __restrict__ nn,
    float* __restrict__ denom, int N)
{
    int w = threadIdx.x >> 6, l = threadIdx.x & 63;
    int n = blockIdx.x * 4 + w;
    if (n >= N) return;
    int b = batch[n];
    float d0 = b2f_u(q[(size_t)n * 128 + l]) * ksum[b * 128 + l];
    float d1 = b2f_u(q[(size_t)n * 128 + 64 + l]) * ksum[b * 128 + 64 + l];
    d0 = wave_reduce_sum(d0);
    d1 = wave_reduce_sum(d1);
    if (l == 0) {
        float nf = (float)nn[b];
        denom[n * 2 + 0] = d0 + nf;
        denom[n * 2 + 1] = d1 + nf;
    }
}

// ---- stage 1: per-chunk partial kv (plain stores, no atomics) --------------
__global__ __launch_bounds__(256) void k_kvp(
    const unsigned short* __restrict__ kq, const unsigned short* __restrict__ cur,
    const int* __restrict__ ptr, const int* __restrict__ cptr,
    float* __restrict__ partKV, float* __restrict__ partVS, int B)
{
    int cid = blockIdx.x;
    if (cid >= cptr[B]) return;
    int lo = 0, hi = B - 1;
    while (lo < hi) { int mid = (lo + hi + 1) >> 1; if (cptr[mid] <= cid) lo = mid; else hi = mid - 1; }
    int b = lo;
    int start = ptr[b] + (cid - cptr[b]) * CHUNK;
    int end = min(start + CHUNK, ptr[b + 1]);

    int w = threadIdx.x >> 6, l = threadIdx.x & 63;
    int h = w >> 1, dhalf = w & 1;
    int d0 = dhalf * 32 + (l & 7) * 4;
    int e0 = (l >> 3) * 8;
    float a[4][8], va[8];
    #pragma unroll
    for (int i = 0; i < 4; ++i)
        #pragma unroll
        for (int j = 0; j < 8; ++j) a[i][j] = 0.f;
    #pragma unroll
    for (int j = 0; j < 8; ++j) va[j] = 0.f;

    const unsigned short* kp = kq + (size_t)start * 128 + h * 64 + d0;
    const unsigned short* vp = cur + (size_t)start * 128 + h * 64 + e0;
    #pragma unroll 4
    for (int n = start; n < end; ++n) {
        uint2 ku = *(const uint2*)kp;
        uint4 vu = *(const uint4*)vp;
        kp += 128; vp += 128;
        float k0 = asf(ku.x << 16), k1 = asf(ku.x & 0xffff0000u);
        float k2 = asf(ku.y << 16), k3 = asf(ku.y & 0xffff0000u);
        float v[8];
        v[0] = asf(vu.x << 16); v[1] = asf(vu.x & 0xffff0000u);
        v[2] = asf(vu.y << 16); v[3] = asf(vu.y & 0xffff0000u);
        v[4] = asf(vu.z << 16); v[5] = asf(vu.z & 0xffff0000u);
        v[6] = asf(vu.w << 16); v[7] = asf(vu.w & 0xffff0000u);
        #pragma unroll
        for (int j = 0; j < 8; ++j) {
            a[0][j] += k0 * v[j]; a[1][j] += k1 * v[j];
            a[2][j] += k2 * v[j]; a[3][j] += k3 * v[j];
            va[j] += v[j];
        }
    }
    float* dst = partKV + (size_t)cid * 8192 + h * 4096;
    #pragma unroll
    for (int j = 0; j < 8; ++j) {
        float4 s4 = { a[0][j], a[1][j], a[2][j], a[3][j] };
        *(float4*)(dst + (e0 + j) * 64 + d0) = s4;
    }
    if (dhalf == 0 && (l & 7) == 0) {
        float* vdst = partVS + (size_t)cid * 128 + h * 64 + e0;
        #pragma unroll
        for (int j = 0; j < 8; ++j) vdst[j] = va[j];
    }
}

// ---- stage 2: sum partials -> kvT bf16 + vsum ------------------------------
__global__ __launch_bounds__(256) void k_red(
    const float* __restrict__ partKV, const float* __restrict__ partVS,
    const int* __restrict__ cptr, unsigned short* __restrict__ kvT_b,
    float* __restrict__ vsum, int B)
{
    int gh = blockIdx.x, g = gh >> 1, h = gh & 1;
    int c0 = cptr[g], c1 = cptr[g + 1];
    int t = threadIdx.x;
    float s[16];
    #pragma unroll
    for (int i = 0; i < 16; ++i) s[i] = 0.f;
    for (int c = c0; c < c1; ++c) {
        const float4* src = (const float4*)(partKV + (size_t)c * 8192 + h * 4096 + t * 16);
        #pragma unroll
        for (int i = 0; i < 4; ++i) {
            float4 v = src[i];
            s[i * 4 + 0] += v.x; s[i * 4 + 1] += v.y; s[i * 4 + 2] += v.z; s[i * 4 + 3] += v.w;
        }
    }
    unsigned int u[8];
    #pragma unroll
    for (int i = 0; i < 8; ++i) u[i] = pack2(s[2 * i], s[2 * i + 1]);
    uint4* dst = (uint4*)(kvT_b + (size_t)gh * 4096 + t * 16);
    dst[0] = make_uint4(u[0], u[1], u[2], u[3]);
    dst[1] = make_uint4(u[4], u[5], u[6], u[7]);
    if (t < 64) {
        float vs = 0.f;
        for (int c = c0; c < c1; ++c) vs += partVS[(size_t)c * 128 + h * 64 + t];
        vsum[g * 128 + h * 64 + t] = vs;
    }
}

// ---- attn via MFMA on graph-aligned 16-node tiles (no slow path) -----------
__global__ __launch_bounds__(256) void k_attn(
    const unsigned short* __restrict__ q, const unsigned short* __restrict__ kvT,
    const float* __restrict__ vsum, const float* __restrict__ denom,
    const int* __restrict__ ptr, const int* __restrict__ tptr,
    unsigned short* __restrict__ curB, int B)
{
    int w = threadIdx.x >> 6, l = threadIdx.x & 63;
    int tid = blockIdx.x * 4 + w;
    if (tid >= tptr[B]) return;
    int lo = 0, hi = B - 1;
    while (lo < hi) { int mid = (lo + hi + 1) >> 1; if (tptr[mid] <= tid) lo = mid; else hi = mid - 1; }
    int b0 = lo;
    int start = ptr[b0] + (tid - tptr[b0]) * 16;
    int end = min(start + 16, ptr[b0 + 1]);
    int quad = l >> 4, six = l & 15;
    int n = start + six;        // this lane's node (C column)
    int nc = min(n, end - 1);   // clamped for loads
    bool live = n < end;
    #pragma unroll
    for (int h = 0; h < 2; ++h) {
        const unsigned short* qrow = q + (size_t)nc * 128 + h * 64;
        bf16x8 qb0 = *(const bf16x8*)(qrow + quad * 8);        // B-frag k=quad*8+j
        bf16x8 qb1 = *(const bf16x8*)(qrow + 32 + quad * 8);
        const unsigned short* Bb = kvT + (size_t)(b0 * 2 + h) * 4096;
        float dn = denom[nc * 2 + h];
        const float* vsb = vsum + (b0 * 2 + h) * 64;
        #pragma unroll
        for (int et = 0; et < 4; ++et) {
            const unsigned short* arow = Bb + (size_t)(et * 16 + six) * 64;  // A m=e row
            bf16x8 a0 = *(const bf16x8*)(arow + quad * 8);
            bf16x8 a1 = *(const bf16x8*)(arow + 32 + quad * 8);
            f32x4v c = {0.f, 0.f, 0.f, 0.f};
            c = __builtin_amdgcn_mfma_f32_16x16x32_bf16(a0, qb0, c, 0, 0, 0);
            c = __builtin_amdgcn_mfma_f32_16x16x32_bf16(a1, qb1, c, 0, 0, 0);
            // lane holds num[node=n][e = et*16 + quad*4 + r], r=0..3
            float4 vs = *(const float4*)(vsb + et * 16 + quad * 4);
            float v0 = 0.5f * (c[0] + vs.x) / dn;
            float v1 = 0.5f * (c[1] + vs.y) / dn;
            float v2 = 0.5f * (c[2] + vs.z) / dn;
            float v3 = 0.5f * (c[3] + vs.w) / dn;
            if (live) {
                uint2 st = make_uint2(pack2(v0, v1), pack2(v2, v3));
                *(uint2*)(curB + (size_t)n * 128 + h * 64 + et * 16 + quad * 4) = st;
            }
        }
    }
}

// ---- GCN gather + combine (wave per node). first=1: acc base = curA row ----
__global__ __launch_bounds__(256) void k_gcn(
    const unsigned short* __restrict__ curA, const float* __restrict__ msg,
    const int* __restrict__ rowstart, const int4* __restrict__ csr_pack,
    unsigned short* __restrict__ curB, unsigned short* __restrict__ acc, int N, int first)
{
    int w = threadIdx.x >> 6, l = threadIdx.x & 63;
    int n = blockIdx.x * 4 + w;
    if (n >= N) return;
    int s0 = rowstart[n], s1 = rowstart[n + 1];
    float g0 = 0.f, g1 = 0.f;
    #pragma unroll 2
    for (int i = s0; i < s1; ++i) {
        int4 pk = csr_pack[i];
        int c = pk.x;
        float wv = __int_as_float(pk.y);
        unsigned int u = *(const unsigned int*)(curA + (size_t)c * 128 + 2 * l);
        g0 += wv * asf(u << 16);
        g1 += wv * asf(u & 0xffff0000u);
    }
    float2 m = *(const float2*)(msg + (size_t)n * 64 + ((2 * l) & 63));
    size_t o = (size_t)n * 128 + 2 * l;
    unsigned int ub = *(const unsigned int*)(curB + o);
    float v0 = 0.5f * (g0 + m.x) + asf(ub << 16);
    float v1 = 0.5f * (g1 + m.y) + asf(ub & 0xffff0000u);
    *(unsigned int*)(curB + o) = pack2(v0, v1);
    unsigned int ua = *(const unsigned int*)(first ? (curA + o) : (acc + o));
    *(unsigned int*)(acc + o) = pack2(asf(ua << 16) + v0, asf(ua & 0xffff0000u) + v1);
}

// ---- out = (acc @ Wo^T + b) / 2 via MFMA -----------------------------------
__global__ __launch_bounds__(256) void k_outm(
    const unsigned short* __restrict__ acc, const unsigned short* __restrict__ Wob,
    const float* __restrict__ Wo_b, float* __restrict__ out, int N)
{
    int w = threadIdx.x >> 6, l = threadIdx.x & 63;
    int six = l & 15, quad = l >> 4;
    int base = (blockIdx.x * 4 + w) * 16;
    if (base >= N) return;
    int n = base + six;
    int nc = min(n, N - 1);
    const unsigned short* ar = acc + (size_t)nc * 128;
    bf16x8 b0 = *(const bf16x8*)(ar + quad * 8);
    bf16x8 b1 = *(const bf16x8*)(ar + 32 + quad * 8);
    bf16x8 b2 = *(const bf16x8*)(ar + 64 + quad * 8);
    bf16x8 b3 = *(const bf16x8*)(ar + 96 + quad * 8);
    #pragma unroll
    for (int t = 0; t < 4; ++t) {
        const unsigned short* wr = Wob + (size_t)(t * 16 + six) * 128;
        bf16x8 a0 = *(const bf16x8*)(wr + quad * 8);
        bf16x8 a1 = *(const bf16x8*)(wr + 32 + quad * 8);
        bf16x8 a2 = *(const bf16x8*)(wr + 64 + quad * 8);
        bf16x8 a3 = *(const bf16x8*)(wr + 96 + quad * 8);
        f32x4v c = {0.f, 0.f, 0.f, 0.f};
        c = __builtin_amdgcn_mfma_f32_16x16x32_bf16(a0, b0, c, 0, 0, 0);
        c = __builtin_amdgcn_mfma_f32_16x16x32_bf16(a1, b1, c, 0, 0, 0);
        c = __builtin_amdgcn_mfma_f32_16x16x32_bf16(a2, b2, c, 0, 0, 0);
        c = __builtin_amdgcn_mfma_f32_16x16x32_bf16(a3, b3, c, 0, 0, 0);
        if (n < N) {
            float4 bias = *(const float4*)(Wo_b + t * 16 + quad * 4);
            float4 o4;
            o4.x = (c[0] + bias.x) * 0.5f;
            o4.y = (c[1] + bias.y) * 0.5f;
            o4.z = (c[2] + bias.z) * 0.5f;
            o4.w = (c[3] + bias.w) * 0.5f;
            *(float4*)(out + (size_t)n * 64 + t * 16 + quad * 4) = o4;
        }
    }
}

extern "C" void kernel_launch(void* const* d_in, const int* in_sizes, int n_in,
                              void* d_out, int out_size, void* d_ws, size_t ws_size,
                              hipStream_t stream) {
    const float* x    = (const float*)d_in[0];
    const float* Wq_w = (const float*)d_in[1];
    const float* Wq_b = (const float*)d_in[2];
    const float* Wk_w = (const float*)d_in[3];
    const float* Wk_b = (const float*)d_in[4];
    const float* Wo_w = (const float*)d_in[5];
    const float* Wo_b = (const float*)d_in[6];
    const float* bond = (const float*)d_in[7];
    const int*   eidx = (const int*)d_in[8];
    const int*   eattr= (const int*)d_in[9];
    const int*   nn   = (const int*)d_in[10];
    float* out = (float*)d_out;
    int N = in_sizes[0] / 64;
    int E = in_sizes[9] / 3;
    int B = in_sizes[10];

    char* p = (char*)d_ws;
    auto alloc = [&](size_t bytes) { char* r = p; p += (bytes + 255) & ~(size_t)255; return r; };
    unsigned short* q    = (unsigned short*)alloc((size_t)N * 128 * 2);
    unsigned short* kq   = (unsigned short*)alloc((size_t)N * 128 * 2);
    unsigned short* curA = (unsigned short*)alloc((size_t)N * 128 * 2);
    unsigned short* curB = (unsigned short*)alloc((size_t)N * 128 * 2);
    unsigned short* acc  = (unsigned short*)alloc((size_t)N * 128 * 2);
    int maxchunks = (N + CHUNK - 1) / CHUNK + B;
    int maxtiles  = (N + 15) / 16 + B;
    float* partKV = (float*)alloc((size_t)maxchunks * 8192 * 4);
    float* partVS = (float*)alloc((size_t)maxchunks * 128 * 4);
    float* partKS = (float*)alloc((size_t)maxchunks * 128 * 4);
    unsigned short* kvT_b = (unsigned short*)alloc((size_t)B * 2 * 64 * 64 * 2);
    float* vsum  = (float*)alloc((size_t)B * 128 * 4);
    float* ksum  = (float*)alloc((size_t)B * 128 * 4);
    float* denom = (float*)alloc((size_t)N * 2 * 4);
    float* dis   = (float*)alloc((size_t)N * 4);
    int* deg     = (int*)alloc((size_t)N * 4);
    int* rowstart= (int*)alloc((size_t)(N + 1) * 4);
    int* cursor  = (int*)alloc((size_t)N * 4);
    int4* csr_pack = (int4*)alloc((size_t)E * 16);
    int* batch   = (int*)alloc((size_t)N * 4);
    int* ptr     = (int*)alloc((size_t)(B + 1) * 4);
    int* cptr    = (int*)alloc((size_t)(B + 1) * 4);
    int* tptr    = (int*)alloc((size_t)(B + 1) * 4);
    unsigned short* Wb = (unsigned short*)alloc(24576 * 2);
    int nb = (N + 255) / 256;
    int* bsum    = (int*)alloc((size_t)nb * 4);
    float* msg   = out;   // [N,64] fp32 aliased onto d_out; k_outm rewrites it last

    hipMemsetAsync(deg,    0, (size_t)N * 4, stream);
    hipMemsetAsync(cursor, 0, (size_t)N * 4, stream);

    k_ptr  <<<1, 64, 0, stream>>>(nn, ptr, cptr, tptr, B);
    k_batch<<<B, 256, 0, stream>>>(ptr, batch);
    k_wcvt <<<96, 256, 0, stream>>>(Wq_w, Wk_w, Wo_w, Wb);
    k_qkm  <<<(N + 63) / 64, 256, 0, stream>>>(x, Wb, Wq_b, Wk_b, q, kq, curA, N);
    k_deg  <<<(E + 255) / 256, 256, 0, stream>>>(eidx, deg, E);
    k_dis  <<<(N + 255) / 256, 256, 0, stream>>>(deg, dis, N);
    k_scan1<<<nb, 256, 0, stream>>>(deg, rowstart, bsum, N);
    k_scan2<<<1, 512, 0, stream>>>(bsum, nb);
    k_scan3<<<nb, 256, 0, stream>>>(rowstart, bsum, N, E);
    k_fill <<<(E + 255) / 256, 256, 0, stream>>>(eidx, dis, rowstart, cursor, csr_pack, eattr, E);
    k_msg  <<<2048, 256, 0, stream>>>(rowstart, csr_pack, bond, msg, N);
    k_ksump<<<maxchunks, 256, 0, stream>>>(kq, ptr, cptr, partKS, B);
    k_ksr  <<<B, 128, 0, stream>>>(partKS, cptr, ksum, B);
    k_denom<<<(N + 3) / 4, 256, 0, stream>>>(q, ksum, batch, nn, denom, N);

    for (int it = 0; it < 4; ++it) {
        k_kvp <<<maxchunks, 256, 0, stream>>>(kq, curA, ptr, cptr, partKV, partVS, B);
        k_red <<<B * 2, 256, 0, stream>>>(partKV, partVS, cptr, kvT_b, vsum, B);
        k_attn<<<(maxtiles + 3) / 4, 256, 0, stream>>>(q, kvT_b, vsum, denom, ptr, tptr, curB, B);
        k_gcn <<<(N + 3) / 4, 256, 0, stream>>>(curA, msg, rowstart, csr_pack, curB, acc, N, it == 0 ? 1 : 0);
        unsigned short* tmp = curA; curA = curB; curB = tmp;
    }
    k_outm<<<(N + 63) / 64, 256, 0, stream>>>(acc, Wb + 16384, Wo_b, out, N);
}